// Round 2
// baseline (4101.442 us; speedup 1.0000x reference)
//
#include <hip/hip_runtime.h>
#include <hip/hip_bf16.h>
#include <math.h>

#define NB 128     // batch
#define NC 512     // channels
#define NT 40      // time steps
#define HW 512     // nH*nW
#define HL 256     // LSTM hidden per direction
#define NG 5000    // nclass
#define XDIM 1024  // 2*NC (GRU input)
#define G4 1024    // 4*HL
#define G3 1536    // 3*NC

// ---------------------------------------------------------------------------
// small setup kernels
// ---------------------------------------------------------------------------
__global__ void offsets_kernel(const int* __restrict__ tl, int* __restrict__ offs) {
  if (threadIdx.x == 0) {
    int o = 0;
    for (int b = 0; b < NB; ++b) { offs[b] = o; o += tl[b]; }
  }
}

__global__ void rowmap_kernel(const int* __restrict__ tl, const int* __restrict__ offs,
                              int* __restrict__ rowmap) {
  int b = blockIdx.x;
  int len = tl[b], off = offs[b];
  for (int t = threadIdx.x; t < len; t += blockDim.x)
    rowmap[off + t] = t * NB + b;   // row index into [t][b][*] matrices
}

__global__ void zero_kernel(float* __restrict__ p, int n) {
  int i = blockIdx.x * 256 + threadIdx.x;
  if (i < n) p[i] = 0.f;
}

// 1/sum over HW per (b,t)
__global__ __launch_bounds__(64) void asum_kernel(const float* __restrict__ A,
                                                  float* __restrict__ out) {
  int row = blockIdx.x;  // b*NT + t
  const float* p = A + (size_t)row * HW;
  float s = 0.f;
#pragma unroll
  for (int i = 0; i < 8; ++i) s += p[threadIdx.x + i * 64];
#pragma unroll
  for (int off = 32; off > 0; off >>= 1) s += __shfl_down(s, off);
  if (threadIdx.x == 0) out[row] = 1.0f / s;
}

// teacher-forcing embedding into x[:,:,512:1024]
__global__ __launch_bounds__(128) void emb_kernel(const float* __restrict__ ce,
                                                  const int* __restrict__ text,
                                                  const int* __restrict__ tl,
                                                  const int* __restrict__ offs,
                                                  float* __restrict__ x) {
  int bid = blockIdx.x;  // t*NB + b
  int t = bid >> 7, b = bid & 127;
  int tok = 0;
  if (t >= 2) {
    int p = t - 2;
    if (p < tl[b]) tok = text[offs[b] + p] + 1;
  }
  float4 v = *(const float4*)(ce + (size_t)tok * NC + threadIdx.x * 4);
  *(float4*)(x + (size_t)bid * XDIM + NC + threadIdx.x * 4) = v;
}

// ---------------------------------------------------------------------------
// device-wide monotonic barrier (grid must be fully co-resident)
// ---------------------------------------------------------------------------
__device__ __forceinline__ void gbar(int* bar, int* gen, int nb, int step) {
  __syncthreads();   // drains vmcnt: all block stores issued & complete-ordered
  if (threadIdx.x == 0) {
    __threadfence();  // release: write back L2 so other XCDs can see h
    int a = __hip_atomic_fetch_add(bar, 1, __ATOMIC_RELAXED, __HIP_MEMORY_SCOPE_AGENT);
    if (a == nb * step - 1) {
      __hip_atomic_store(gen, step, __ATOMIC_RELEASE, __HIP_MEMORY_SCOPE_AGENT);
    } else {
      while (__hip_atomic_load(gen, __ATOMIC_RELAXED, __HIP_MEMORY_SCOPE_AGENT) < step) {
        __builtin_amdgcn_s_sleep(1);
      }
    }
    __threadfence();  // acquire: invalidate stale L1/L2 before reading new h
  }
  __syncthreads();
}

// ---------------------------------------------------------------------------
// generic f32 SGEMM: out[m][n] = sum_k Arow(m)[k] * B[n][k] * (bscale?bscale[n]:1)
//                    + (bias?bias[n]:0)
// A rows optionally gathered through rowmap. Batched via blockIdx.z strides.
// out address = out + b*Obstride + m*ldoM + n*ldoN  (supports transposed writes)
// 128x128 tile, 256 threads, 8x8 per thread, BK=16, register-prefetch dbuf.
// B-fragment split (c0, c0+64) => 2-way LDS aliasing only (free).
// ---------------------------------------------------------------------------
__global__ __launch_bounds__(256) void sgemm_kernel(
    int M, int N, int K,
    const float* __restrict__ A, int lda, long Abstride,
    const int* __restrict__ rowmap,
    const float* __restrict__ B, int ldb, long Bbstride,
    const float* __restrict__ bscale, int bscaleBstride,
    const float* __restrict__ bias,
    float* __restrict__ out, long ldoM, long ldoN, long Obstride) {
  const int batch = blockIdx.z;
  A += (long)batch * Abstride;
  B += (long)batch * Bbstride;
  out += (long)batch * Obstride;
  const float* bsc = bscale ? bscale + (long)batch * bscaleBstride : nullptr;

  __shared__ __align__(16) float As[16][132];  // [k][m]
  __shared__ __align__(16) float Bs[16][132];  // [k][n]

  const int m0 = blockIdx.y * 128, n0 = blockIdx.x * 128;
  const int tid = threadIdx.x;
  const int tm = tid >> 4, tn = tid & 15;
  const int r0 = tm * 8, c0 = tn * 4;   // B frag split: cols c0..c0+3, c0+64..c0+67
  float acc[8][8] = {};
  float4 pa[2], pb[2];

  auto fetch = [&](int k0) {
#pragma unroll
    for (int it = 0; it < 2; ++it) {
      int ch = tid + it * 256;  // (row, kq) chunks
      int mm = ch >> 2;
      int kq = (ch & 3) << 2;
      int gm = m0 + mm;
      float4 v = make_float4(0.f, 0.f, 0.f, 0.f);
      if (gm < M) {
        long ar = rowmap ? (long)rowmap[gm] : (long)gm;
        v = *(const float4*)(A + ar * lda + k0 + kq);
      }
      pa[it] = v;
      int gn = n0 + mm;
      v = make_float4(0.f, 0.f, 0.f, 0.f);
      if (gn < N) {
        v = *(const float4*)(B + (long)gn * ldb + k0 + kq);
        if (bsc) { float s = bsc[gn]; v.x *= s; v.y *= s; v.z *= s; v.w *= s; }
      }
      pb[it] = v;
    }
  };

  auto store_lds = [&]() {
#pragma unroll
    for (int it = 0; it < 2; ++it) {
      int ch = tid + it * 256;
      int mm = ch >> 2;
      int kq = (ch & 3) << 2;
      As[kq + 0][mm] = pa[it].x; As[kq + 1][mm] = pa[it].y;
      As[kq + 2][mm] = pa[it].z; As[kq + 3][mm] = pa[it].w;
      Bs[kq + 0][mm] = pb[it].x; Bs[kq + 1][mm] = pb[it].y;
      Bs[kq + 2][mm] = pb[it].z; Bs[kq + 3][mm] = pb[it].w;
    }
  };

  fetch(0);
  for (int k0 = 0; k0 < K; k0 += 16) {
    store_lds();
    __syncthreads();
    if (k0 + 16 < K) fetch(k0 + 16);  // overlap next-tile global latency w/ compute
#pragma unroll
    for (int kk = 0; kk < 16; ++kk) {
      float a[8], bb[8];
      *(float4*)&a[0] = *(const float4*)&As[kk][r0];
      *(float4*)&a[4] = *(const float4*)&As[kk][r0 + 4];
      *(float4*)&bb[0] = *(const float4*)&Bs[kk][c0];
      *(float4*)&bb[4] = *(const float4*)&Bs[kk][c0 + 64];
#pragma unroll
      for (int i = 0; i < 8; ++i)
#pragma unroll
        for (int j = 0; j < 8; ++j) acc[i][j] += a[i] * bb[j];
    }
    __syncthreads();
  }
#pragma unroll
  for (int i = 0; i < 8; ++i) {
    int gm = m0 + r0 + i;
    if (gm >= M) continue;
#pragma unroll
    for (int j = 0; j < 8; ++j) {
      int gn = n0 + c0 + (j & 3) + ((j >> 2) << 6);
      if (gn >= N) continue;
      float v = acc[i][j];
      if (bias) v += bias[gn];
      out[(long)gm * ldoM + (long)gn * ldoN] = v;
    }
  }
}

// ---------------------------------------------------------------------------
// persistent LSTM (both directions), grid = 256 blocks x 256 thr, 1/CU.
// block: dir = bid>>7, j-chunk of 2. thread = (b, jj). c lives in a register.
// ---------------------------------------------------------------------------
__device__ __forceinline__ float sigm(float x) { return 1.f / (1.f + expf(-x)); }

__global__ __launch_bounds__(256) void lstm_persist_kernel(
    const float* __restrict__ xg_f, const float* __restrict__ xg_b,
    const float* __restrict__ Whh_f, const float* __restrict__ Whh_b,
    const float* __restrict__ bhh_f, const float* __restrict__ bhh_b,
    float* __restrict__ hl,   // [dir][slot][NB][HL]
    float* __restrict__ x, int* bar, int* gen) {
  const int bid = blockIdx.x;
  const int dir = bid >> 7;
  const int j0 = (bid & 127) * 2;
  const float* xg = dir ? xg_b : xg_f;
  const float* Whh = dir ? Whh_b : Whh_f;
  const float* bhh = dir ? bhh_b : bhh_f;
  float* hbase = hl + (size_t)dir * 2 * NB * HL;

  __shared__ __align__(16) float Wl[8][256];  // rows: gate*2+jj
#pragma unroll
  for (int it = 0; it < 2; ++it) {
    int i = threadIdx.x + it * 256;  // 512 float4 chunks
    int r = i >> 6, k4 = i & 63;
    int gate = r >> 1, j2 = r & 1;
    float4 v = *(const float4*)(Whh + (size_t)(gate * HL + j0 + j2) * HL + k4 * 4);
    *(float4*)&Wl[r][k4 * 4] = v;
  }
  __syncthreads();

  const int b = threadIdx.x & 127;
  const int jj = threadIdx.x >> 7;
  const int j = j0 + jj;
  const float bh0 = bhh[j], bh1 = bhh[HL + j], bh2 = bhh[2 * HL + j], bh3 = bhh[3 * HL + j];
  float creg = 0.f;

  for (int s = 0; s < NT; ++s) {
    const int t = dir ? (NT - 1 - s) : s;
    const long row = (long)t * NB + b;
    // xg prefetch (independent of h) -- issue before the dot loop
    float xi = xg[row * G4 + j];
    float xf = xg[row * G4 + HL + j];
    float xgg = xg[row * G4 + 2 * HL + j];
    float xo = xg[row * G4 + 3 * HL + j];

    const float* hb = hbase + (s & 1) * NB * HL + b * HL;
    float4 s0 = make_float4(0, 0, 0, 0), s1 = s0, s2 = s0, s3 = s0;
#pragma unroll 4
    for (int k4 = 0; k4 < 64; ++k4) {
      float4 hv = *(const float4*)(hb + k4 * 4);
      float4 w0 = *(const float4*)&Wl[0 + jj][k4 * 4];
      float4 w1 = *(const float4*)&Wl[2 + jj][k4 * 4];
      float4 w2 = *(const float4*)&Wl[4 + jj][k4 * 4];
      float4 w3 = *(const float4*)&Wl[6 + jj][k4 * 4];
      s0.x += hv.x * w0.x; s0.y += hv.y * w0.y; s0.z += hv.z * w0.z; s0.w += hv.w * w0.w;
      s1.x += hv.x * w1.x; s1.y += hv.y * w1.y; s1.z += hv.z * w1.z; s1.w += hv.w * w1.w;
      s2.x += hv.x * w2.x; s2.y += hv.y * w2.y; s2.z += hv.z * w2.z; s2.w += hv.w * w2.w;
      s3.x += hv.x * w3.x; s3.y += hv.y * w3.y; s3.z += hv.z * w3.z; s3.w += hv.w * w3.w;
    }
    float gi = xi + (s0.x + s0.y + s0.z + s0.w) + bh0;
    float gf = xf + (s1.x + s1.y + s1.z + s1.w) + bh1;
    float gg = xgg + (s2.x + s2.y + s2.z + s2.w) + bh2;
    float go = xo + (s3.x + s3.y + s3.z + s3.w) + bh3;
    creg = sigm(gf) * creg + sigm(gi) * tanhf(gg);
    float hn = sigm(go) * tanhf(creg);
    hbase[((s + 1) & 1) * NB * HL + b * HL + j] = hn;
    x[row * XDIM + dir * HL + j] = hn;  // fwd -> cols 0:256, bwd -> 256:512
    gbar(bar, gen, 256, s + 1);
  }
}

// ---------------------------------------------------------------------------
// persistent GRU, grid = 256 blocks x 256 thr. block: j-chunk of 2.
// ---------------------------------------------------------------------------
__global__ __launch_bounds__(256) void gru_persist_kernel(
    const float* __restrict__ xg, const float* __restrict__ Whh,
    const float* __restrict__ bhh, float* __restrict__ gh,  // [slot][NB][NC]
    float* __restrict__ gout, int* bar, int* gen) {
  const int j0 = blockIdx.x * 2;
  __shared__ __align__(16) float Wl[6][512];  // rows gate*2+jj, gates r,z,n
#pragma unroll
  for (int it = 0; it < 3; ++it) {
    int i = threadIdx.x + it * 256;  // 768 float4 chunks
    int r = i >> 7, k4 = i & 127;
    int gate = r >> 1, j2 = r & 1;
    float4 v = *(const float4*)(Whh + (size_t)(gate * NC + j0 + j2) * NC + k4 * 4);
    *(float4*)&Wl[r][k4 * 4] = v;
  }
  __syncthreads();

  const int b = threadIdx.x & 127;
  const int jj = threadIdx.x >> 7;
  const int j = j0 + jj;
  const float bh0 = bhh[j], bh1 = bhh[NC + j], bh2 = bhh[2 * NC + j];

  for (int t = 0; t < NT; ++t) {
    const long row = (long)t * NB + b;
    float xr = xg[row * G3 + j];
    float xz = xg[row * G3 + NC + j];
    float xn = xg[row * G3 + 2 * NC + j];

    const float* hb = gh + (t & 1) * NB * NC + b * NC;
    float4 s0 = make_float4(0, 0, 0, 0), s1 = s0, s2 = s0;
#pragma unroll 4
    for (int k4 = 0; k4 < 128; ++k4) {
      float4 hv = *(const float4*)(hb + k4 * 4);
      float4 w0 = *(const float4*)&Wl[0 + jj][k4 * 4];
      float4 w1 = *(const float4*)&Wl[2 + jj][k4 * 4];
      float4 w2 = *(const float4*)&Wl[4 + jj][k4 * 4];
      s0.x += hv.x * w0.x; s0.y += hv.y * w0.y; s0.z += hv.z * w0.z; s0.w += hv.w * w0.w;
      s1.x += hv.x * w1.x; s1.y += hv.y * w1.y; s1.z += hv.z * w1.z; s1.w += hv.w * w1.w;
      s2.x += hv.x * w2.x; s2.y += hv.y * w2.y; s2.z += hv.z * w2.z; s2.w += hv.w * w2.w;
    }
    float hr = (s0.x + s0.y + s0.z + s0.w) + bh0;
    float hz = (s1.x + s1.y + s1.z + s1.w) + bh1;
    float hn = (s2.x + s2.y + s2.z + s2.w) + bh2;
    float hold = hb[j];
    float r = sigm(xr + hr);
    float z = sigm(xz + hz);
    float n = tanhf(xn + r * hn);
    float hv = (1.f - z) * n + z * hold;
    gh[((t + 1) & 1) * NB * NC + b * NC + j] = hv;
    gout[row * NC + j] = hv;
    gbar(bar, gen, 256, t + 1);
  }
}

// ---------------------------------------------------------------------------
extern "C" void kernel_launch(void* const* d_in, const int* in_sizes, int n_in,
                              void* d_out, int out_size, void* d_ws, size_t ws_size,
                              hipStream_t stream) {
  const float* feature = (const float*)d_in[0];
  const float* A       = (const float*)d_in[1];
  const int*   text    = (const int*)d_in[2];
  const int*   tlen    = (const int*)d_in[3];
  const float* Wih_f   = (const float*)d_in[4];
  const float* Whh_f   = (const float*)d_in[5];
  const float* bih_f   = (const float*)d_in[6];
  const float* bhh_f   = (const float*)d_in[7];
  const float* Wih_b   = (const float*)d_in[8];
  const float* Whh_b   = (const float*)d_in[9];
  const float* bih_b   = (const float*)d_in[10];
  const float* bhh_b   = (const float*)d_in[11];
  const float* gWih    = (const float*)d_in[12];
  const float* gWhh    = (const float*)d_in[13];
  const float* gbih    = (const float*)d_in[14];
  const float* gbhh    = (const float*)d_in[15];
  const float* genW    = (const float*)d_in[16];
  const float* genb    = (const float*)d_in[17];
  const float* cemb    = (const float*)d_in[18];
  float* out = (float*)d_out;
  const int total = in_sizes[2];

  char* ws = (char*)d_ws;
  size_t off = 0;
  auto alloc = [&](size_t bytes) -> void* {
    void* p = ws + off;
    off += (bytes + 255) & ~(size_t)255;
    return p;
  };
  float* asum  = (float*)alloc((size_t)NB * NT * 4);
  int*   offs  = (int*)alloc(NB * 4);
  int*   rowmap= (int*)alloc((size_t)NB * NT * 4);
  float* Cbuf  = (float*)alloc((size_t)NT * NB * NC * 4);   // phase1: C; phase2: gru_out
  float* xgf   = (float*)alloc((size_t)NT * NB * G4 * 4);   // } reused as gru xg
  float* xgb   = (float*)alloc((size_t)NT * NB * G4 * 4);   // } (gxg 31.5MB spills into dead xgb)
  float* xbuf  = (float*)alloc((size_t)NT * NB * XDIM * 4);
  float* hlstm = (float*)alloc((size_t)2 * 2 * NB * HL * 4);  // [dir][slot][b][j]
  float* gh    = (float*)alloc((size_t)2 * NB * NC * 4);      // [slot][b][j]
  int*   bars  = (int*)alloc(256);                            // {bar_l, gen_l, bar_g, gen_g}
  float* gxg   = xgf;
  float* gout  = Cbuf;

  // --- setup ---
  offsets_kernel<<<1, 64, 0, stream>>>(tlen, offs);
  rowmap_kernel<<<NB, 64, 0, stream>>>(tlen, offs, rowmap);
  {
    int zn = (int)((((char*)bars + 256) - (char*)hlstm) / 4);  // states + barriers
    zero_kernel<<<(zn + 255) / 256, 256, 0, stream>>>(hlstm, zn);
  }
  asum_kernel<<<NB * NT, 64, 0, stream>>>(A, asum);

  // --- attention pooling: per-b GEMM, M=c(512), N=t(40), K=hw(512) ---
  sgemm_kernel<<<dim3(1, 4, NB), 256, 0, stream>>>(
      NC, NT, HW,
      feature, HW, (long)NC * HW, nullptr,
      A, HW, (long)NT * HW,
      asum, NT,
      nullptr,
      Cbuf, 1L, (long)NB * NC, (long)NC);

  // --- LSTM input projections ---
  sgemm_kernel<<<dim3(G4 / 128, (NT * NB) / 128, 1), 256, 0, stream>>>(
      NT * NB, G4, NC, Cbuf, NC, 0, nullptr, Wih_f, NC, 0, nullptr, 0, bih_f,
      xgf, (long)G4, 1L, 0);
  sgemm_kernel<<<dim3(G4 / 128, (NT * NB) / 128, 1), 256, 0, stream>>>(
      NT * NB, G4, NC, Cbuf, NC, 0, nullptr, Wih_b, NC, 0, nullptr, 0, bih_b,
      xgb, (long)G4, 1L, 0);

  // --- LSTM recurrence: ONE persistent kernel, 40 grid barriers ---
  lstm_persist_kernel<<<256, 256, 0, stream>>>(
      xgf, xgb, Whh_f, Whh_b, bhh_f, bhh_b, hlstm, xbuf, bars + 0, bars + 1);

  // --- embedding into x[:,:,512:1024] ---
  emb_kernel<<<NT * NB, 128, 0, stream>>>(cemb, text, tlen, offs, xbuf);

  // --- GRU input projection ---
  sgemm_kernel<<<dim3(G3 / 128, (NT * NB) / 128, 1), 256, 0, stream>>>(
      NT * NB, G3, XDIM, xbuf, XDIM, 0, nullptr, gWih, XDIM, 0, nullptr, 0, gbih,
      gxg, (long)G3, 1L, 0);

  // --- GRU recurrence: ONE persistent kernel ---
  gru_persist_kernel<<<256, 256, 0, stream>>>(
      gxg, gWhh, gbhh, gh, gout, bars + 2, bars + 3);

  // --- vocab projection, ragged-gathered rows straight into d_out ---
  sgemm_kernel<<<dim3((NG + 127) / 128, (total + 127) / 128, 1), 256, 0, stream>>>(
      total, NG, NC, gout, NC, 0, rowmap, genW, NC, 0, nullptr, 0, genb,
      out, (long)NG, 1L, 0);
}

// Round 3
// 2997.232 us; speedup vs baseline: 1.3684x; 1.3684x over previous
//
#include <hip/hip_runtime.h>
#include <hip/hip_bf16.h>
#include <math.h>

#define NB 128     // batch
#define NC 512     // channels
#define NT 40      // time steps
#define HW 512     // nH*nW
#define HL 256     // LSTM hidden per direction
#define NG 5000    // nclass
#define XDIM 1024  // 2*NC (GRU input)
#define G4 1024    // 4*HL
#define G3 1536    // 3*NC

// ---------------------------------------------------------------------------
// small setup kernels
// ---------------------------------------------------------------------------
__global__ void offsets_kernel(const int* __restrict__ tl, int* __restrict__ offs) {
  if (threadIdx.x == 0) {
    int o = 0;
    for (int b = 0; b < NB; ++b) { offs[b] = o; o += tl[b]; }
  }
}

__global__ void rowmap_kernel(const int* __restrict__ tl, const int* __restrict__ offs,
                              int* __restrict__ rowmap) {
  int b = blockIdx.x;
  int len = tl[b], off = offs[b];
  for (int t = threadIdx.x; t < len; t += blockDim.x)
    rowmap[off + t] = t * NB + b;   // row index into [t][b][*] matrices
}

__global__ void zero_kernel(float* __restrict__ p, int n) {
  int i = blockIdx.x * 256 + threadIdx.x;
  if (i < n) p[i] = 0.f;
}

// 1/sum over HW per (b,t)
__global__ __launch_bounds__(64) void asum_kernel(const float* __restrict__ A,
                                                  float* __restrict__ out) {
  int row = blockIdx.x;  // b*NT + t
  const float* p = A + (size_t)row * HW;
  float s = 0.f;
#pragma unroll
  for (int i = 0; i < 8; ++i) s += p[threadIdx.x + i * 64];
#pragma unroll
  for (int off = 32; off > 0; off >>= 1) s += __shfl_down(s, off);
  if (threadIdx.x == 0) out[row] = 1.0f / s;
}

// teacher-forcing embedding into x[:,:,512:1024]
__global__ __launch_bounds__(128) void emb_kernel(const float* __restrict__ ce,
                                                  const int* __restrict__ text,
                                                  const int* __restrict__ tl,
                                                  const int* __restrict__ offs,
                                                  float* __restrict__ x) {
  int bid = blockIdx.x;  // t*NB + b
  int t = bid >> 7, b = bid & 127;
  int tok = 0;
  if (t >= 2) {
    int p = t - 2;
    if (p < tl[b]) tok = text[offs[b] + p] + 1;
  }
  float4 v = *(const float4*)(ce + (size_t)tok * NC + threadIdx.x * 4);
  *(float4*)(x + (size_t)bid * XDIM + NC + threadIdx.x * 4) = v;
}

// ---------------------------------------------------------------------------
// generic f32 SGEMM: out[m][n] = sum_k Arow(m)[k] * B[n][k] * (bscale?bscale[n]:1)
//                    + (bias?bias[n]:0)
// A rows optionally gathered through rowmap. Batched via blockIdx.z strides.
// 128x128 tile, 256 threads, 8x8 per thread, BK=16, register-prefetch dbuf.
// B-fragment split (c0, c0+64) => 2-way LDS aliasing only (free).
// ---------------------------------------------------------------------------
__global__ __launch_bounds__(256) void sgemm_kernel(
    int M, int N, int K,
    const float* __restrict__ A, int lda, long Abstride,
    const int* __restrict__ rowmap,
    const float* __restrict__ B, int ldb, long Bbstride,
    const float* __restrict__ bscale, int bscaleBstride,
    const float* __restrict__ bias,
    float* __restrict__ out, long ldoM, long ldoN, long Obstride) {
  const int batch = blockIdx.z;
  A += (long)batch * Abstride;
  B += (long)batch * Bbstride;
  out += (long)batch * Obstride;
  const float* bsc = bscale ? bscale + (long)batch * bscaleBstride : nullptr;

  __shared__ __align__(16) float As[16][132];  // [k][m]
  __shared__ __align__(16) float Bs[16][132];  // [k][n]

  const int m0 = blockIdx.y * 128, n0 = blockIdx.x * 128;
  const int tid = threadIdx.x;
  const int tm = tid >> 4, tn = tid & 15;
  const int r0 = tm * 8, c0 = tn * 4;   // B frag split: cols c0..c0+3, c0+64..c0+67
  float acc[8][8] = {};
  float4 pa[2], pb[2];

  auto fetch = [&](int k0) {
#pragma unroll
    for (int it = 0; it < 2; ++it) {
      int ch = tid + it * 256;  // (row, kq) chunks
      int mm = ch >> 2;
      int kq = (ch & 3) << 2;
      int gm = m0 + mm;
      float4 v = make_float4(0.f, 0.f, 0.f, 0.f);
      if (gm < M) {
        long ar = rowmap ? (long)rowmap[gm] : (long)gm;
        v = *(const float4*)(A + ar * lda + k0 + kq);
      }
      pa[it] = v;
      int gn = n0 + mm;
      v = make_float4(0.f, 0.f, 0.f, 0.f);
      if (gn < N) {
        v = *(const float4*)(B + (long)gn * ldb + k0 + kq);
        if (bsc) { float s = bsc[gn]; v.x *= s; v.y *= s; v.z *= s; v.w *= s; }
      }
      pb[it] = v;
    }
  };

  auto store_lds = [&]() {
#pragma unroll
    for (int it = 0; it < 2; ++it) {
      int ch = tid + it * 256;
      int mm = ch >> 2;
      int kq = (ch & 3) << 2;
      As[kq + 0][mm] = pa[it].x; As[kq + 1][mm] = pa[it].y;
      As[kq + 2][mm] = pa[it].z; As[kq + 3][mm] = pa[it].w;
      Bs[kq + 0][mm] = pb[it].x; Bs[kq + 1][mm] = pb[it].y;
      Bs[kq + 2][mm] = pb[it].z; Bs[kq + 3][mm] = pb[it].w;
    }
  };

  fetch(0);
  for (int k0 = 0; k0 < K; k0 += 16) {
    store_lds();
    __syncthreads();
    if (k0 + 16 < K) fetch(k0 + 16);  // overlap next-tile global latency w/ compute
#pragma unroll
    for (int kk = 0; kk < 16; ++kk) {
      float a[8], bb[8];
      *(float4*)&a[0] = *(const float4*)&As[kk][r0];
      *(float4*)&a[4] = *(const float4*)&As[kk][r0 + 4];
      *(float4*)&bb[0] = *(const float4*)&Bs[kk][c0];
      *(float4*)&bb[4] = *(const float4*)&Bs[kk][c0 + 64];
#pragma unroll
      for (int i = 0; i < 8; ++i)
#pragma unroll
        for (int j = 0; j < 8; ++j) acc[i][j] += a[i] * bb[j];
    }
    __syncthreads();
  }
#pragma unroll
  for (int i = 0; i < 8; ++i) {
    int gm = m0 + r0 + i;
    if (gm >= M) continue;
#pragma unroll
    for (int j = 0; j < 8; ++j) {
      int gn = n0 + c0 + (j & 3) + ((j >> 2) << 6);
      if (gn >= N) continue;
      float v = acc[i][j];
      if (bias) v += bias[gn];
      out[(long)gm * ldoM + (long)gn * ldoN] = v;
    }
  }
}

// ---------------------------------------------------------------------------
// LSTM step v3 (both directions in one launch).
// grid = 128 blocks (dir = bid>>6, j-chunk of 4), 512 threads = (b, jq).
// Each thread: 4 gate dots of K=256 for its (b, j); W rows in LDS (broadcast
// reads); h row streamed float4 (L1/L2-shared); coalesced-in-traffic accesses.
// ---------------------------------------------------------------------------
__device__ __forceinline__ float sigm(float x) { return 1.f / (1.f + expf(-x)); }

__global__ __launch_bounds__(512) void lstm_step_kernel(
    const float* __restrict__ xg_f, const float* __restrict__ xg_b,
    const float* __restrict__ Whh_f, const float* __restrict__ Whh_b,
    const float* __restrict__ bhh_f, const float* __restrict__ bhh_b,
    const float* __restrict__ hprev_f, float* __restrict__ hnew_f, float* __restrict__ c_f,
    const float* __restrict__ hprev_b, float* __restrict__ hnew_b, float* __restrict__ c_b,
    float* __restrict__ x, int step) {
  const int dir = blockIdx.x >> 6;
  const int j0 = (blockIdx.x & 63) * 4;
  const int t = dir ? (NT - 1 - step) : step;
  const float* xg = dir ? xg_b : xg_f;
  const float* Whh = dir ? Whh_b : Whh_f;
  const float* bhh = dir ? bhh_b : bhh_f;
  const float* hprev = dir ? hprev_b : hprev_f;
  float* hnew = dir ? hnew_b : hnew_f;
  float* cst = dir ? c_b : c_f;

  __shared__ __align__(16) float Wl[16][HL];  // rows: gate*4 + jq
#pragma unroll
  for (int it = 0; it < 2; ++it) {
    int i = threadIdx.x + it * 512;  // 1024 float4 chunks
    int r = i >> 6, k4 = i & 63;
    int gate = r >> 2, jq = r & 3;
    float4 v = *(const float4*)(Whh + (size_t)(gate * HL + j0 + jq) * HL + k4 * 4);
    *(float4*)&Wl[r][k4 * 4] = v;
  }
  __syncthreads();

  const int b = threadIdx.x & 127;
  const int jq = threadIdx.x >> 7;
  const int j = j0 + jq;
  const long row = (long)t * NB + b;

  // xg loads (independent of h) issued early
  float xi = xg[row * G4 + 0 * HL + j];
  float xf = xg[row * G4 + 1 * HL + j];
  float xgg = xg[row * G4 + 2 * HL + j];
  float xo = xg[row * G4 + 3 * HL + j];
  float cold = cst[b * HL + j];

  const float* hb = hprev + b * HL;
  float4 s0 = make_float4(0, 0, 0, 0), s1 = s0, s2 = s0, s3 = s0;
#pragma unroll 4
  for (int k4 = 0; k4 < 64; ++k4) {
    float4 hv = *(const float4*)(hb + k4 * 4);
    float4 w0 = *(const float4*)&Wl[0 + jq][k4 * 4];
    float4 w1 = *(const float4*)&Wl[4 + jq][k4 * 4];
    float4 w2 = *(const float4*)&Wl[8 + jq][k4 * 4];
    float4 w3 = *(const float4*)&Wl[12 + jq][k4 * 4];
    s0.x += hv.x * w0.x; s0.y += hv.y * w0.y; s0.z += hv.z * w0.z; s0.w += hv.w * w0.w;
    s1.x += hv.x * w1.x; s1.y += hv.y * w1.y; s1.z += hv.z * w1.z; s1.w += hv.w * w1.w;
    s2.x += hv.x * w2.x; s2.y += hv.y * w2.y; s2.z += hv.z * w2.z; s2.w += hv.w * w2.w;
    s3.x += hv.x * w3.x; s3.y += hv.y * w3.y; s3.z += hv.z * w3.z; s3.w += hv.w * w3.w;
  }
  float gi = xi + (s0.x + s0.y + s0.z + s0.w) + bhh[0 * HL + j];
  float gf = xf + (s1.x + s1.y + s1.z + s1.w) + bhh[1 * HL + j];
  float gg = xgg + (s2.x + s2.y + s2.z + s2.w) + bhh[2 * HL + j];
  float go = xo + (s3.x + s3.y + s3.z + s3.w) + bhh[3 * HL + j];
  float cn = sigm(gf) * cold + sigm(gi) * tanhf(gg);
  cst[b * HL + j] = cn;
  float hn = sigm(go) * tanhf(cn);
  hnew[b * HL + j] = hn;
  x[row * XDIM + dir * HL + j] = hn;  // fwd -> cols 0:256, bwd -> 256:512
}

// ---------------------------------------------------------------------------
// GRU step v3. grid = 128 blocks (j-chunk of 4), 512 threads = (b, jq).
// ---------------------------------------------------------------------------
__global__ __launch_bounds__(512) void gru_step_kernel(
    const float* __restrict__ xg, const float* __restrict__ Whh,
    const float* __restrict__ bhh, const float* __restrict__ hprev,
    float* __restrict__ hnew, float* __restrict__ gout, int t) {
  const int j0 = blockIdx.x * 4;
  __shared__ __align__(16) float Wl[12][NC];  // rows: gate*4 + jq
#pragma unroll
  for (int it = 0; it < 3; ++it) {
    int i = threadIdx.x + it * 512;  // 1536 float4 chunks
    int r = i >> 7, k4 = i & 127;
    int gate = r >> 2, jq = r & 3;
    float4 v = *(const float4*)(Whh + (size_t)(gate * NC + j0 + jq) * NC + k4 * 4);
    *(float4*)&Wl[r][k4 * 4] = v;
  }
  __syncthreads();

  const int b = threadIdx.x & 127;
  const int jq = threadIdx.x >> 7;
  const int j = j0 + jq;
  const long row = (long)t * NB + b;

  float xr = xg[row * G3 + 0 * NC + j];
  float xz = xg[row * G3 + 1 * NC + j];
  float xn = xg[row * G3 + 2 * NC + j];
  float hold = hprev[b * NC + j];

  const float* hb = hprev + b * NC;
  float4 s0 = make_float4(0, 0, 0, 0), s1 = s0, s2 = s0;
#pragma unroll 4
  for (int k4 = 0; k4 < 128; ++k4) {
    float4 hv = *(const float4*)(hb + k4 * 4);
    float4 w0 = *(const float4*)&Wl[0 + jq][k4 * 4];
    float4 w1 = *(const float4*)&Wl[4 + jq][k4 * 4];
    float4 w2 = *(const float4*)&Wl[8 + jq][k4 * 4];
    s0.x += hv.x * w0.x; s0.y += hv.y * w0.y; s0.z += hv.z * w0.z; s0.w += hv.w * w0.w;
    s1.x += hv.x * w1.x; s1.y += hv.y * w1.y; s1.z += hv.z * w1.z; s1.w += hv.w * w1.w;
    s2.x += hv.x * w2.x; s2.y += hv.y * w2.y; s2.z += hv.z * w2.z; s2.w += hv.w * w2.w;
  }
  float hr = (s0.x + s0.y + s0.z + s0.w) + bhh[0 * NC + j];
  float hz = (s1.x + s1.y + s1.z + s1.w) + bhh[1 * NC + j];
  float hn = (s2.x + s2.y + s2.z + s2.w) + bhh[2 * NC + j];
  float r = sigm(xr + hr);
  float z = sigm(xz + hz);
  float n = tanhf(xn + r * hn);
  float hv = (1.f - z) * n + z * hold;
  hnew[b * NC + j] = hv;
  gout[row * NC + j] = hv;
}

// ---------------------------------------------------------------------------
extern "C" void kernel_launch(void* const* d_in, const int* in_sizes, int n_in,
                              void* d_out, int out_size, void* d_ws, size_t ws_size,
                              hipStream_t stream) {
  const float* feature = (const float*)d_in[0];
  const float* A       = (const float*)d_in[1];
  const int*   text    = (const int*)d_in[2];
  const int*   tlen    = (const int*)d_in[3];
  const float* Wih_f   = (const float*)d_in[4];
  const float* Whh_f   = (const float*)d_in[5];
  const float* bih_f   = (const float*)d_in[6];
  const float* bhh_f   = (const float*)d_in[7];
  const float* Wih_b   = (const float*)d_in[8];
  const float* Whh_b   = (const float*)d_in[9];
  const float* bih_b   = (const float*)d_in[10];
  const float* bhh_b   = (const float*)d_in[11];
  const float* gWih    = (const float*)d_in[12];
  const float* gWhh    = (const float*)d_in[13];
  const float* gbih    = (const float*)d_in[14];
  const float* gbhh    = (const float*)d_in[15];
  const float* genW    = (const float*)d_in[16];
  const float* genb    = (const float*)d_in[17];
  const float* cemb    = (const float*)d_in[18];
  float* out = (float*)d_out;
  const int total = in_sizes[2];

  char* ws = (char*)d_ws;
  size_t off = 0;
  auto alloc = [&](size_t bytes) -> void* {
    void* p = ws + off;
    off += (bytes + 255) & ~(size_t)255;
    return p;
  };
  float* asum  = (float*)alloc((size_t)NB * NT * 4);
  int*   offs  = (int*)alloc(NB * 4);
  int*   rowmap= (int*)alloc((size_t)NB * NT * 4);
  float* Cbuf  = (float*)alloc((size_t)NT * NB * NC * 4);   // phase1: C; phase2: gru_out
  float* xgf   = (float*)alloc((size_t)NT * NB * G4 * 4);   // } reused as gru xg
  float* xgb   = (float*)alloc((size_t)NT * NB * G4 * 4);   // } (gxg 31.5MB spills into dead xgb)
  float* xbuf  = (float*)alloc((size_t)NT * NB * XDIM * 4);
  float* hf    = (float*)alloc((size_t)2 * NB * HL * 4);
  float* cf    = (float*)alloc((size_t)NB * HL * 4);
  float* hb    = (float*)alloc((size_t)2 * NB * HL * 4);
  float* cb    = (float*)alloc((size_t)NB * HL * 4);
  float* gh    = (float*)alloc((size_t)2 * NB * NC * 4);
  float* gxg   = xgf;
  float* gout  = Cbuf;

  // --- setup ---
  offsets_kernel<<<1, 64, 0, stream>>>(tlen, offs);
  rowmap_kernel<<<NB, 64, 0, stream>>>(tlen, offs, rowmap);
  {
    int zn = (int)((((char*)gh + 2 * NB * NC * 4) - (char*)hf) / 4);  // all states
    zero_kernel<<<(zn + 255) / 256, 256, 0, stream>>>(hf, zn);
  }
  asum_kernel<<<NB * NT, 64, 0, stream>>>(A, asum);

  // --- attention pooling: per-b GEMM, M=c(512), N=t(40), K=hw(512) ---
  sgemm_kernel<<<dim3(1, 4, NB), 256, 0, stream>>>(
      NC, NT, HW,
      feature, HW, (long)NC * HW, nullptr,
      A, HW, (long)NT * HW,
      asum, NT,
      nullptr,
      Cbuf, 1L, (long)NB * NC, (long)NC);

  // --- LSTM input projections ---
  sgemm_kernel<<<dim3(G4 / 128, (NT * NB) / 128, 1), 256, 0, stream>>>(
      NT * NB, G4, NC, Cbuf, NC, 0, nullptr, Wih_f, NC, 0, nullptr, 0, bih_f,
      xgf, (long)G4, 1L, 0);
  sgemm_kernel<<<dim3(G4 / 128, (NT * NB) / 128, 1), 256, 0, stream>>>(
      NT * NB, G4, NC, Cbuf, NC, 0, nullptr, Wih_b, NC, 0, nullptr, 0, bih_b,
      xgb, (long)G4, 1L, 0);

  // --- LSTM recurrence (fwd+bwd fused per launch), writes x[:,:,0:512] ---
  for (int s = 0; s < NT; ++s) {
    lstm_step_kernel<<<dim3(128), 512, 0, stream>>>(
        xgf, xgb, Whh_f, Whh_b, bhh_f, bhh_b,
        hf + (s & 1) * NB * HL, hf + ((s + 1) & 1) * NB * HL, cf,
        hb + (s & 1) * NB * HL, hb + ((s + 1) & 1) * NB * HL, cb,
        xbuf, s);
  }

  // --- embedding into x[:,:,512:1024] ---
  emb_kernel<<<NT * NB, 128, 0, stream>>>(cemb, text, tlen, offs, xbuf);

  // --- GRU input projection ---
  sgemm_kernel<<<dim3(G3 / 128, (NT * NB) / 128, 1), 256, 0, stream>>>(
      NT * NB, G3, XDIM, xbuf, XDIM, 0, nullptr, gWih, XDIM, 0, nullptr, 0, gbih,
      gxg, (long)G3, 1L, 0);

  // --- GRU recurrence ---
  for (int s = 0; s < NT; ++s) {
    gru_step_kernel<<<dim3(128), 512, 0, stream>>>(
        gxg, gWhh, gbhh, gh + (s & 1) * NB * NC, gh + ((s + 1) & 1) * NB * NC,
        gout, s);
  }

  // --- vocab projection, ragged-gathered rows straight into d_out ---
  sgemm_kernel<<<dim3((NG + 127) / 128, (total + 127) / 128, 1), 256, 0, stream>>>(
      total, NG, NC, gout, NC, 0, rowmap, genW, NC, 0, nullptr, 0, genb,
      out, (long)NG, 1L, 0);
}

// Round 4
// 1736.857 us; speedup vs baseline: 2.3614x; 1.7257x over previous
//
#include <hip/hip_runtime.h>
#include <hip/hip_bf16.h>
#include <math.h>

#define NB 128     // batch
#define NC 512     // channels
#define NT 40      // time steps
#define HW 512     // nH*nW
#define HL 256     // LSTM hidden per direction
#define NG 5000    // nclass
#define XDIM 1024  // 2*NC (GRU input)
#define G4 1024    // 4*HL
#define G3 1536    // 3*NC

// ---------------------------------------------------------------------------
// small setup kernels
// ---------------------------------------------------------------------------
__global__ void offsets_kernel(const int* __restrict__ tl, int* __restrict__ offs) {
  if (threadIdx.x == 0) {
    int o = 0;
    for (int b = 0; b < NB; ++b) { offs[b] = o; o += tl[b]; }
  }
}

__global__ void rowmap_kernel(const int* __restrict__ tl, const int* __restrict__ offs,
                              int* __restrict__ rowmap) {
  int b = blockIdx.x;
  int len = tl[b], off = offs[b];
  for (int t = threadIdx.x; t < len; t += blockDim.x)
    rowmap[off + t] = t * NB + b;   // row index into [t][b][*] matrices
}

// 1/sum over HW per (b,t)
__global__ __launch_bounds__(64) void asum_kernel(const float* __restrict__ A,
                                                  float* __restrict__ out) {
  int row = blockIdx.x;  // b*NT + t
  const float* p = A + (size_t)row * HW;
  float s = 0.f;
#pragma unroll
  for (int i = 0; i < 8; ++i) s += p[threadIdx.x + i * 64];
#pragma unroll
  for (int off = 32; off > 0; off >>= 1) s += __shfl_down(s, off);
  if (threadIdx.x == 0) out[row] = 1.0f / s;
}

// teacher-forcing embedding into x[:,:,512:1024]
__global__ __launch_bounds__(128) void emb_kernel(const float* __restrict__ ce,
                                                  const int* __restrict__ text,
                                                  const int* __restrict__ tl,
                                                  const int* __restrict__ offs,
                                                  float* __restrict__ x) {
  int bid = blockIdx.x;  // t*NB + b
  int t = bid >> 7, b = bid & 127;
  int tok = 0;
  if (t >= 2) {
    int p = t - 2;
    if (p < tl[b]) tok = text[offs[b] + p] + 1;
  }
  float4 v = *(const float4*)(ce + (size_t)tok * NC + threadIdx.x * 4);
  *(float4*)(x + (size_t)bid * XDIM + NC + threadIdx.x * 4) = v;
}

// ---------------------------------------------------------------------------
// weight pack kernels: f32 [g][j][k] row-major -> bf16 k-pair [g][k2][j] (u32)
// RNE bf16 rounding.
// ---------------------------------------------------------------------------
__device__ __forceinline__ uint32_t f2bf(float f) {
  uint32_t u = __float_as_uint(f);
  return (u + 0x7fffu + ((u >> 16) & 1u)) >> 16;
}

// LSTM: rows (dir,g,j) = 2*4*256 = 2048 blocks x 64 threads; lane l -> k=4l..4l+3
__global__ __launch_bounds__(64) void lstm_pack_kernel(
    const float* __restrict__ Wf, const float* __restrict__ Wb,
    uint32_t* __restrict__ Wp) {
  int row = blockIdx.x;                 // (dir*4+g)*256 + j
  int dir = row >> 10, g = (row >> 8) & 3, j = row & 255;
  const float* W = (dir ? Wb : Wf) + ((size_t)g * HL + j) * HL;
  int l = threadIdx.x;
  float4 v = *(const float4*)(W + l * 4);
  uint32_t p0 = f2bf(v.x) | (f2bf(v.y) << 16);
  uint32_t p1 = f2bf(v.z) | (f2bf(v.w) << 16);
  size_t base = ((size_t)(dir * 4 + g) * 128) * 256;
  Wp[base + (size_t)(2 * l) * 256 + j] = p0;
  Wp[base + (size_t)(2 * l + 1) * 256 + j] = p1;
}

// GRU: rows (g,j) = 3*512 = 1536 blocks x 128 threads; lane l -> k=4l..4l+3
__global__ __launch_bounds__(128) void gru_pack_kernel(
    const float* __restrict__ W, uint32_t* __restrict__ Wp) {
  int row = blockIdx.x;                 // g*512 + j
  int g = row >> 9, j = row & 511;
  const float* Wr = W + ((size_t)g * NC + j) * NC;
  int l = threadIdx.x;
  float4 v = *(const float4*)(Wr + l * 4);
  uint32_t p0 = f2bf(v.x) | (f2bf(v.y) << 16);
  uint32_t p1 = f2bf(v.z) | (f2bf(v.w) << 16);
  size_t base = (size_t)g * 256 * 512;
  Wp[base + (size_t)(2 * l) * 512 + j] = p0;
  Wp[base + (size_t)(2 * l + 1) * 512 + j] = p1;
}

// ---------------------------------------------------------------------------
// generic f32 SGEMM (unchanged from R3): 128x128 tile, 8x8/thread, BK=16,
// register-prefetch, split B-fragment (2-way LDS aliasing only).
// ---------------------------------------------------------------------------
__global__ __launch_bounds__(256) void sgemm_kernel(
    int M, int N, int K,
    const float* __restrict__ A, int lda, long Abstride,
    const int* __restrict__ rowmap,
    const float* __restrict__ B, int ldb, long Bbstride,
    const float* __restrict__ bscale, int bscaleBstride,
    const float* __restrict__ bias,
    float* __restrict__ out, long ldoM, long ldoN, long Obstride) {
  const int batch = blockIdx.z;
  A += (long)batch * Abstride;
  B += (long)batch * Bbstride;
  out += (long)batch * Obstride;
  const float* bsc = bscale ? bscale + (long)batch * bscaleBstride : nullptr;

  __shared__ __align__(16) float As[16][132];
  __shared__ __align__(16) float Bs[16][132];

  const int m0 = blockIdx.y * 128, n0 = blockIdx.x * 128;
  const int tid = threadIdx.x;
  const int tm = tid >> 4, tn = tid & 15;
  const int r0 = tm * 8, c0 = tn * 4;
  float acc[8][8] = {};
  float4 pa[2], pb[2];

  auto fetch = [&](int k0) {
#pragma unroll
    for (int it = 0; it < 2; ++it) {
      int ch = tid + it * 256;
      int mm = ch >> 2;
      int kq = (ch & 3) << 2;
      int gm = m0 + mm;
      float4 v = make_float4(0.f, 0.f, 0.f, 0.f);
      if (gm < M) {
        long ar = rowmap ? (long)rowmap[gm] : (long)gm;
        v = *(const float4*)(A + ar * lda + k0 + kq);
      }
      pa[it] = v;
      int gn = n0 + mm;
      v = make_float4(0.f, 0.f, 0.f, 0.f);
      if (gn < N) {
        v = *(const float4*)(B + (long)gn * ldb + k0 + kq);
        if (bsc) { float s = bsc[gn]; v.x *= s; v.y *= s; v.z *= s; v.w *= s; }
      }
      pb[it] = v;
    }
  };

  auto store_lds = [&]() {
#pragma unroll
    for (int it = 0; it < 2; ++it) {
      int ch = tid + it * 256;
      int mm = ch >> 2;
      int kq = (ch & 3) << 2;
      As[kq + 0][mm] = pa[it].x; As[kq + 1][mm] = pa[it].y;
      As[kq + 2][mm] = pa[it].z; As[kq + 3][mm] = pa[it].w;
      Bs[kq + 0][mm] = pb[it].x; Bs[kq + 1][mm] = pb[it].y;
      Bs[kq + 2][mm] = pb[it].z; Bs[kq + 3][mm] = pb[it].w;
    }
  };

  fetch(0);
  for (int k0 = 0; k0 < K; k0 += 16) {
    store_lds();
    __syncthreads();
    if (k0 + 16 < K) fetch(k0 + 16);
#pragma unroll
    for (int kk = 0; kk < 16; ++kk) {
      float a[8], bb[8];
      *(float4*)&a[0] = *(const float4*)&As[kk][r0];
      *(float4*)&a[4] = *(const float4*)&As[kk][r0 + 4];
      *(float4*)&bb[0] = *(const float4*)&Bs[kk][c0];
      *(float4*)&bb[4] = *(const float4*)&Bs[kk][c0 + 64];
#pragma unroll
      for (int i = 0; i < 8; ++i)
#pragma unroll
        for (int j = 0; j < 8; ++j) acc[i][j] += a[i] * bb[j];
    }
    __syncthreads();
  }
#pragma unroll
  for (int i = 0; i < 8; ++i) {
    int gm = m0 + r0 + i;
    if (gm >= M) continue;
#pragma unroll
    for (int j = 0; j < 8; ++j) {
      int gn = n0 + c0 + (j & 3) + ((j >> 2) << 6);
      if (gn >= N) continue;
      float v = acc[i][j];
      if (bias) v += bias[gn];
      out[(long)gm * ldoM + (long)gn * ldoN] = v;
    }
  }
}

// ---------------------------------------------------------------------------
// b-split persistent recurrences: block owns (dir,b) / b, loops all T steps
// in one launch. h lives in LDS (ping-pong), c in registers. NO cross-block
// communication, NO grid sync. Weights streamed from L2 as bf16 k-pairs.
// ---------------------------------------------------------------------------
__device__ __forceinline__ float sigm(float x) { return 1.f / (1.f + expf(-x)); }
__device__ __forceinline__ float lo16(uint32_t u) { return __uint_as_float(u << 16); }
__device__ __forceinline__ float hi16(uint32_t u) { return __uint_as_float(u & 0xffff0000u); }

// grid = 256 blocks (dir = bid>>7, b = bid&127), 256 threads (thread = j)
__global__ __launch_bounds__(256) void lstm_bsplit_kernel(
    const float* __restrict__ xg_f, const float* __restrict__ xg_b,
    const uint32_t* __restrict__ Wp,
    const float* __restrict__ bhh_f, const float* __restrict__ bhh_b,
    float* __restrict__ x) {
  const int dir = blockIdx.x >> 7, b = blockIdx.x & 127;
  const float* xg = dir ? xg_b : xg_f;
  const float* bhh = dir ? bhh_b : bhh_f;
  const int j = threadIdx.x;

  __shared__ float hh[2][HL];
  hh[0][j] = 0.f;
  float c = 0.f;
  const float b0 = bhh[j], b1 = bhh[HL + j], b2 = bhh[2 * HL + j], b3 = bhh[3 * HL + j];
  const uint32_t* w0 = Wp + (size_t)dir * 4 * 128 * 256 + j;
  const uint32_t* w1 = w0 + 1 * 128 * 256;
  const uint32_t* w2 = w0 + 2 * 128 * 256;
  const uint32_t* w3 = w0 + 3 * 128 * 256;
  __syncthreads();

  for (int s = 0; s < NT; ++s) {
    const int t = dir ? (NT - 1 - s) : s;
    const long row = (long)t * NB + b;
    float xi = xg[row * G4 + j];
    float xf = xg[row * G4 + HL + j];
    float xgg = xg[row * G4 + 2 * HL + j];
    float xo = xg[row * G4 + 3 * HL + j];
    const int p = s & 1;
    float a0 = 0.f, a1 = 0.f, a2 = 0.f, a3 = 0.f;
#pragma unroll 8
    for (int k2 = 0; k2 < 128; ++k2) {
      float2 hp = *(const float2*)&hh[p][2 * k2];   // broadcast (uniform addr)
      uint32_t u0 = w0[(size_t)k2 * 256];
      uint32_t u1 = w1[(size_t)k2 * 256];
      uint32_t u2 = w2[(size_t)k2 * 256];
      uint32_t u3 = w3[(size_t)k2 * 256];
      a0 += lo16(u0) * hp.x + hi16(u0) * hp.y;
      a1 += lo16(u1) * hp.x + hi16(u1) * hp.y;
      a2 += lo16(u2) * hp.x + hi16(u2) * hp.y;
      a3 += lo16(u3) * hp.x + hi16(u3) * hp.y;
    }
    float gi = xi + a0 + b0;
    float gf = xf + a1 + b1;
    float gg = xgg + a2 + b2;
    float go = xo + a3 + b3;
    c = sigm(gf) * c + sigm(gi) * tanhf(gg);
    float hn = sigm(go) * tanhf(c);
    x[row * XDIM + dir * HL + j] = hn;   // fwd -> cols 0:256, bwd -> 256:512
    hh[p ^ 1][j] = hn;
    __syncthreads();
  }
}

// grid = 128 blocks (b), 512 threads (thread = j)
__global__ __launch_bounds__(512) void gru_bsplit_kernel(
    const float* __restrict__ xg, const uint32_t* __restrict__ Wp,
    const float* __restrict__ bhh, float* __restrict__ gout) {
  const int b = blockIdx.x;
  const int j = threadIdx.x;

  __shared__ float hh[2][NC];
  hh[0][j] = 0.f;
  const float b0 = bhh[j], b1 = bhh[NC + j], b2 = bhh[2 * NC + j];
  const uint32_t* wr = Wp + j;
  const uint32_t* wz = Wp + 1 * 256 * 512 + j;
  const uint32_t* wn = Wp + 2 * 256 * 512 + j;
  __syncthreads();

  for (int t = 0; t < NT; ++t) {
    const long row = (long)t * NB + b;
    float xr = xg[row * G3 + j];
    float xz = xg[row * G3 + NC + j];
    float xn = xg[row * G3 + 2 * NC + j];
    const int p = t & 1;
    float ar = 0.f, az = 0.f, an = 0.f;
#pragma unroll 8
    for (int k2 = 0; k2 < 256; ++k2) {
      float2 hp = *(const float2*)&hh[p][2 * k2];   // broadcast
      uint32_t ur = wr[(size_t)k2 * 512];
      uint32_t uz = wz[(size_t)k2 * 512];
      uint32_t un = wn[(size_t)k2 * 512];
      ar += lo16(ur) * hp.x + hi16(ur) * hp.y;
      az += lo16(uz) * hp.x + hi16(uz) * hp.y;
      an += lo16(un) * hp.x + hi16(un) * hp.y;
    }
    float r = sigm(xr + ar + b0);
    float z = sigm(xz + az + b1);
    float n = tanhf(xn + r * (an + b2));
    float hold = hh[p][j];
    float h = (1.f - z) * n + z * hold;
    gout[row * NC + j] = h;
    hh[p ^ 1][j] = h;
    __syncthreads();
  }
}

// ---------------------------------------------------------------------------
extern "C" void kernel_launch(void* const* d_in, const int* in_sizes, int n_in,
                              void* d_out, int out_size, void* d_ws, size_t ws_size,
                              hipStream_t stream) {
  const float* feature = (const float*)d_in[0];
  const float* A       = (const float*)d_in[1];
  const int*   text    = (const int*)d_in[2];
  const int*   tlen    = (const int*)d_in[3];
  const float* Wih_f   = (const float*)d_in[4];
  const float* Whh_f   = (const float*)d_in[5];
  const float* bih_f   = (const float*)d_in[6];
  const float* bhh_f   = (const float*)d_in[7];
  const float* Wih_b   = (const float*)d_in[8];
  const float* Whh_b   = (const float*)d_in[9];
  const float* bih_b   = (const float*)d_in[10];
  const float* bhh_b   = (const float*)d_in[11];
  const float* gWih    = (const float*)d_in[12];
  const float* gWhh    = (const float*)d_in[13];
  const float* gbih    = (const float*)d_in[14];
  const float* gbhh    = (const float*)d_in[15];
  const float* genW    = (const float*)d_in[16];
  const float* genb    = (const float*)d_in[17];
  const float* cemb    = (const float*)d_in[18];
  float* out = (float*)d_out;
  const int total = in_sizes[2];

  char* ws = (char*)d_ws;
  size_t off = 0;
  auto alloc = [&](size_t bytes) -> void* {
    void* p = ws + off;
    off += (bytes + 255) & ~(size_t)255;
    return p;
  };
  float*    asum  = (float*)alloc((size_t)NB * NT * 4);
  int*      offs  = (int*)alloc(NB * 4);
  int*      rowmap= (int*)alloc((size_t)NB * NT * 4);
  float*    Cbuf  = (float*)alloc((size_t)NT * NB * NC * 4);   // phase1: C; phase2: gru_out
  float*    xgf   = (float*)alloc((size_t)NT * NB * G4 * 4);   // } reused as gru xg
  float*    xgb   = (float*)alloc((size_t)NT * NB * G4 * 4);   // } (gxg 31.5MB spills into dead xgb)
  float*    xbuf  = (float*)alloc((size_t)NT * NB * XDIM * 4);
  uint32_t* WpL   = (uint32_t*)alloc((size_t)2 * 4 * 128 * 256 * 4);  // 1 MB
  uint32_t* WpG   = (uint32_t*)alloc((size_t)3 * 256 * 512 * 4);      // 1.5 MB
  float*    gxg   = xgf;
  float*    gout  = Cbuf;

  // --- setup + weight packing (independent of GEMMs) ---
  offsets_kernel<<<1, 64, 0, stream>>>(tlen, offs);
  rowmap_kernel<<<NB, 64, 0, stream>>>(tlen, offs, rowmap);
  asum_kernel<<<NB * NT, 64, 0, stream>>>(A, asum);
  lstm_pack_kernel<<<2048, 64, 0, stream>>>(Whh_f, Whh_b, WpL);
  gru_pack_kernel<<<1536, 128, 0, stream>>>(gWhh, WpG);

  // --- attention pooling: per-b GEMM, M=c(512), N=t(40), K=hw(512) ---
  sgemm_kernel<<<dim3(1, 4, NB), 256, 0, stream>>>(
      NC, NT, HW,
      feature, HW, (long)NC * HW, nullptr,
      A, HW, (long)NT * HW,
      asum, NT,
      nullptr,
      Cbuf, 1L, (long)NB * NC, (long)NC);

  // --- LSTM input projections ---
  sgemm_kernel<<<dim3(G4 / 128, (NT * NB) / 128, 1), 256, 0, stream>>>(
      NT * NB, G4, NC, Cbuf, NC, 0, nullptr, Wih_f, NC, 0, nullptr, 0, bih_f,
      xgf, (long)G4, 1L, 0);
  sgemm_kernel<<<dim3(G4 / 128, (NT * NB) / 128, 1), 256, 0, stream>>>(
      NT * NB, G4, NC, Cbuf, NC, 0, nullptr, Wih_b, NC, 0, nullptr, 0, bih_b,
      xgb, (long)G4, 1L, 0);

  // --- LSTM recurrence: ONE launch, no grid sync (batch-parallel blocks) ---
  lstm_bsplit_kernel<<<256, 256, 0, stream>>>(
      xgf, xgb, WpL, bhh_f, bhh_b, xbuf);

  // --- embedding into x[:,:,512:1024] ---
  emb_kernel<<<NT * NB, 128, 0, stream>>>(cemb, text, tlen, offs, xbuf);

  // --- GRU input projection ---
  sgemm_kernel<<<dim3(G3 / 128, (NT * NB) / 128, 1), 256, 0, stream>>>(
      NT * NB, G3, XDIM, xbuf, XDIM, 0, nullptr, gWih, XDIM, 0, nullptr, 0, gbih,
      gxg, (long)G3, 1L, 0);

  // --- GRU recurrence: ONE launch, no grid sync ---
  gru_bsplit_kernel<<<128, 512, 0, stream>>>(gxg, WpG, gbhh, gout);

  // --- vocab projection, ragged-gathered rows straight into d_out ---
  sgemm_kernel<<<dim3((NG + 127) / 128, (total + 127) / 128, 1), 256, 0, stream>>>(
      total, NG, NC, gout, NC, 0, rowmap, genW, NC, 0, nullptr, 0, genb,
      out, (long)NG, 1L, 0);
}

// Round 6
// 1453.547 us; speedup vs baseline: 2.8217x; 1.1949x over previous
//
#include <hip/hip_runtime.h>
#include <hip/hip_bf16.h>
#include <hip/hip_fp16.h>
#include <math.h>

#define NB 128     // batch
#define NC 512     // channels
#define NT 40      // time steps
#define HW 512     // nH*nW
#define HL 256     // LSTM hidden per direction
#define NG 5000    // nclass
#define XDIM 1024  // 2*NC (GRU input)
#define G4 1024    // 4*HL
#define G3 1536    // 3*NC

typedef _Float16 half2v __attribute__((ext_vector_type(2)));

__device__ __forceinline__ float dot2(uint32_t w, uint32_t h, float acc) {
#if __has_builtin(__builtin_amdgcn_fdot2)
  return __builtin_amdgcn_fdot2(__builtin_bit_cast(half2v, w),
                                __builtin_bit_cast(half2v, h), acc, false);
#else
  half2v wv = __builtin_bit_cast(half2v, w), hv = __builtin_bit_cast(half2v, h);
  return acc + (float)wv.x * (float)hv.x + (float)wv.y * (float)hv.y;
#endif
}

__device__ __forceinline__ float sigm(float x) { return 1.f / (1.f + expf(-x)); }
// f32 -> f16 bits (clang native _Float16 conversion, RNE)
__device__ __forceinline__ ushort f2hs(float f) {
  _Float16 h = (_Float16)f;
  return __builtin_bit_cast(ushort, h);
}
__device__ __forceinline__ uint32_t f2h(float f) { return (uint32_t)f2hs(f); }

// ---------------------------------------------------------------------------
// small setup kernels
// ---------------------------------------------------------------------------
__global__ void offsets_kernel(const int* __restrict__ tl, int* __restrict__ offs) {
  if (threadIdx.x == 0) {
    int o = 0;
    for (int b = 0; b < NB; ++b) { offs[b] = o; o += tl[b]; }
  }
}

__global__ void rowmap_kernel(const int* __restrict__ tl, const int* __restrict__ offs,
                              int* __restrict__ rowmap) {
  int b = blockIdx.x;
  int len = tl[b], off = offs[b];
  for (int t = threadIdx.x; t < len; t += blockDim.x)
    rowmap[off + t] = t * NB + b;   // row index into [t][b][*] matrices
}

// 1/sum over HW per (b,t)
__global__ __launch_bounds__(64) void asum_kernel(const float* __restrict__ A,
                                                  float* __restrict__ out) {
  int row = blockIdx.x;  // b*NT + t
  const float* p = A + (size_t)row * HW;
  float s = 0.f;
#pragma unroll
  for (int i = 0; i < 8; ++i) s += p[threadIdx.x + i * 64];
#pragma unroll
  for (int off = 32; off > 0; off >>= 1) s += __shfl_down(s, off);
  if (threadIdx.x == 0) out[row] = 1.0f / s;
}

// teacher-forcing embedding into x[:,:,512:1024]
__global__ __launch_bounds__(128) void emb_kernel(const float* __restrict__ ce,
                                                  const int* __restrict__ text,
                                                  const int* __restrict__ tl,
                                                  const int* __restrict__ offs,
                                                  float* __restrict__ x) {
  int bid = blockIdx.x;  // t*NB + b
  int t = bid >> 7, b = bid & 127;
  int tok = 0;
  if (t >= 2) {
    int p = t - 2;
    if (p < tl[b]) tok = text[offs[b] + p] + 1;
  }
  float4 v = *(const float4*)(ce + (size_t)tok * NC + threadIdx.x * 4);
  *(float4*)(x + (size_t)bid * XDIM + NC + threadIdx.x * 4) = v;
}

// ---------------------------------------------------------------------------
// weight pack: f32 [g][j][k] -> f16 k-pair layout [g][k2g][j][q] (u32, q=k2&3)
// ---------------------------------------------------------------------------
// LSTM: 2048 blocks = (dir,g,j), 64 threads; thread l -> k = 4l..4l+3
__global__ __launch_bounds__(64) void lstm_pack_kernel(
    const float* __restrict__ Wf, const float* __restrict__ Wb,
    uint32_t* __restrict__ Wp) {
  int row = blockIdx.x;                 // (dir*4+g)*256 + j
  int dg = row >> 8, j = row & 255;     // dg = dir*4+g
  int dir = dg >> 2;
  const float* W = (dir ? Wb : Wf) + ((size_t)(dg & 3) * HL + j) * HL;
  int l = threadIdx.x;
  float4 v = *(const float4*)(W + l * 4);
  uint32_t p0 = f2h(v.x) | (f2h(v.y) << 16);   // k2 = 2l
  uint32_t p1 = f2h(v.z) | (f2h(v.w) << 16);   // k2 = 2l+1
  int k2g = l >> 1, q0 = (2 * l) & 3;
  size_t base = ((size_t)dg * 32 + k2g) * 1024 + j * 4;
  Wp[base + q0] = p0;
  Wp[base + q0 + 1] = p1;
}

// GRU: 1536 blocks = (g,j), 128 threads; thread l -> k = 4l..4l+3
__global__ __launch_bounds__(128) void gru_pack_kernel(
    const float* __restrict__ W, uint32_t* __restrict__ Wp) {
  int row = blockIdx.x;                 // g*512 + j
  int g = row >> 9, j = row & 511;
  const float* Wr = W + ((size_t)g * NC + j) * NC;
  int l = threadIdx.x;
  float4 v = *(const float4*)(Wr + l * 4);
  uint32_t p0 = f2h(v.x) | (f2h(v.y) << 16);
  uint32_t p1 = f2h(v.z) | (f2h(v.w) << 16);
  int k2g = l >> 1, q0 = (2 * l) & 3;
  size_t base = ((size_t)g * 64 + k2g) * 2048 + j * 4;
  Wp[base + q0] = p0;
  Wp[base + q0 + 1] = p1;
}

// ---------------------------------------------------------------------------
// generic f32 SGEMM (unchanged): 128x128 tile, 8x8/thread, BK=16,
// register-prefetch, split B-fragment (2-way LDS aliasing only).
// ---------------------------------------------------------------------------
__global__ __launch_bounds__(256) void sgemm_kernel(
    int M, int N, int K,
    const float* __restrict__ A, int lda, long Abstride,
    const int* __restrict__ rowmap,
    const float* __restrict__ B, int ldb, long Bbstride,
    const float* __restrict__ bscale, int bscaleBstride,
    const float* __restrict__ bias,
    float* __restrict__ out, long ldoM, long ldoN, long Obstride) {
  const int batch = blockIdx.z;
  A += (long)batch * Abstride;
  B += (long)batch * Bbstride;
  out += (long)batch * Obstride;
  const float* bsc = bscale ? bscale + (long)batch * bscaleBstride : nullptr;

  __shared__ __align__(16) float As[16][132];
  __shared__ __align__(16) float Bs[16][132];

  const int m0 = blockIdx.y * 128, n0 = blockIdx.x * 128;
  const int tid = threadIdx.x;
  const int tm = tid >> 4, tn = tid & 15;
  const int r0 = tm * 8, c0 = tn * 4;
  float acc[8][8] = {};
  float4 pa[2], pb[2];

  auto fetch = [&](int k0) {
#pragma unroll
    for (int it = 0; it < 2; ++it) {
      int ch = tid + it * 256;
      int mm = ch >> 2;
      int kq = (ch & 3) << 2;
      int gm = m0 + mm;
      float4 v = make_float4(0.f, 0.f, 0.f, 0.f);
      if (gm < M) {
        long ar = rowmap ? (long)rowmap[gm] : (long)gm;
        v = *(const float4*)(A + ar * lda + k0 + kq);
      }
      pa[it] = v;
      int gn = n0 + mm;
      v = make_float4(0.f, 0.f, 0.f, 0.f);
      if (gn < N) {
        v = *(const float4*)(B + (long)gn * ldb + k0 + kq);
        if (bsc) { float s = bsc[gn]; v.x *= s; v.y *= s; v.z *= s; v.w *= s; }
      }
      pb[it] = v;
    }
  };

  auto store_lds = [&]() {
#pragma unroll
    for (int it = 0; it < 2; ++it) {
      int ch = tid + it * 256;
      int mm = ch >> 2;
      int kq = (ch & 3) << 2;
      As[kq + 0][mm] = pa[it].x; As[kq + 1][mm] = pa[it].y;
      As[kq + 2][mm] = pa[it].z; As[kq + 3][mm] = pa[it].w;
      Bs[kq + 0][mm] = pb[it].x; Bs[kq + 1][mm] = pb[it].y;
      Bs[kq + 2][mm] = pb[it].z; Bs[kq + 3][mm] = pb[it].w;
    }
  };

  fetch(0);
  for (int k0 = 0; k0 < K; k0 += 16) {
    store_lds();
    __syncthreads();
    if (k0 + 16 < K) fetch(k0 + 16);
#pragma unroll
    for (int kk = 0; kk < 16; ++kk) {
      float a[8], bb[8];
      *(float4*)&a[0] = *(const float4*)&As[kk][r0];
      *(float4*)&a[4] = *(const float4*)&As[kk][r0 + 4];
      *(float4*)&bb[0] = *(const float4*)&Bs[kk][c0];
      *(float4*)&bb[4] = *(const float4*)&Bs[kk][c0 + 64];
#pragma unroll
      for (int i = 0; i < 8; ++i)
#pragma unroll
        for (int j = 0; j < 8; ++j) acc[i][j] += a[i] * bb[j];
    }
    __syncthreads();
  }
#pragma unroll
  for (int i = 0; i < 8; ++i) {
    int gm = m0 + r0 + i;
    if (gm >= M) continue;
#pragma unroll
    for (int j = 0; j < 8; ++j) {
      int gn = n0 + c0 + (j & 3) + ((j >> 2) << 6);
      if (gn >= N) continue;
      float v = acc[i][j];
      if (bias) v += bias[gn];
      out[(long)gm * ldoM + (long)gn * ldoN] = v;
    }
  }
}

// ---------------------------------------------------------------------------
// b-split recurrences v2: block owns 2 batch elements; weight uint4 loads are
// shared across both. f16 dot2 pairs; h broadcast via LDS f16; carry state
// (c / h_old) stays f32 in registers. k-split across thread halves, LDS
// partial reduce, 2 barriers/step. No cross-block communication.
// ---------------------------------------------------------------------------
// grid = 128 (dir = bid>>6, bpair = bid&63), 512 threads (kh = tid>>8, j)
__global__ __launch_bounds__(512) void lstm_bsplit_kernel(
    const float* __restrict__ xg_f, const float* __restrict__ xg_b,
    const uint32_t* __restrict__ Wp,
    const float* __restrict__ bhh_f, const float* __restrict__ bhh_b,
    float* __restrict__ x) {
  const int dir = blockIdx.x >> 6, bp = blockIdx.x & 63;
  const float* xg = dir ? xg_b : xg_f;
  const float* bhh = dir ? bhh_b : bhh_f;
  const int j = threadIdx.x & 255;
  const int kh = threadIdx.x >> 8;   // k-half; also this thread's b in activation
  const int gb = bp * 2 + kh;        // global batch for activation phase

  __shared__ __align__(16) ushort hh16[2][2][HL];  // [ping][b][j]
  __shared__ float part[2][4][2][HL];              // [b][g][kh][j]
  hh16[0][kh][j] = 0;
  float c = 0.f;
  const float bb0 = bhh[j], bb1 = bhh[HL + j], bb2 = bhh[2 * HL + j], bb3 = bhh[3 * HL + j];

  const uint32_t* wg0 = Wp + ((size_t)(dir * 4 + 0) * 32) * 1024 + j * 4;
  const uint32_t* wg1 = Wp + ((size_t)(dir * 4 + 1) * 32) * 1024 + j * 4;
  const uint32_t* wg2 = Wp + ((size_t)(dir * 4 + 2) * 32) * 1024 + j * 4;
  const uint32_t* wg3 = Wp + ((size_t)(dir * 4 + 3) * 32) * 1024 + j * 4;
  __syncthreads();

  for (int s = 0; s < NT; ++s) {
    const int t = dir ? (NT - 1 - s) : s;
    const long row = (long)t * NB + gb;
    float xi = xg[row * G4 + j];
    float xf = xg[row * G4 + HL + j];
    float xgg = xg[row * G4 + 2 * HL + j];
    float xo = xg[row * G4 + 3 * HL + j];
    const int p = s & 1;
    float a00 = 0.f, a10 = 0.f, a20 = 0.f, a30 = 0.f;  // b0
    float a01 = 0.f, a11 = 0.f, a21 = 0.f, a31 = 0.f;  // b1
#pragma unroll 4
    for (int k2g = kh * 16; k2g < kh * 16 + 16; ++k2g) {
      uint4 h0 = *(const uint4*)&hh16[p][0][8 * k2g];
      uint4 h1 = *(const uint4*)&hh16[p][1][8 * k2g];
      uint4 w0 = *(const uint4*)(wg0 + (size_t)k2g * 1024);
      uint4 w1 = *(const uint4*)(wg1 + (size_t)k2g * 1024);
      uint4 w2 = *(const uint4*)(wg2 + (size_t)k2g * 1024);
      uint4 w3 = *(const uint4*)(wg3 + (size_t)k2g * 1024);
      a00 = dot2(w0.x, h0.x, a00); a00 = dot2(w0.y, h0.y, a00);
      a00 = dot2(w0.z, h0.z, a00); a00 = dot2(w0.w, h0.w, a00);
      a01 = dot2(w0.x, h1.x, a01); a01 = dot2(w0.y, h1.y, a01);
      a01 = dot2(w0.z, h1.z, a01); a01 = dot2(w0.w, h1.w, a01);
      a10 = dot2(w1.x, h0.x, a10); a10 = dot2(w1.y, h0.y, a10);
      a10 = dot2(w1.z, h0.z, a10); a10 = dot2(w1.w, h0.w, a10);
      a11 = dot2(w1.x, h1.x, a11); a11 = dot2(w1.y, h1.y, a11);
      a11 = dot2(w1.z, h1.z, a11); a11 = dot2(w1.w, h1.w, a11);
      a20 = dot2(w2.x, h0.x, a20); a20 = dot2(w2.y, h0.y, a20);
      a20 = dot2(w2.z, h0.z, a20); a20 = dot2(w2.w, h0.w, a20);
      a21 = dot2(w2.x, h1.x, a21); a21 = dot2(w2.y, h1.y, a21);
      a21 = dot2(w2.z, h1.z, a21); a21 = dot2(w2.w, h1.w, a21);
      a30 = dot2(w3.x, h0.x, a30); a30 = dot2(w3.y, h0.y, a30);
      a30 = dot2(w3.z, h0.z, a30); a30 = dot2(w3.w, h0.w, a30);
      a31 = dot2(w3.x, h1.x, a31); a31 = dot2(w3.y, h1.y, a31);
      a31 = dot2(w3.z, h1.z, a31); a31 = dot2(w3.w, h1.w, a31);
    }
    part[0][0][kh][j] = a00; part[0][1][kh][j] = a10;
    part[0][2][kh][j] = a20; part[0][3][kh][j] = a30;
    part[1][0][kh][j] = a01; part[1][1][kh][j] = a11;
    part[1][2][kh][j] = a21; part[1][3][kh][j] = a31;
    __syncthreads();
    const int b = kh;
    float gi = xi + part[b][0][0][j] + part[b][0][1][j] + bb0;
    float gf = xf + part[b][1][0][j] + part[b][1][1][j] + bb1;
    float gg = xgg + part[b][2][0][j] + part[b][2][1][j] + bb2;
    float go = xo + part[b][3][0][j] + part[b][3][1][j] + bb3;
    c = sigm(gf) * c + sigm(gi) * tanhf(gg);
    float hn = sigm(go) * tanhf(c);
    x[row * XDIM + dir * HL + j] = hn;   // fwd -> cols 0:256, bwd -> 256:512
    hh16[p ^ 1][b][j] = f2hs(hn);
    __syncthreads();
  }
}

// grid = 64 (bpair), 1024 threads (kh = tid>>9, j = tid&511)
__global__ __launch_bounds__(1024) void gru_bsplit_kernel(
    const float* __restrict__ xg, const uint32_t* __restrict__ Wp,
    const float* __restrict__ bhh, float* __restrict__ gout) {
  const int bp = blockIdx.x;
  const int j = threadIdx.x & 511;
  const int kh = threadIdx.x >> 9;
  const int gb = bp * 2 + kh;

  __shared__ __align__(16) ushort hh16[2][2][NC];  // [ping][b][j]
  __shared__ float part[2][3][2][NC];              // [b][g][kh][j]
  hh16[0][kh][j] = 0;
  float hreg = 0.f;                                // own (b=kh, j) carry, f32
  const float bb0 = bhh[j], bb1 = bhh[NC + j], bb2 = bhh[2 * NC + j];

  const uint32_t* wr = Wp + j * 4;
  const uint32_t* wz = Wp + (size_t)1 * 64 * 2048 + j * 4;
  const uint32_t* wn = Wp + (size_t)2 * 64 * 2048 + j * 4;
  __syncthreads();

  for (int t = 0; t < NT; ++t) {
    const long row = (long)t * NB + gb;
    float xr = xg[row * G3 + j];
    float xz = xg[row * G3 + NC + j];
    float xn = xg[row * G3 + 2 * NC + j];
    const int p = t & 1;
    float ar0 = 0.f, az0 = 0.f, an0 = 0.f;
    float ar1 = 0.f, az1 = 0.f, an1 = 0.f;
#pragma unroll 4
    for (int k2g = kh * 32; k2g < kh * 32 + 32; ++k2g) {
      uint4 h0 = *(const uint4*)&hh16[p][0][8 * k2g];
      uint4 h1 = *(const uint4*)&hh16[p][1][8 * k2g];
      uint4 w0 = *(const uint4*)(wr + (size_t)k2g * 2048);
      uint4 w1 = *(const uint4*)(wz + (size_t)k2g * 2048);
      uint4 w2 = *(const uint4*)(wn + (size_t)k2g * 2048);
      ar0 = dot2(w0.x, h0.x, ar0); ar0 = dot2(w0.y, h0.y, ar0);
      ar0 = dot2(w0.z, h0.z, ar0); ar0 = dot2(w0.w, h0.w, ar0);
      ar1 = dot2(w0.x, h1.x, ar1); ar1 = dot2(w0.y, h1.y, ar1);
      ar1 = dot2(w0.z, h1.z, ar1); ar1 = dot2(w0.w, h1.w, ar1);
      az0 = dot2(w1.x, h0.x, az0); az0 = dot2(w1.y, h0.y, az0);
      az0 = dot2(w1.z, h0.z, az0); az0 = dot2(w1.w, h0.w, az0);
      az1 = dot2(w1.x, h1.x, az1); az1 = dot2(w1.y, h1.y, az1);
      az1 = dot2(w1.z, h1.z, az1); az1 = dot2(w1.w, h1.w, az1);
      an0 = dot2(w2.x, h0.x, an0); an0 = dot2(w2.y, h0.y, an0);
      an0 = dot2(w2.z, h0.z, an0); an0 = dot2(w2.w, h0.w, an0);
      an1 = dot2(w2.x, h1.x, an1); an1 = dot2(w2.y, h1.y, an1);
      an1 = dot2(w2.z, h1.z, an1); an1 = dot2(w2.w, h1.w, an1);
    }
    part[0][0][kh][j] = ar0; part[0][1][kh][j] = az0; part[0][2][kh][j] = an0;
    part[1][0][kh][j] = ar1; part[1][1][kh][j] = az1; part[1][2][kh][j] = an1;
    __syncthreads();
    const int b = kh;
    float hr = part[b][0][0][j] + part[b][0][1][j] + bb0;
    float hz = part[b][1][0][j] + part[b][1][1][j] + bb1;
    float hn = part[b][2][0][j] + part[b][2][1][j] + bb2;
    float r = sigm(xr + hr);
    float z = sigm(xz + hz);
    float n = tanhf(xn + r * hn);
    float h = (1.f - z) * n + z * hreg;
    hreg = h;
    gout[row * NC + j] = h;
    hh16[p ^ 1][b][j] = f2hs(h);
    __syncthreads();
  }
}

// ---------------------------------------------------------------------------
extern "C" void kernel_launch(void* const* d_in, const int* in_sizes, int n_in,
                              void* d_out, int out_size, void* d_ws, size_t ws_size,
                              hipStream_t stream) {
  const float* feature = (const float*)d_in[0];
  const float* A       = (const float*)d_in[1];
  const int*   text    = (const int*)d_in[2];
  const int*   tlen    = (const int*)d_in[3];
  const float* Wih_f   = (const float*)d_in[4];
  const float* Whh_f   = (const float*)d_in[5];
  const float* bih_f   = (const float*)d_in[6];
  const float* bhh_f   = (const float*)d_in[7];
  const float* Wih_b   = (const float*)d_in[8];
  const float* Whh_b   = (const float*)d_in[9];
  const float* bih_b   = (const float*)d_in[10];
  const float* bhh_b   = (const float*)d_in[11];
  const float* gWih    = (const float*)d_in[12];
  const float* gWhh    = (const float*)d_in[13];
  const float* gbih    = (const float*)d_in[14];
  const float* gbhh    = (const float*)d_in[15];
  const float* genW    = (const float*)d_in[16];
  const float* genb    = (const float*)d_in[17];
  const float* cemb    = (const float*)d_in[18];
  float* out = (float*)d_out;
  const int total = in_sizes[2];

  char* ws = (char*)d_ws;
  size_t off = 0;
  auto alloc = [&](size_t bytes) -> void* {
    void* p = ws + off;
    off += (bytes + 255) & ~(size_t)255;
    return p;
  };
  float*    asum  = (float*)alloc((size_t)NB * NT * 4);
  int*      offs  = (int*)alloc(NB * 4);
  int*      rowmap= (int*)alloc((size_t)NB * NT * 4);
  float*    Cbuf  = (float*)alloc((size_t)NT * NB * NC * 4);   // phase1: C; phase2: gru_out
  float*    xgf   = (float*)alloc((size_t)NT * NB * G4 * 4);   // } reused as gru xg
  float*    xgb   = (float*)alloc((size_t)NT * NB * G4 * 4);   // } (gxg 31.5MB spills into dead xgb)
  float*    xbuf  = (float*)alloc((size_t)NT * NB * XDIM * 4);
  uint32_t* WpL   = (uint32_t*)alloc((size_t)2 * 4 * 32 * 256 * 4 * 4);  // 1 MB
  uint32_t* WpG   = (uint32_t*)alloc((size_t)3 * 64 * 512 * 4 * 4);      // 1.5 MB
  float*    gxg   = xgf;
  float*    gout  = Cbuf;

  // --- setup + weight packing (independent of GEMMs) ---
  offsets_kernel<<<1, 64, 0, stream>>>(tlen, offs);
  rowmap_kernel<<<NB, 64, 0, stream>>>(tlen, offs, rowmap);
  asum_kernel<<<NB * NT, 64, 0, stream>>>(A, asum);
  lstm_pack_kernel<<<2048, 64, 0, stream>>>(Whh_f, Whh_b, WpL);
  gru_pack_kernel<<<1536, 128, 0, stream>>>(gWhh, WpG);

  // --- attention pooling: per-b GEMM, M=c(512), N=t(40), K=hw(512) ---
  sgemm_kernel<<<dim3(1, 4, NB), 256, 0, stream>>>(
      NC, NT, HW,
      feature, HW, (long)NC * HW, nullptr,
      A, HW, (long)NT * HW,
      asum, NT,
      nullptr,
      Cbuf, 1L, (long)NB * NC, (long)NC);

  // --- LSTM input projections ---
  sgemm_kernel<<<dim3(G4 / 128, (NT * NB) / 128, 1), 256, 0, stream>>>(
      NT * NB, G4, NC, Cbuf, NC, 0, nullptr, Wih_f, NC, 0, nullptr, 0, bih_f,
      xgf, (long)G4, 1L, 0);
  sgemm_kernel<<<dim3(G4 / 128, (NT * NB) / 128, 1), 256, 0, stream>>>(
      NT * NB, G4, NC, Cbuf, NC, 0, nullptr, Wih_b, NC, 0, nullptr, 0, bih_b,
      xgb, (long)G4, 1L, 0);

  // --- LSTM recurrence: ONE launch, batch-pair blocks, no grid sync ---
  lstm_bsplit_kernel<<<128, 512, 0, stream>>>(
      xgf, xgb, WpL, bhh_f, bhh_b, xbuf);

  // --- embedding into x[:,:,512:1024] ---
  emb_kernel<<<NT * NB, 128, 0, stream>>>(cemb, text, tlen, offs, xbuf);

  // --- GRU input projection ---
  sgemm_kernel<<<dim3(G3 / 128, (NT * NB) / 128, 1), 256, 0, stream>>>(
      NT * NB, G3, XDIM, xbuf, XDIM, 0, nullptr, gWih, XDIM, 0, nullptr, 0, gbih,
      gxg, (long)G3, 1L, 0);

  // --- GRU recurrence: ONE launch, batch-pair blocks, no grid sync ---
  gru_bsplit_kernel<<<64, 1024, 0, stream>>>(gxg, WpG, gbhh, gout);

  // --- vocab projection, ragged-gathered rows straight into d_out ---
  sgemm_kernel<<<dim3((NG + 127) / 128, (total + 127) / 128, 1), 256, 0, stream>>>(
      total, NG, NC, gout, NC, 0, rowmap, genW, NC, 0, nullptr, 0, genb,
      out, (long)NG, 1L, 0);
}

// Round 7
// 1451.409 us; speedup vs baseline: 2.8258x; 1.0015x over previous
//
#include <hip/hip_runtime.h>
#include <hip/hip_bf16.h>
#include <hip/hip_fp16.h>
#include <math.h>

#define NB 128     // batch
#define NC 512     // channels
#define NT 40      // time steps
#define HW 512     // nH*nW
#define HL 256     // LSTM hidden per direction
#define NG 5000    // nclass
#define XDIM 1024  // 2*NC (GRU input)
#define G4 1024    // 4*HL
#define G3 1536    // 3*NC

typedef _Float16 half2v __attribute__((ext_vector_type(2)));

__device__ __forceinline__ float dot2(uint32_t w, uint32_t h, float acc) {
#if __has_builtin(__builtin_amdgcn_fdot2)
  return __builtin_amdgcn_fdot2(__builtin_bit_cast(half2v, w),
                                __builtin_bit_cast(half2v, h), acc, false);
#else
  half2v wv = __builtin_bit_cast(half2v, w), hv = __builtin_bit_cast(half2v, h);
  return acc + (float)wv.x * (float)hv.x + (float)wv.y * (float)hv.y;
#endif
}

__device__ __forceinline__ float sigm(float x) { return 1.f / (1.f + expf(-x)); }
// f32 -> f16 bits (clang native _Float16 conversion, RNE)
__device__ __forceinline__ ushort f2hs(float f) {
  _Float16 h = (_Float16)f;
  return __builtin_bit_cast(ushort, h);
}
__device__ __forceinline__ uint32_t f2h(float f) { return (uint32_t)f2hs(f); }

// ---------------------------------------------------------------------------
// small setup kernels
// ---------------------------------------------------------------------------
__global__ void offsets_kernel(const int* __restrict__ tl, int* __restrict__ offs) {
  if (threadIdx.x == 0) {
    int o = 0;
    for (int b = 0; b < NB; ++b) { offs[b] = o; o += tl[b]; }
  }
}

__global__ void rowmap_kernel(const int* __restrict__ tl, const int* __restrict__ offs,
                              int* __restrict__ rowmap) {
  int b = blockIdx.x;
  int len = tl[b], off = offs[b];
  for (int t = threadIdx.x; t < len; t += blockDim.x)
    rowmap[off + t] = t * NB + b;   // row index into [t][b][*] matrices
}

// 1/sum over HW per (b,t)
__global__ __launch_bounds__(64) void asum_kernel(const float* __restrict__ A,
                                                  float* __restrict__ out) {
  int row = blockIdx.x;  // b*NT + t
  const float* p = A + (size_t)row * HW;
  float s = 0.f;
#pragma unroll
  for (int i = 0; i < 8; ++i) s += p[threadIdx.x + i * 64];
#pragma unroll
  for (int off = 32; off > 0; off >>= 1) s += __shfl_down(s, off);
  if (threadIdx.x == 0) out[row] = 1.0f / s;
}

// teacher-forcing embedding into x[:,:,512:1024]
__global__ __launch_bounds__(128) void emb_kernel(const float* __restrict__ ce,
                                                  const int* __restrict__ text,
                                                  const int* __restrict__ tl,
                                                  const int* __restrict__ offs,
                                                  float* __restrict__ x) {
  int bid = blockIdx.x;  // t*NB + b
  int t = bid >> 7, b = bid & 127;
  int tok = 0;
  if (t >= 2) {
    int p = t - 2;
    if (p < tl[b]) tok = text[offs[b] + p] + 1;
  }
  float4 v = *(const float4*)(ce + (size_t)tok * NC + threadIdx.x * 4);
  *(float4*)(x + (size_t)bid * XDIM + NC + threadIdx.x * 4) = v;
}

// ---------------------------------------------------------------------------
// weight pack: f32 [g][j][k] -> f16 k-pair layout [g][k2g][j][q] (u32, q=k2&3)
// ---------------------------------------------------------------------------
// LSTM: 2048 blocks = (dir,g,j), 64 threads; thread l -> k = 4l..4l+3
__global__ __launch_bounds__(64) void lstm_pack_kernel(
    const float* __restrict__ Wf, const float* __restrict__ Wb,
    uint32_t* __restrict__ Wp) {
  int row = blockIdx.x;                 // (dir*4+g)*256 + j
  int dg = row >> 8, j = row & 255;     // dg = dir*4+g
  int dir = dg >> 2;
  const float* W = (dir ? Wb : Wf) + ((size_t)(dg & 3) * HL + j) * HL;
  int l = threadIdx.x;
  float4 v = *(const float4*)(W + l * 4);
  uint32_t p0 = f2h(v.x) | (f2h(v.y) << 16);   // k2 = 2l
  uint32_t p1 = f2h(v.z) | (f2h(v.w) << 16);   // k2 = 2l+1
  int k2g = l >> 1, q0 = (2 * l) & 3;
  size_t base = ((size_t)dg * 32 + k2g) * 1024 + j * 4;
  Wp[base + q0] = p0;
  Wp[base + q0 + 1] = p1;
}

// GRU: 1536 blocks = (g,j), 128 threads; thread l -> k = 4l..4l+3
__global__ __launch_bounds__(128) void gru_pack_kernel(
    const float* __restrict__ W, uint32_t* __restrict__ Wp) {
  int row = blockIdx.x;                 // g*512 + j
  int g = row >> 9, j = row & 511;
  const float* Wr = W + ((size_t)g * NC + j) * NC;
  int l = threadIdx.x;
  float4 v = *(const float4*)(Wr + l * 4);
  uint32_t p0 = f2h(v.x) | (f2h(v.y) << 16);
  uint32_t p1 = f2h(v.z) | (f2h(v.w) << 16);
  int k2g = l >> 1, q0 = (2 * l) & 3;
  size_t base = ((size_t)g * 64 + k2g) * 2048 + j * 4;
  Wp[base + q0] = p0;
  Wp[base + q0 + 1] = p1;
}

// ---------------------------------------------------------------------------
// generic f32 SGEMM (unchanged): 128x128 tile, 8x8/thread, BK=16,
// register-prefetch, split B-fragment (2-way LDS aliasing only).
// ---------------------------------------------------------------------------
__global__ __launch_bounds__(256) void sgemm_kernel(
    int M, int N, int K,
    const float* __restrict__ A, int lda, long Abstride,
    const int* __restrict__ rowmap,
    const float* __restrict__ B, int ldb, long Bbstride,
    const float* __restrict__ bscale, int bscaleBstride,
    const float* __restrict__ bias,
    float* __restrict__ out, long ldoM, long ldoN, long Obstride) {
  const int batch = blockIdx.z;
  A += (long)batch * Abstride;
  B += (long)batch * Bbstride;
  out += (long)batch * Obstride;
  const float* bsc = bscale ? bscale + (long)batch * bscaleBstride : nullptr;

  __shared__ __align__(16) float As[16][132];
  __shared__ __align__(16) float Bs[16][132];

  const int m0 = blockIdx.y * 128, n0 = blockIdx.x * 128;
  const int tid = threadIdx.x;
  const int tm = tid >> 4, tn = tid & 15;
  const int r0 = tm * 8, c0 = tn * 4;
  float acc[8][8] = {};
  float4 pa[2], pb[2];

  auto fetch = [&](int k0) {
#pragma unroll
    for (int it = 0; it < 2; ++it) {
      int ch = tid + it * 256;
      int mm = ch >> 2;
      int kq = (ch & 3) << 2;
      int gm = m0 + mm;
      float4 v = make_float4(0.f, 0.f, 0.f, 0.f);
      if (gm < M) {
        long ar = rowmap ? (long)rowmap[gm] : (long)gm;
        v = *(const float4*)(A + ar * lda + k0 + kq);
      }
      pa[it] = v;
      int gn = n0 + mm;
      v = make_float4(0.f, 0.f, 0.f, 0.f);
      if (gn < N) {
        v = *(const float4*)(B + (long)gn * ldb + k0 + kq);
        if (bsc) { float s = bsc[gn]; v.x *= s; v.y *= s; v.z *= s; v.w *= s; }
      }
      pb[it] = v;
    }
  };

  auto store_lds = [&]() {
#pragma unroll
    for (int it = 0; it < 2; ++it) {
      int ch = tid + it * 256;
      int mm = ch >> 2;
      int kq = (ch & 3) << 2;
      As[kq + 0][mm] = pa[it].x; As[kq + 1][mm] = pa[it].y;
      As[kq + 2][mm] = pa[it].z; As[kq + 3][mm] = pa[it].w;
      Bs[kq + 0][mm] = pb[it].x; Bs[kq + 1][mm] = pb[it].y;
      Bs[kq + 2][mm] = pb[it].z; Bs[kq + 3][mm] = pb[it].w;
    }
  };

  fetch(0);
  for (int k0 = 0; k0 < K; k0 += 16) {
    store_lds();
    __syncthreads();
    if (k0 + 16 < K) fetch(k0 + 16);
#pragma unroll
    for (int kk = 0; kk < 16; ++kk) {
      float a[8], bb[8];
      *(float4*)&a[0] = *(const float4*)&As[kk][r0];
      *(float4*)&a[4] = *(const float4*)&As[kk][r0 + 4];
      *(float4*)&bb[0] = *(const float4*)&Bs[kk][c0];
      *(float4*)&bb[4] = *(const float4*)&Bs[kk][c0 + 64];
#pragma unroll
      for (int i = 0; i < 8; ++i)
#pragma unroll
        for (int j = 0; j < 8; ++j) acc[i][j] += a[i] * bb[j];
    }
    __syncthreads();
  }
#pragma unroll
  for (int i = 0; i < 8; ++i) {
    int gm = m0 + r0 + i;
    if (gm >= M) continue;
#pragma unroll
    for (int j = 0; j < 8; ++j) {
      int gn = n0 + c0 + (j & 3) + ((j >> 2) << 6);
      if (gn >= N) continue;
      float v = acc[i][j];
      if (bias) v += bias[gn];
      out[(long)gm * ldoM + (long)gn * ldoN] = v;
    }
  }
}

// ---------------------------------------------------------------------------
// b-split recurrences v2: block owns 2 batch elements; weight uint4 loads are
// shared across both. f16 dot2 pairs; h broadcast via LDS f16; carry state
// (c / h_old) stays f32 in registers. k-split across thread halves, LDS
// partial reduce, 2 barriers/step. No cross-block communication.
// ---------------------------------------------------------------------------
// grid = 128 (dir = bid>>6, bpair = bid&63), 512 threads (kh = tid>>8, j)
__global__ __launch_bounds__(512) void lstm_bsplit_kernel(
    const float* __restrict__ xg_f, const float* __restrict__ xg_b,
    const uint32_t* __restrict__ Wp,
    const float* __restrict__ bhh_f, const float* __restrict__ bhh_b,
    float* __restrict__ x) {
  const int dir = blockIdx.x >> 6, bp = blockIdx.x & 63;
  const float* xg = dir ? xg_b : xg_f;
  const float* bhh = dir ? bhh_b : bhh_f;
  const int j = threadIdx.x & 255;
  const int kh = threadIdx.x >> 8;   // k-half; also this thread's b in activation
  const int gb = bp * 2 + kh;        // global batch for activation phase

  __shared__ __align__(16) ushort hh16[2][2][HL];  // [ping][b][j]
  __shared__ float part[2][4][2][HL];              // [b][g][kh][j]
  hh16[0][kh][j] = 0;
  float c = 0.f;
  const float bb0 = bhh[j], bb1 = bhh[HL + j], bb2 = bhh[2 * HL + j], bb3 = bhh[3 * HL + j];

  const uint32_t* wg0 = Wp + ((size_t)(dir * 4 + 0) * 32) * 1024 + j * 4;
  const uint32_t* wg1 = Wp + ((size_t)(dir * 4 + 1) * 32) * 1024 + j * 4;
  const uint32_t* wg2 = Wp + ((size_t)(dir * 4 + 2) * 32) * 1024 + j * 4;
  const uint32_t* wg3 = Wp + ((size_t)(dir * 4 + 3) * 32) * 1024 + j * 4;
  __syncthreads();

  for (int s = 0; s < NT; ++s) {
    const int t = dir ? (NT - 1 - s) : s;
    const long row = (long)t * NB + gb;
    float xi = xg[row * G4 + j];
    float xf = xg[row * G4 + HL + j];
    float xgg = xg[row * G4 + 2 * HL + j];
    float xo = xg[row * G4 + 3 * HL + j];
    const int p = s & 1;
    float a00 = 0.f, a10 = 0.f, a20 = 0.f, a30 = 0.f;  // b0
    float a01 = 0.f, a11 = 0.f, a21 = 0.f, a31 = 0.f;  // b1
#pragma unroll 4
    for (int k2g = kh * 16; k2g < kh * 16 + 16; ++k2g) {
      uint4 h0 = *(const uint4*)&hh16[p][0][8 * k2g];
      uint4 h1 = *(const uint4*)&hh16[p][1][8 * k2g];
      uint4 w0 = *(const uint4*)(wg0 + (size_t)k2g * 1024);
      uint4 w1 = *(const uint4*)(wg1 + (size_t)k2g * 1024);
      uint4 w2 = *(const uint4*)(wg2 + (size_t)k2g * 1024);
      uint4 w3 = *(const uint4*)(wg3 + (size_t)k2g * 1024);
      a00 = dot2(w0.x, h0.x, a00); a00 = dot2(w0.y, h0.y, a00);
      a00 = dot2(w0.z, h0.z, a00); a00 = dot2(w0.w, h0.w, a00);
      a01 = dot2(w0.x, h1.x, a01); a01 = dot2(w0.y, h1.y, a01);
      a01 = dot2(w0.z, h1.z, a01); a01 = dot2(w0.w, h1.w, a01);
      a10 = dot2(w1.x, h0.x, a10); a10 = dot2(w1.y, h0.y, a10);
      a10 = dot2(w1.z, h0.z, a10); a10 = dot2(w1.w, h0.w, a10);
      a11 = dot2(w1.x, h1.x, a11); a11 = dot2(w1.y, h1.y, a11);
      a11 = dot2(w1.z, h1.z, a11); a11 = dot2(w1.w, h1.w, a11);
      a20 = dot2(w2.x, h0.x, a20); a20 = dot2(w2.y, h0.y, a20);
      a20 = dot2(w2.z, h0.z, a20); a20 = dot2(w2.w, h0.w, a20);
      a21 = dot2(w2.x, h1.x, a21); a21 = dot2(w2.y, h1.y, a21);
      a21 = dot2(w2.z, h1.z, a21); a21 = dot2(w2.w, h1.w, a21);
      a30 = dot2(w3.x, h0.x, a30); a30 = dot2(w3.y, h0.y, a30);
      a30 = dot2(w3.z, h0.z, a30); a30 = dot2(w3.w, h0.w, a30);
      a31 = dot2(w3.x, h1.x, a31); a31 = dot2(w3.y, h1.y, a31);
      a31 = dot2(w3.z, h1.z, a31); a31 = dot2(w3.w, h1.w, a31);
    }
    part[0][0][kh][j] = a00; part[0][1][kh][j] = a10;
    part[0][2][kh][j] = a20; part[0][3][kh][j] = a30;
    part[1][0][kh][j] = a01; part[1][1][kh][j] = a11;
    part[1][2][kh][j] = a21; part[1][3][kh][j] = a31;
    __syncthreads();
    const int b = kh;
    float gi = xi + part[b][0][0][j] + part[b][0][1][j] + bb0;
    float gf = xf + part[b][1][0][j] + part[b][1][1][j] + bb1;
    float gg = xgg + part[b][2][0][j] + part[b][2][1][j] + bb2;
    float go = xo + part[b][3][0][j] + part[b][3][1][j] + bb3;
    c = sigm(gf) * c + sigm(gi) * tanhf(gg);
    float hn = sigm(go) * tanhf(c);
    x[row * XDIM + dir * HL + j] = hn;   // fwd -> cols 0:256, bwd -> 256:512
    hh16[p ^ 1][b][j] = f2hs(hn);
    __syncthreads();
  }
}

// grid = 64 (bpair), 1024 threads (kh = tid>>9, j = tid&511)
__global__ __launch_bounds__(1024) void gru_bsplit_kernel(
    const float* __restrict__ xg, const uint32_t* __restrict__ Wp,
    const float* __restrict__ bhh, float* __restrict__ gout) {
  const int bp = blockIdx.x;
  const int j = threadIdx.x & 511;
  const int kh = threadIdx.x >> 9;
  const int gb = bp * 2 + kh;

  __shared__ __align__(16) ushort hh16[2][2][NC];  // [ping][b][j]
  __shared__ float part[2][3][2][NC];              // [b][g][kh][j]
  hh16[0][kh][j] = 0;
  float hreg = 0.f;                                // own (b=kh, j) carry, f32
  const float bb0 = bhh[j], bb1 = bhh[NC + j], bb2 = bhh[2 * NC + j];

  const uint32_t* wr = Wp + j * 4;
  const uint32_t* wz = Wp + (size_t)1 * 64 * 2048 + j * 4;
  const uint32_t* wn = Wp + (size_t)2 * 64 * 2048 + j * 4;
  __syncthreads();

  for (int t = 0; t < NT; ++t) {
    const long row = (long)t * NB + gb;
    float xr = xg[row * G3 + j];
    float xz = xg[row * G3 + NC + j];
    float xn = xg[row * G3 + 2 * NC + j];
    const int p = t & 1;
    float ar0 = 0.f, az0 = 0.f, an0 = 0.f;
    float ar1 = 0.f, az1 = 0.f, an1 = 0.f;
#pragma unroll 4
    for (int k2g = kh * 32; k2g < kh * 32 + 32; ++k2g) {
      uint4 h0 = *(const uint4*)&hh16[p][0][8 * k2g];
      uint4 h1 = *(const uint4*)&hh16[p][1][8 * k2g];
      uint4 w0 = *(const uint4*)(wr + (size_t)k2g * 2048);
      uint4 w1 = *(const uint4*)(wz + (size_t)k2g * 2048);
      uint4 w2 = *(const uint4*)(wn + (size_t)k2g * 2048);
      ar0 = dot2(w0.x, h0.x, ar0); ar0 = dot2(w0.y, h0.y, ar0);
      ar0 = dot2(w0.z, h0.z, ar0); ar0 = dot2(w0.w, h0.w, ar0);
      ar1 = dot2(w0.x, h1.x, ar1); ar1 = dot2(w0.y, h1.y, ar1);
      ar1 = dot2(w0.z, h1.z, ar1); ar1 = dot2(w0.w, h1.w, ar1);
      az0 = dot2(w1.x, h0.x, az0); az0 = dot2(w1.y, h0.y, az0);
      az0 = dot2(w1.z, h0.z, az0); az0 = dot2(w1.w, h0.w, az0);
      az1 = dot2(w1.x, h1.x, az1); az1 = dot2(w1.y, h1.y, az1);
      az1 = dot2(w1.z, h1.z, az1); az1 = dot2(w1.w, h1.w, az1);
      an0 = dot2(w2.x, h0.x, an0); an0 = dot2(w2.y, h0.y, an0);
      an0 = dot2(w2.z, h0.z, an0); an0 = dot2(w2.w, h0.w, an0);
      an1 = dot2(w2.x, h1.x, an1); an1 = dot2(w2.y, h1.y, an1);
      an1 = dot2(w2.z, h1.z, an1); an1 = dot2(w2.w, h1.w, an1);
    }
    part[0][0][kh][j] = ar0; part[0][1][kh][j] = az0; part[0][2][kh][j] = an0;
    part[1][0][kh][j] = ar1; part[1][1][kh][j] = az1; part[1][2][kh][j] = an1;
    __syncthreads();
    const int b = kh;
    float hr = part[b][0][0][j] + part[b][0][1][j] + bb0;
    float hz = part[b][1][0][j] + part[b][1][1][j] + bb1;
    float hn = part[b][2][0][j] + part[b][2][1][j] + bb2;
    float r = sigm(xr + hr);
    float z = sigm(xz + hz);
    float n = tanhf(xn + r * hn);
    float h = (1.f - z) * n + z * hreg;
    hreg = h;
    gout[row * NC + j] = h;
    hh16[p ^ 1][b][j] = f2hs(h);
    __syncthreads();
  }
}

// ---------------------------------------------------------------------------
extern "C" void kernel_launch(void* const* d_in, const int* in_sizes, int n_in,
                              void* d_out, int out_size, void* d_ws, size_t ws_size,
                              hipStream_t stream) {
  const float* feature = (const float*)d_in[0];
  const float* A       = (const float*)d_in[1];
  const int*   text    = (const int*)d_in[2];
  const int*   tlen    = (const int*)d_in[3];
  const float* Wih_f   = (const float*)d_in[4];
  const float* Whh_f   = (const float*)d_in[5];
  const float* bih_f   = (const float*)d_in[6];
  const float* bhh_f   = (const float*)d_in[7];
  const float* Wih_b   = (const float*)d_in[8];
  const float* Whh_b   = (const float*)d_in[9];
  const float* bih_b   = (const float*)d_in[10];
  const float* bhh_b   = (const float*)d_in[11];
  const float* gWih    = (const float*)d_in[12];
  const float* gWhh    = (const float*)d_in[13];
  const float* gbih    = (const float*)d_in[14];
  const float* gbhh    = (const float*)d_in[15];
  const float* genW    = (const float*)d_in[16];
  const float* genb    = (const float*)d_in[17];
  const float* cemb    = (const float*)d_in[18];
  float* out = (float*)d_out;
  const int total = in_sizes[2];

  char* ws = (char*)d_ws;
  size_t off = 0;
  auto alloc = [&](size_t bytes) -> void* {
    void* p = ws + off;
    off += (bytes + 255) & ~(size_t)255;
    return p;
  };
  float*    asum  = (float*)alloc((size_t)NB * NT * 4);
  int*      offs  = (int*)alloc(NB * 4);
  int*      rowmap= (int*)alloc((size_t)NB * NT * 4);
  float*    Cbuf  = (float*)alloc((size_t)NT * NB * NC * 4);   // phase1: C; phase2: gru_out
  float*    xgf   = (float*)alloc((size_t)NT * NB * G4 * 4);   // } reused as gru xg
  float*    xgb   = (float*)alloc((size_t)NT * NB * G4 * 4);   // } (gxg 31.5MB spills into dead xgb)
  float*    xbuf  = (float*)alloc((size_t)NT * NB * XDIM * 4);
  uint32_t* WpL   = (uint32_t*)alloc((size_t)2 * 4 * 32 * 256 * 4 * 4);  // 1 MB
  uint32_t* WpG   = (uint32_t*)alloc((size_t)3 * 64 * 512 * 4 * 4);      // 1.5 MB
  float*    gxg   = xgf;
  float*    gout  = Cbuf;

  // --- setup + weight packing (independent of GEMMs) ---
  offsets_kernel<<<1, 64, 0, stream>>>(tlen, offs);
  rowmap_kernel<<<NB, 64, 0, stream>>>(tlen, offs, rowmap);
  asum_kernel<<<NB * NT, 64, 0, stream>>>(A, asum);
  lstm_pack_kernel<<<2048, 64, 0, stream>>>(Whh_f, Whh_b, WpL);
  gru_pack_kernel<<<1536, 128, 0, stream>>>(gWhh, WpG);

  // --- attention pooling: per-b GEMM, M=c(512), N=t(40), K=hw(512) ---
  sgemm_kernel<<<dim3(1, 4, NB), 256, 0, stream>>>(
      NC, NT, HW,
      feature, HW, (long)NC * HW, nullptr,
      A, HW, (long)NT * HW,
      asum, NT,
      nullptr,
      Cbuf, 1L, (long)NB * NC, (long)NC);

  // --- LSTM input projections ---
  sgemm_kernel<<<dim3(G4 / 128, (NT * NB) / 128, 1), 256, 0, stream>>>(
      NT * NB, G4, NC, Cbuf, NC, 0, nullptr, Wih_f, NC, 0, nullptr, 0, bih_f,
      xgf, (long)G4, 1L, 0);
  sgemm_kernel<<<dim3(G4 / 128, (NT * NB) / 128, 1), 256, 0, stream>>>(
      NT * NB, G4, NC, Cbuf, NC, 0, nullptr, Wih_b, NC, 0, nullptr, 0, bih_b,
      xgb, (long)G4, 1L, 0);

  // --- LSTM recurrence: ONE launch, batch-pair blocks, no grid sync ---
  lstm_bsplit_kernel<<<128, 512, 0, stream>>>(
      xgf, xgb, WpL, bhh_f, bhh_b, xbuf);

  // --- embedding into x[:,:,512:1024] ---
  emb_kernel<<<NT * NB, 128, 0, stream>>>(cemb, text, tlen, offs, xbuf);

  // --- GRU input projection ---
  sgemm_kernel<<<dim3(G3 / 128, (NT * NB) / 128, 1), 256, 0, stream>>>(
      NT * NB, G3, XDIM, xbuf, XDIM, 0, nullptr, gWih, XDIM, 0, nullptr, 0, gbih,
      gxg, (long)G3, 1L, 0);

  // --- GRU recurrence: ONE launch, batch-pair blocks, no grid sync ---
  gru_bsplit_kernel<<<64, 1024, 0, stream>>>(gxg, WpG, gbhh, gout);

  // --- vocab projection, ragged-gathered rows straight into d_out ---
  sgemm_kernel<<<dim3((NG + 127) / 128, (total + 127) / 128, 1), 256, 0, stream>>>(
      total, NG, NC, gout, NC, 0, rowmap, genW, NC, 0, nullptr, 0, genb,
      out, (long)NG, 1L, 0);
}

// Round 8
// 1000.273 us; speedup vs baseline: 4.1003x; 1.4510x over previous
//
#include <hip/hip_runtime.h>
#include <hip/hip_bf16.h>
#include <hip/hip_fp16.h>
#include <math.h>

#define NB 128     // batch
#define NC 512     // channels
#define NT 40      // time steps
#define HW 512     // nH*nW
#define HL 256     // LSTM hidden per direction
#define NG 5000    // nclass
#define XDIM 1024  // 2*NC (GRU input)
#define G4 1024    // 4*HL
#define G3 1536    // 3*NC

typedef _Float16 half2v __attribute__((ext_vector_type(2)));
typedef short s16x8 __attribute__((ext_vector_type(8)));
typedef float f32x4_ __attribute__((ext_vector_type(4)));

__device__ __forceinline__ float dot2(uint32_t w, uint32_t h, float acc) {
#if __has_builtin(__builtin_amdgcn_fdot2)
  return __builtin_amdgcn_fdot2(__builtin_bit_cast(half2v, w),
                                __builtin_bit_cast(half2v, h), acc, false);
#else
  half2v wv = __builtin_bit_cast(half2v, w), hv = __builtin_bit_cast(half2v, h);
  return acc + (float)wv.x * (float)hv.x + (float)wv.y * (float)hv.y;
#endif
}

__device__ __forceinline__ float sigm(float x) { return 1.f / (1.f + expf(-x)); }
// f32 -> f16 bits (clang native _Float16 conversion, RNE)
__device__ __forceinline__ ushort f2hs(float f) {
  _Float16 h = (_Float16)f;
  return __builtin_bit_cast(ushort, h);
}
__device__ __forceinline__ uint32_t f2h(float f) { return (uint32_t)f2hs(f); }
// f32 -> bf16 bits (RNE)
__device__ __forceinline__ uint32_t f2bf(float f) {
  uint32_t u = __float_as_uint(f);
  return (u + 0x7fffu + ((u >> 16) & 1u)) >> 16;
}
__device__ __forceinline__ float bf2f(ushort u) {
  return __uint_as_float((uint32_t)u << 16);
}

// ---------------------------------------------------------------------------
// small setup kernels
// ---------------------------------------------------------------------------
__global__ void offsets_kernel(const int* __restrict__ tl, int* __restrict__ offs) {
  if (threadIdx.x == 0) {
    int o = 0;
    for (int b = 0; b < NB; ++b) { offs[b] = o; o += tl[b]; }
  }
}

__global__ void rowmap_kernel(const int* __restrict__ tl, const int* __restrict__ offs,
                              int* __restrict__ rowmap) {
  int b = blockIdx.x;
  int len = tl[b], off = offs[b];
  for (int t = threadIdx.x; t < len; t += blockDim.x)
    rowmap[off + t] = t * NB + b;   // row index into [t][b][*] matrices
}

// 1/sum over HW per (b,t)
__global__ __launch_bounds__(64) void asum_kernel(const float* __restrict__ A,
                                                  float* __restrict__ out) {
  int row = blockIdx.x;  // b*NT + t
  const float* p = A + (size_t)row * HW;
  float s = 0.f;
#pragma unroll
  for (int i = 0; i < 8; ++i) s += p[threadIdx.x + i * 64];
#pragma unroll
  for (int off = 32; off > 0; off >>= 1) s += __shfl_down(s, off);
  if (threadIdx.x == 0) out[row] = 1.0f / s;
}

// teacher-forcing embedding into x[:,:,512:1024]
__global__ __launch_bounds__(128) void emb_kernel(const float* __restrict__ ce,
                                                  const int* __restrict__ text,
                                                  const int* __restrict__ tl,
                                                  const int* __restrict__ offs,
                                                  float* __restrict__ x) {
  int bid = blockIdx.x;  // t*NB + b
  int t = bid >> 7, b = bid & 127;
  int tok = 0;
  if (t >= 2) {
    int p = t - 2;
    if (p < tl[b]) tok = text[offs[b] + p] + 1;
  }
  float4 v = *(const float4*)(ce + (size_t)tok * NC + threadIdx.x * 4);
  *(float4*)(x + (size_t)bid * XDIM + NC + threadIdx.x * 4) = v;
}

// f32 -> bf16 bulk convert (n4 = count/4)
__global__ __launch_bounds__(256) void cvtbf_kernel(const float* __restrict__ in,
                                                    ushort* __restrict__ out, int n4) {
  int i = blockIdx.x * 256 + threadIdx.x;
  if (i >= n4) return;
  float4 v = ((const float4*)in)[i];
  ushort4 o;
  o.x = (ushort)f2bf(v.x); o.y = (ushort)f2bf(v.y);
  o.z = (ushort)f2bf(v.z); o.w = (ushort)f2bf(v.w);
  ((ushort4*)out)[i] = o;
}

// ---------------------------------------------------------------------------
// recurrence weight pack: f32 [g][j][k] -> f16 k-pair layout [g][k2g][j][q]
// ---------------------------------------------------------------------------
__global__ __launch_bounds__(64) void lstm_pack_kernel(
    const float* __restrict__ Wf, const float* __restrict__ Wb,
    uint32_t* __restrict__ Wp) {
  int row = blockIdx.x;                 // (dir*4+g)*256 + j
  int dg = row >> 8, j = row & 255;     // dg = dir*4+g
  int dir = dg >> 2;
  const float* W = (dir ? Wb : Wf) + ((size_t)(dg & 3) * HL + j) * HL;
  int l = threadIdx.x;
  float4 v = *(const float4*)(W + l * 4);
  uint32_t p0 = f2h(v.x) | (f2h(v.y) << 16);   // k2 = 2l
  uint32_t p1 = f2h(v.z) | (f2h(v.w) << 16);   // k2 = 2l+1
  int k2g = l >> 1, q0 = (2 * l) & 3;
  size_t base = ((size_t)dg * 32 + k2g) * 1024 + j * 4;
  Wp[base + q0] = p0;
  Wp[base + q0 + 1] = p1;
}

__global__ __launch_bounds__(128) void gru_pack_kernel(
    const float* __restrict__ W, uint32_t* __restrict__ Wp) {
  int row = blockIdx.x;                 // g*512 + j
  int g = row >> 9, j = row & 511;
  const float* Wr = W + ((size_t)g * NC + j) * NC;
  int l = threadIdx.x;
  float4 v = *(const float4*)(Wr + l * 4);
  uint32_t p0 = f2h(v.x) | (f2h(v.y) << 16);
  uint32_t p1 = f2h(v.z) | (f2h(v.w) << 16);
  int k2g = l >> 1, q0 = (2 * l) & 3;
  size_t base = ((size_t)g * 64 + k2g) * 2048 + j * 4;
  Wp[base + q0] = p0;
  Wp[base + q0 + 1] = p1;
}

// ---------------------------------------------------------------------------
// generic f32 SGEMM (pool only now): 128x128 tile, 8x8/thread, BK=16.
// ---------------------------------------------------------------------------
__global__ __launch_bounds__(256) void sgemm_kernel(
    int M, int N, int K,
    const float* __restrict__ A, int lda, long Abstride,
    const int* __restrict__ rowmap,
    const float* __restrict__ B, int ldb, long Bbstride,
    const float* __restrict__ bscale, int bscaleBstride,
    const float* __restrict__ bias,
    float* __restrict__ out, long ldoM, long ldoN, long Obstride) {
  const int batch = blockIdx.z;
  A += (long)batch * Abstride;
  B += (long)batch * Bbstride;
  out += (long)batch * Obstride;
  const float* bsc = bscale ? bscale + (long)batch * bscaleBstride : nullptr;

  __shared__ __align__(16) float As[16][132];
  __shared__ __align__(16) float Bs[16][132];

  const int m0 = blockIdx.y * 128, n0 = blockIdx.x * 128;
  const int tid = threadIdx.x;
  const int tm = tid >> 4, tn = tid & 15;
  const int r0 = tm * 8, c0 = tn * 4;
  float acc[8][8] = {};
  float4 pa[2], pb[2];

  auto fetch = [&](int k0) {
#pragma unroll
    for (int it = 0; it < 2; ++it) {
      int ch = tid + it * 256;
      int mm = ch >> 2;
      int kq = (ch & 3) << 2;
      int gm = m0 + mm;
      float4 v = make_float4(0.f, 0.f, 0.f, 0.f);
      if (gm < M) {
        long ar = rowmap ? (long)rowmap[gm] : (long)gm;
        v = *(const float4*)(A + ar * lda + k0 + kq);
      }
      pa[it] = v;
      int gn = n0 + mm;
      v = make_float4(0.f, 0.f, 0.f, 0.f);
      if (gn < N) {
        v = *(const float4*)(B + (long)gn * ldb + k0 + kq);
        if (bsc) { float s = bsc[gn]; v.x *= s; v.y *= s; v.z *= s; v.w *= s; }
      }
      pb[it] = v;
    }
  };

  auto store_lds = [&]() {
#pragma unroll
    for (int it = 0; it < 2; ++it) {
      int ch = tid + it * 256;
      int mm = ch >> 2;
      int kq = (ch & 3) << 2;
      As[kq + 0][mm] = pa[it].x; As[kq + 1][mm] = pa[it].y;
      As[kq + 2][mm] = pa[it].z; As[kq + 3][mm] = pa[it].w;
      Bs[kq + 0][mm] = pb[it].x; Bs[kq + 1][mm] = pb[it].y;
      Bs[kq + 2][mm] = pb[it].z; Bs[kq + 3][mm] = pb[it].w;
    }
  };

  fetch(0);
  for (int k0 = 0; k0 < K; k0 += 16) {
    store_lds();
    __syncthreads();
    if (k0 + 16 < K) fetch(k0 + 16);
#pragma unroll
    for (int kk = 0; kk < 16; ++kk) {
      float a[8], bb[8];
      *(float4*)&a[0] = *(const float4*)&As[kk][r0];
      *(float4*)&a[4] = *(const float4*)&As[kk][r0 + 4];
      *(float4*)&bb[0] = *(const float4*)&Bs[kk][c0];
      *(float4*)&bb[4] = *(const float4*)&Bs[kk][c0 + 64];
#pragma unroll
      for (int i = 0; i < 8; ++i)
#pragma unroll
        for (int j = 0; j < 8; ++j) acc[i][j] += a[i] * bb[j];
    }
    __syncthreads();
  }
#pragma unroll
  for (int i = 0; i < 8; ++i) {
    int gm = m0 + r0 + i;
    if (gm >= M) continue;
#pragma unroll
    for (int j = 0; j < 8; ++j) {
      int gn = n0 + c0 + (j & 3) + ((j >> 2) << 6);
      if (gn >= N) continue;
      float v = acc[i][j];
      if (bias) v += bias[gn];
      out[(long)gm * ldoM + (long)gn * ldoN] = v;
    }
  }
}

// ---------------------------------------------------------------------------
// bf16 MFMA GEMM: out[m][n] = A[m]·B[n] + bias[n].
// A bf16 [M][K] (rows via rowmap), B bf16 [N][K]. 128x128 tile, 4 waves 2x2,
// 16x16x32 mfma, LDS stride 40 elems (80B -> 2-way bank aliasing only).
// out f32 or bf16 (outBf).
// ---------------------------------------------------------------------------
#define MG_LDT 40

__global__ __launch_bounds__(256) void mgemm_kernel(
    int M, int N, int K,
    const ushort* __restrict__ A, const int* __restrict__ rowmap,
    const ushort* __restrict__ B, const float* __restrict__ bias,
    void* __restrict__ outp, long ldo, int outBf) {
  __shared__ __align__(16) ushort Al[128 * MG_LDT];
  __shared__ __align__(16) ushort Bl[128 * MG_LDT];
  const int m0 = blockIdx.y * 128, n0 = blockIdx.x * 128;
  const int tid = threadIdx.x;
  const int lane = tid & 63, wid = tid >> 6;
  const int wm = (wid >> 1) * 64, wn = (wid & 1) * 64;
  const int lr = lane & 15, lk = lane >> 4;

  f32x4_ acc[4][4];
#pragma unroll
  for (int i = 0; i < 4; ++i)
#pragma unroll
    for (int j = 0; j < 4; ++j) {
      acc[i][j][0] = 0.f; acc[i][j][1] = 0.f;
      acc[i][j][2] = 0.f; acc[i][j][3] = 0.f;
    }

  for (int k0 = 0; k0 < K; k0 += 32) {
    __syncthreads();
#pragma unroll
    for (int it = 0; it < 2; ++it) {
      int ch = tid + it * 256;          // 0..511
      int rr = ch >> 2, kq = (ch & 3) * 8;
      int gm = m0 + rr; if (gm >= M) gm = M - 1;
      long ar = rowmap ? (long)rowmap[gm] : (long)gm;
      uint4 av = *(const uint4*)(A + ar * K + k0 + kq);
      int gn = n0 + rr; if (gn >= N) gn = N - 1;
      uint4 bv = *(const uint4*)(B + (long)gn * K + k0 + kq);
      *(uint4*)&Al[rr * MG_LDT + kq] = av;
      *(uint4*)&Bl[rr * MG_LDT + kq] = bv;
    }
    __syncthreads();
    s16x8 af[4], bf[4];
#pragma unroll
    for (int i = 0; i < 4; ++i)
      af[i] = *(const s16x8*)&Al[(wm + i * 16 + lr) * MG_LDT + lk * 8];
#pragma unroll
    for (int i = 0; i < 4; ++i)
      bf[i] = *(const s16x8*)&Bl[(wn + i * 16 + lr) * MG_LDT + lk * 8];
#pragma unroll
    for (int i = 0; i < 4; ++i)
#pragma unroll
      for (int j = 0; j < 4; ++j)
        acc[i][j] = __builtin_amdgcn_mfma_f32_16x16x32_bf16(af[i], bf[j], acc[i][j], 0, 0, 0);
  }

#pragma unroll
  for (int i = 0; i < 4; ++i) {
#pragma unroll
    for (int j = 0; j < 4; ++j) {
      int n = n0 + wn + j * 16 + lr;
      if (n >= N) continue;
      float bv = bias ? bias[n] : 0.f;
#pragma unroll
      for (int r = 0; r < 4; ++r) {
        int m = m0 + wm + i * 16 + lk * 4 + r;
        if (m >= M) continue;
        float v = acc[i][j][r] + bv;
        if (outBf) ((ushort*)outp)[(long)m * ldo + n] = (ushort)f2bf(v);
        else       ((float*)outp)[(long)m * ldo + n] = v;
      }
    }
  }
}

// ---------------------------------------------------------------------------
// b-split recurrences (R7 structure, unchanged except GRU reads bf16 xg)
// ---------------------------------------------------------------------------
__global__ __launch_bounds__(512) void lstm_bsplit_kernel(
    const float* __restrict__ xg_f, const float* __restrict__ xg_b,
    const uint32_t* __restrict__ Wp,
    const float* __restrict__ bhh_f, const float* __restrict__ bhh_b,
    float* __restrict__ x) {
  const int dir = blockIdx.x >> 6, bp = blockIdx.x & 63;
  const float* xg = dir ? xg_b : xg_f;
  const float* bhh = dir ? bhh_b : bhh_f;
  const int j = threadIdx.x & 255;
  const int kh = threadIdx.x >> 8;
  const int gb = bp * 2 + kh;

  __shared__ __align__(16) ushort hh16[2][2][HL];  // [ping][b][j]
  __shared__ float part[2][4][2][HL];              // [b][g][kh][j]
  hh16[0][kh][j] = 0;
  float c = 0.f;
  const float bb0 = bhh[j], bb1 = bhh[HL + j], bb2 = bhh[2 * HL + j], bb3 = bhh[3 * HL + j];

  const uint32_t* wg0 = Wp + ((size_t)(dir * 4 + 0) * 32) * 1024 + j * 4;
  const uint32_t* wg1 = Wp + ((size_t)(dir * 4 + 1) * 32) * 1024 + j * 4;
  const uint32_t* wg2 = Wp + ((size_t)(dir * 4 + 2) * 32) * 1024 + j * 4;
  const uint32_t* wg3 = Wp + ((size_t)(dir * 4 + 3) * 32) * 1024 + j * 4;
  __syncthreads();

  for (int s = 0; s < NT; ++s) {
    const int t = dir ? (NT - 1 - s) : s;
    const long row = (long)t * NB + gb;
    float xi = xg[row * G4 + j];
    float xf = xg[row * G4 + HL + j];
    float xgg = xg[row * G4 + 2 * HL + j];
    float xo = xg[row * G4 + 3 * HL + j];
    const int p = s & 1;
    float a00 = 0.f, a10 = 0.f, a20 = 0.f, a30 = 0.f;
    float a01 = 0.f, a11 = 0.f, a21 = 0.f, a31 = 0.f;
#pragma unroll 4
    for (int k2g = kh * 16; k2g < kh * 16 + 16; ++k2g) {
      uint4 h0 = *(const uint4*)&hh16[p][0][8 * k2g];
      uint4 h1 = *(const uint4*)&hh16[p][1][8 * k2g];
      uint4 w0 = *(const uint4*)(wg0 + (size_t)k2g * 1024);
      uint4 w1 = *(const uint4*)(wg1 + (size_t)k2g * 1024);
      uint4 w2 = *(const uint4*)(wg2 + (size_t)k2g * 1024);
      uint4 w3 = *(const uint4*)(wg3 + (size_t)k2g * 1024);
      a00 = dot2(w0.x, h0.x, a00); a00 = dot2(w0.y, h0.y, a00);
      a00 = dot2(w0.z, h0.z, a00); a00 = dot2(w0.w, h0.w, a00);
      a01 = dot2(w0.x, h1.x, a01); a01 = dot2(w0.y, h1.y, a01);
      a01 = dot2(w0.z, h1.z, a01); a01 = dot2(w0.w, h1.w, a01);
      a10 = dot2(w1.x, h0.x, a10); a10 = dot2(w1.y, h0.y, a10);
      a10 = dot2(w1.z, h0.z, a10); a10 = dot2(w1.w, h0.w, a10);
      a11 = dot2(w1.x, h1.x, a11); a11 = dot2(w1.y, h1.y, a11);
      a11 = dot2(w1.z, h1.z, a11); a11 = dot2(w1.w, h1.w, a11);
      a20 = dot2(w2.x, h0.x, a20); a20 = dot2(w2.y, h0.y, a20);
      a20 = dot2(w2.z, h0.z, a20); a20 = dot2(w2.w, h0.w, a20);
      a21 = dot2(w2.x, h1.x, a21); a21 = dot2(w2.y, h1.y, a21);
      a21 = dot2(w2.z, h1.z, a21); a21 = dot2(w2.w, h1.w, a21);
      a30 = dot2(w3.x, h0.x, a30); a30 = dot2(w3.y, h0.y, a30);
      a30 = dot2(w3.z, h0.z, a30); a30 = dot2(w3.w, h0.w, a30);
      a31 = dot2(w3.x, h1.x, a31); a31 = dot2(w3.y, h1.y, a31);
      a31 = dot2(w3.z, h1.z, a31); a31 = dot2(w3.w, h1.w, a31);
    }
    part[0][0][kh][j] = a00; part[0][1][kh][j] = a10;
    part[0][2][kh][j] = a20; part[0][3][kh][j] = a30;
    part[1][0][kh][j] = a01; part[1][1][kh][j] = a11;
    part[1][2][kh][j] = a21; part[1][3][kh][j] = a31;
    __syncthreads();
    const int b = kh;
    float gi = xi + part[b][0][0][j] + part[b][0][1][j] + bb0;
    float gf = xf + part[b][1][0][j] + part[b][1][1][j] + bb1;
    float gg = xgg + part[b][2][0][j] + part[b][2][1][j] + bb2;
    float go = xo + part[b][3][0][j] + part[b][3][1][j] + bb3;
    c = sigm(gf) * c + sigm(gi) * tanhf(gg);
    float hn = sigm(go) * tanhf(c);
    x[row * XDIM + dir * HL + j] = hn;
    hh16[p ^ 1][b][j] = f2hs(hn);
    __syncthreads();
  }
}

// grid = 64 (bpair), 1024 threads (kh = tid>>9, j = tid&511); xg is bf16 now
__global__ __launch_bounds__(1024) void gru_bsplit_kernel(
    const ushort* __restrict__ xg, const uint32_t* __restrict__ Wp,
    const float* __restrict__ bhh, float* __restrict__ gout) {
  const int bp = blockIdx.x;
  const int j = threadIdx.x & 511;
  const int kh = threadIdx.x >> 9;
  const int gb = bp * 2 + kh;

  __shared__ __align__(16) ushort hh16[2][2][NC];
  __shared__ float part[2][3][2][NC];
  hh16[0][kh][j] = 0;
  float hreg = 0.f;
  const float bb0 = bhh[j], bb1 = bhh[NC + j], bb2 = bhh[2 * NC + j];

  const uint32_t* wr = Wp + j * 4;
  const uint32_t* wz = Wp + (size_t)1 * 64 * 2048 + j * 4;
  const uint32_t* wn = Wp + (size_t)2 * 64 * 2048 + j * 4;
  __syncthreads();

  for (int t = 0; t < NT; ++t) {
    const long row = (long)t * NB + gb;
    float xr = bf2f(xg[row * G3 + j]);
    float xz = bf2f(xg[row * G3 + NC + j]);
    float xn = bf2f(xg[row * G3 + 2 * NC + j]);
    const int p = t & 1;
    float ar0 = 0.f, az0 = 0.f, an0 = 0.f;
    float ar1 = 0.f, az1 = 0.f, an1 = 0.f;
#pragma unroll 4
    for (int k2g = kh * 32; k2g < kh * 32 + 32; ++k2g) {
      uint4 h0 = *(const uint4*)&hh16[p][0][8 * k2g];
      uint4 h1 = *(const uint4*)&hh16[p][1][8 * k2g];
      uint4 w0 = *(const uint4*)(wr + (size_t)k2g * 2048);
      uint4 w1 = *(const uint4*)(wz + (size_t)k2g * 2048);
      uint4 w2 = *(const uint4*)(wn + (size_t)k2g * 2048);
      ar0 = dot2(w0.x, h0.x, ar0); ar0 = dot2(w0.y, h0.y, ar0);
      ar0 = dot2(w0.z, h0.z, ar0); ar0 = dot2(w0.w, h0.w, ar0);
      ar1 = dot2(w0.x, h1.x, ar1); ar1 = dot2(w0.y, h1.y, ar1);
      ar1 = dot2(w0.z, h1.z, ar1); ar1 = dot2(w0.w, h1.w, ar1);
      az0 = dot2(w1.x, h0.x, az0); az0 = dot2(w1.y, h0.y, az0);
      az0 = dot2(w1.z, h0.z, az0); az0 = dot2(w1.w, h0.w, az0);
      az1 = dot2(w1.x, h1.x, az1); az1 = dot2(w1.y, h1.y, az1);
      az1 = dot2(w1.z, h1.z, az1); az1 = dot2(w1.w, h1.w, az1);
      an0 = dot2(w2.x, h0.x, an0); an0 = dot2(w2.y, h0.y, an0);
      an0 = dot2(w2.z, h0.z, an0); an0 = dot2(w2.w, h0.w, an0);
      an1 = dot2(w2.x, h1.x, an1); an1 = dot2(w2.y, h1.y, an1);
      an1 = dot2(w2.z, h1.z, an1); an1 = dot2(w2.w, h1.w, an1);
    }
    part[0][0][kh][j] = ar0; part[0][1][kh][j] = az0; part[0][2][kh][j] = an0;
    part[1][0][kh][j] = ar1; part[1][1][kh][j] = az1; part[1][2][kh][j] = an1;
    __syncthreads();
    const int b = kh;
    float hr = part[b][0][0][j] + part[b][0][1][j] + bb0;
    float hz = part[b][1][0][j] + part[b][1][1][j] + bb1;
    float hn = part[b][2][0][j] + part[b][2][1][j] + bb2;
    float r = sigm(xr + hr);
    float z = sigm(xz + hz);
    float n = tanhf(xn + r * hn);
    float h = (1.f - z) * n + z * hreg;
    hreg = h;
    gout[row * NC + j] = h;
    hh16[p ^ 1][b][j] = f2hs(h);
    __syncthreads();
  }
}

// ---------------------------------------------------------------------------
extern "C" void kernel_launch(void* const* d_in, const int* in_sizes, int n_in,
                              void* d_out, int out_size, void* d_ws, size_t ws_size,
                              hipStream_t stream) {
  const float* feature = (const float*)d_in[0];
  const float* A       = (const float*)d_in[1];
  const int*   text    = (const int*)d_in[2];
  const int*   tlen    = (const int*)d_in[3];
  const float* Wih_f   = (const float*)d_in[4];
  const float* Whh_f   = (const float*)d_in[5];
  const float* bih_f   = (const float*)d_in[6];
  const float* bhh_f   = (const float*)d_in[7];
  const float* Wih_b   = (const float*)d_in[8];
  const float* Whh_b   = (const float*)d_in[9];
  const float* bih_b   = (const float*)d_in[10];
  const float* bhh_b   = (const float*)d_in[11];
  const float* gWih    = (const float*)d_in[12];
  const float* gWhh    = (const float*)d_in[13];
  const float* gbih    = (const float*)d_in[14];
  const float* gbhh    = (const float*)d_in[15];
  const float* genW    = (const float*)d_in[16];
  const float* genb    = (const float*)d_in[17];
  const float* cemb    = (const float*)d_in[18];
  float* out = (float*)d_out;
  const int total = in_sizes[2];

  char* ws = (char*)d_ws;
  size_t off = 0;
  auto alloc = [&](size_t bytes) -> void* {
    void* p = ws + off;
    off += (bytes + 255) & ~(size_t)255;
    return p;
  };
  float*    asum   = (float*)alloc((size_t)NB * NT * 4);
  int*      offs   = (int*)alloc(NB * 4);
  int*      rowmap = (int*)alloc((size_t)NB * NT * 4);
  float*    Cbuf   = (float*)alloc((size_t)NT * NB * NC * 4);    // pool C; later gru_out f32
  float*    xgf    = (float*)alloc((size_t)NT * NB * G4 * 4);    // lstm fwd xg; later gxg bf16
  float*    xgb    = (float*)alloc((size_t)NT * NB * G4 * 4);    // lstm bwd xg; later overlays
  float*    xbuf   = (float*)alloc((size_t)NT * NB * XDIM * 4);
  uint32_t* WpL    = (uint32_t*)alloc((size_t)2 * 4 * 32 * 256 * 4 * 4);  // 1 MB
  uint32_t* WpG    = (uint32_t*)alloc((size_t)3 * 64 * 512 * 4 * 4);      // 1.5 MB
  ushort*   Cbf    = (ushort*)alloc((size_t)NT * NB * NC * 2);   // C bf16; later gru_out bf16
  ushort*   Wihf_bf= (ushort*)alloc((size_t)G4 * NC * 2);        // 1 MB
  ushort*   Wihb_bf= (ushort*)alloc((size_t)G4 * NC * 2);        // 1 MB
  // overlays inside xgb (free after lstm_bsplit):
  ushort*   xbuf_bf = (ushort*)xgb;                               // 10.5 MB
  ushort*   gWih_bf = (ushort*)((char*)xgb + (11u << 20));        // 3 MB
  ushort*   genW_bf = (ushort*)((char*)xgb + (size_t)(14.5 * (1 << 20)));  // 5.12 MB
  ushort*   gxg     = (ushort*)xgf;                               // bf16 [5120][1536]
  float*    gout    = Cbuf;
  ushort*   gout_bf = Cbf;

  // --- setup + recurrence weight packing + lstm weight converts ---
  offsets_kernel<<<1, 64, 0, stream>>>(tlen, offs);
  rowmap_kernel<<<NB, 64, 0, stream>>>(tlen, offs, rowmap);
  asum_kernel<<<NB * NT, 64, 0, stream>>>(A, asum);
  lstm_pack_kernel<<<2048, 64, 0, stream>>>(Whh_f, Whh_b, WpL);
  gru_pack_kernel<<<1536, 128, 0, stream>>>(gWhh, WpG);
  cvtbf_kernel<<<512, 256, 0, stream>>>(Wih_f, Wihf_bf, G4 * NC / 4);
  cvtbf_kernel<<<512, 256, 0, stream>>>(Wih_b, Wihb_bf, G4 * NC / 4);

  // --- attention pooling (f32, small N) ---
  sgemm_kernel<<<dim3(1, 4, NB), 256, 0, stream>>>(
      NC, NT, HW,
      feature, HW, (long)NC * HW, nullptr,
      A, HW, (long)NT * HW,
      asum, NT, nullptr,
      Cbuf, 1L, (long)NB * NC, (long)NC);

  // --- LSTM input projections via MFMA ---
  cvtbf_kernel<<<2560, 256, 0, stream>>>(Cbuf, Cbf, NT * NB * NC / 4);
  mgemm_kernel<<<dim3(G4 / 128, NT * NB / 128), 256, 0, stream>>>(
      NT * NB, G4, NC, Cbf, nullptr, Wihf_bf, bih_f, xgf, (long)G4, 0);
  mgemm_kernel<<<dim3(G4 / 128, NT * NB / 128), 256, 0, stream>>>(
      NT * NB, G4, NC, Cbf, nullptr, Wihb_bf, bih_b, xgb, (long)G4, 0);

  // --- LSTM recurrence (one launch, batch-pair blocks) ---
  lstm_bsplit_kernel<<<128, 512, 0, stream>>>(
      xgf, xgb, WpL, bhh_f, bhh_b, xbuf);

  // --- embedding into x[:,:,512:1024] ---
  emb_kernel<<<NT * NB, 128, 0, stream>>>(cemb, text, tlen, offs, xbuf);

  // --- GRU input projection via MFMA (xgb now free -> overlays) ---
  cvtbf_kernel<<<5120, 256, 0, stream>>>(xbuf, xbuf_bf, NT * NB * XDIM / 4);
  cvtbf_kernel<<<1536, 256, 0, stream>>>(gWih, gWih_bf, G3 * XDIM / 4);
  cvtbf_kernel<<<2500, 256, 0, stream>>>(genW, genW_bf, NG * NC / 4);
  mgemm_kernel<<<dim3(G3 / 128, NT * NB / 128), 256, 0, stream>>>(
      NT * NB, G3, XDIM, xbuf_bf, nullptr, gWih_bf, gbih, gxg, (long)G3, 1);

  // --- GRU recurrence ---
  gru_bsplit_kernel<<<64, 1024, 0, stream>>>(gxg, WpG, gbhh, gout);

  // --- vocab projection via MFMA, ragged rows straight into d_out ---
  cvtbf_kernel<<<2560, 256, 0, stream>>>(gout, gout_bf, NT * NB * NC / 4);
  mgemm_kernel<<<dim3((NG + 127) / 128, (total + 127) / 128), 256, 0, stream>>>(
      total, NG, NC, gout_bf, rowmap, genW_bf, genb, out, (long)NG, 0);
}

// Round 9
// 849.045 us; speedup vs baseline: 4.8307x; 1.1781x over previous
//
#include <hip/hip_runtime.h>
#include <hip/hip_bf16.h>
#include <hip/hip_fp16.h>
#include <math.h>

#define NB 128     // batch
#define NC 512     // channels
#define NT 40      // time steps
#define HW 512     // nH*nW
#define HL 256     // LSTM hidden per direction
#define NG 5000    // nclass
#define XDIM 1024  // 2*NC (GRU input)
#define G4 1024    // 4*HL
#define G3 1536    // 3*NC

typedef _Float16 half2v __attribute__((ext_vector_type(2)));
typedef _Float16 f16x8 __attribute__((ext_vector_type(8)));
typedef short s16x8 __attribute__((ext_vector_type(8)));
typedef float f32x4_ __attribute__((ext_vector_type(4)));

__device__ __forceinline__ float dot2(uint32_t w, uint32_t h, float acc) {
#if __has_builtin(__builtin_amdgcn_fdot2)
  return __builtin_amdgcn_fdot2(__builtin_bit_cast(half2v, w),
                                __builtin_bit_cast(half2v, h), acc, false);
#else
  half2v wv = __builtin_bit_cast(half2v, w), hv = __builtin_bit_cast(half2v, h);
  return acc + (float)wv.x * (float)hv.x + (float)wv.y * (float)hv.y;
#endif
}

__device__ __forceinline__ float sigm(float x) { return 1.f / (1.f + expf(-x)); }
__device__ __forceinline__ ushort f2hs(float f) {
  _Float16 h = (_Float16)f;
  return __builtin_bit_cast(ushort, h);
}
__device__ __forceinline__ uint32_t f2h(float f) { return (uint32_t)f2hs(f); }
__device__ __forceinline__ uint32_t f2bf(float f) {
  uint32_t u = __float_as_uint(f);
  return (u + 0x7fffu + ((u >> 16) & 1u)) >> 16;
}
__device__ __forceinline__ float bf2f(ushort u) {
  return __uint_as_float((uint32_t)u << 16);
}

// ---------------------------------------------------------------------------
// device-wide group barrier (R2-proven pattern; groups must be co-resident)
// ---------------------------------------------------------------------------
__device__ __forceinline__ void gbar(int* bar, int* gen, int nb, int step) {
  __syncthreads();
  if (threadIdx.x == 0) {
    __threadfence();  // release own h stores
    int a = __hip_atomic_fetch_add(bar, 1, __ATOMIC_RELAXED, __HIP_MEMORY_SCOPE_AGENT);
    if (a == nb * step - 1) {
      __hip_atomic_store(gen, step, __ATOMIC_RELEASE, __HIP_MEMORY_SCOPE_AGENT);
    } else {
      while (__hip_atomic_load(gen, __ATOMIC_RELAXED, __HIP_MEMORY_SCOPE_AGENT) < step) {
        __builtin_amdgcn_s_sleep(1);
      }
    }
    __threadfence();  // acquire others' h stores
  }
  __syncthreads();
}

// ---------------------------------------------------------------------------
// small setup kernels
// ---------------------------------------------------------------------------
__global__ void offsets_kernel(const int* __restrict__ tl, int* __restrict__ offs) {
  if (threadIdx.x == 0) {
    int o = 0;
    for (int b = 0; b < NB; ++b) { offs[b] = o; o += tl[b]; }
  }
}

__global__ void rowmap_kernel(const int* __restrict__ tl, const int* __restrict__ offs,
                              int* __restrict__ rowmap) {
  int b = blockIdx.x;
  int len = tl[b], off = offs[b];
  for (int t = threadIdx.x; t < len; t += blockDim.x)
    rowmap[off + t] = t * NB + b;   // row index into [t][b][*] matrices
}

__global__ void zero_kernel(int* __restrict__ p, int n) {
  int i = blockIdx.x * 256 + threadIdx.x;
  if (i < n) p[i] = 0;
}

// 1/sum over HW per (b,t)
__global__ __launch_bounds__(64) void asum_kernel(const float* __restrict__ A,
                                                  float* __restrict__ out) {
  int row = blockIdx.x;  // b*NT + t
  const float* p = A + (size_t)row * HW;
  float s = 0.f;
#pragma unroll
  for (int i = 0; i < 8; ++i) s += p[threadIdx.x + i * 64];
#pragma unroll
  for (int off = 32; off > 0; off >>= 1) s += __shfl_down(s, off);
  if (threadIdx.x == 0) out[row] = 1.0f / s;
}

// teacher-forcing embedding into x[:,:,512:1024]
__global__ __launch_bounds__(128) void emb_kernel(const float* __restrict__ ce,
                                                  const int* __restrict__ text,
                                                  const int* __restrict__ tl,
                                                  const int* __restrict__ offs,
                                                  float* __restrict__ x) {
  int bid = blockIdx.x;  // t*NB + b
  int t = bid >> 7, b = bid & 127;
  int tok = 0;
  if (t >= 2) {
    int p = t - 2;
    if (p < tl[b]) tok = text[offs[b] + p] + 1;
  }
  float4 v = *(const float4*)(ce + (size_t)tok * NC + threadIdx.x * 4);
  *(float4*)(x + (size_t)bid * XDIM + NC + threadIdx.x * 4) = v;
}

// f32 -> bf16 bulk convert (n4 = count/4)
__global__ __launch_bounds__(256) void cvtbf_kernel(const float* __restrict__ in,
                                                    ushort* __restrict__ out, int n4) {
  int i = blockIdx.x * 256 + threadIdx.x;
  if (i >= n4) return;
  float4 v = ((const float4*)in)[i];
  ushort4 o;
  o.x = (ushort)f2bf(v.x); o.y = (ushort)f2bf(v.y);
  o.z = (ushort)f2bf(v.z); o.w = (ushort)f2bf(v.w);
  ((ushort4*)out)[i] = o;
}

// f32 -> f16 bulk convert (n4 = count/4)
__global__ __launch_bounds__(256) void cvtf16_kernel(const float* __restrict__ in,
                                                     ushort* __restrict__ out, int n4) {
  int i = blockIdx.x * 256 + threadIdx.x;
  if (i >= n4) return;
  float4 v = ((const float4*)in)[i];
  ushort4 o;
  o.x = f2hs(v.x); o.y = f2hs(v.y); o.z = f2hs(v.z); o.w = f2hs(v.w);
  ((ushort4*)out)[i] = o;
}

// ---------------------------------------------------------------------------
// LSTM recurrence weight pack: f32 [g][j][k] -> f16 k-pair [g][k2g][j][q]
// ---------------------------------------------------------------------------
__global__ __launch_bounds__(64) void lstm_pack_kernel(
    const float* __restrict__ Wf, const float* __restrict__ Wb,
    uint32_t* __restrict__ Wp) {
  int row = blockIdx.x;                 // (dir*4+g)*256 + j
  int dg = row >> 8, j = row & 255;     // dg = dir*4+g
  int dir = dg >> 2;
  const float* W = (dir ? Wb : Wf) + ((size_t)(dg & 3) * HL + j) * HL;
  int l = threadIdx.x;
  float4 v = *(const float4*)(W + l * 4);
  uint32_t p0 = f2h(v.x) | (f2h(v.y) << 16);   // k2 = 2l
  uint32_t p1 = f2h(v.z) | (f2h(v.w) << 16);   // k2 = 2l+1
  int k2g = l >> 1, q0 = (2 * l) & 3;
  size_t base = ((size_t)dg * 32 + k2g) * 1024 + j * 4;
  Wp[base + q0] = p0;
  Wp[base + q0 + 1] = p1;
}

// ---------------------------------------------------------------------------
// generic f32 SGEMM (pool only): 128x128 tile, 8x8/thread, BK=16.
// ---------------------------------------------------------------------------
__global__ __launch_bounds__(256) void sgemm_kernel(
    int M, int N, int K,
    const float* __restrict__ A, int lda, long Abstride,
    const int* __restrict__ rowmap,
    const float* __restrict__ B, int ldb, long Bbstride,
    const float* __restrict__ bscale, int bscaleBstride,
    const float* __restrict__ bias,
    float* __restrict__ out, long ldoM, long ldoN, long Obstride) {
  const int batch = blockIdx.z;
  A += (long)batch * Abstride;
  B += (long)batch * Bbstride;
  out += (long)batch * Obstride;
  const float* bsc = bscale ? bscale + (long)batch * bscaleBstride : nullptr;

  __shared__ __align__(16) float As[16][132];
  __shared__ __align__(16) float Bs[16][132];

  const int m0 = blockIdx.y * 128, n0 = blockIdx.x * 128;
  const int tid = threadIdx.x;
  const int tm = tid >> 4, tn = tid & 15;
  const int r0 = tm * 8, c0 = tn * 4;
  float acc[8][8] = {};
  float4 pa[2], pb[2];

  auto fetch = [&](int k0) {
#pragma unroll
    for (int it = 0; it < 2; ++it) {
      int ch = tid + it * 256;
      int mm = ch >> 2;
      int kq = (ch & 3) << 2;
      int gm = m0 + mm;
      float4 v = make_float4(0.f, 0.f, 0.f, 0.f);
      if (gm < M) {
        long ar = rowmap ? (long)rowmap[gm] : (long)gm;
        v = *(const float4*)(A + ar * lda + k0 + kq);
      }
      pa[it] = v;
      int gn = n0 + mm;
      v = make_float4(0.f, 0.f, 0.f, 0.f);
      if (gn < N) {
        v = *(const float4*)(B + (long)gn * ldb + k0 + kq);
        if (bsc) { float s = bsc[gn]; v.x *= s; v.y *= s; v.z *= s; v.w *= s; }
      }
      pb[it] = v;
    }
  };

  auto store_lds = [&]() {
#pragma unroll
    for (int it = 0; it < 2; ++it) {
      int ch = tid + it * 256;
      int mm = ch >> 2;
      int kq = (ch & 3) << 2;
      As[kq + 0][mm] = pa[it].x; As[kq + 1][mm] = pa[it].y;
      As[kq + 2][mm] = pa[it].z; As[kq + 3][mm] = pa[it].w;
      Bs[kq + 0][mm] = pb[it].x; Bs[kq + 1][mm] = pb[it].y;
      Bs[kq + 2][mm] = pb[it].z; Bs[kq + 3][mm] = pb[it].w;
    }
  };

  fetch(0);
  for (int k0 = 0; k0 < K; k0 += 16) {
    store_lds();
    __syncthreads();
    if (k0 + 16 < K) fetch(k0 + 16);
#pragma unroll
    for (int kk = 0; kk < 16; ++kk) {
      float a[8], bb[8];
      *(float4*)&a[0] = *(const float4*)&As[kk][r0];
      *(float4*)&a[4] = *(const float4*)&As[kk][r0 + 4];
      *(float4*)&bb[0] = *(const float4*)&Bs[kk][c0];
      *(float4*)&bb[4] = *(const float4*)&Bs[kk][c0 + 64];
#pragma unroll
      for (int i = 0; i < 8; ++i)
#pragma unroll
        for (int j = 0; j < 8; ++j) acc[i][j] += a[i] * bb[j];
    }
    __syncthreads();
  }
#pragma unroll
  for (int i = 0; i < 8; ++i) {
    int gm = m0 + r0 + i;
    if (gm >= M) continue;
#pragma unroll
    for (int j = 0; j < 8; ++j) {
      int gn = n0 + c0 + (j & 3) + ((j >> 2) << 6);
      if (gn >= N) continue;
      float v = acc[i][j];
      if (bias) v += bias[gn];
      out[(long)gm * ldoM + (long)gn * ldoN] = v;
    }
  }
}

// ---------------------------------------------------------------------------
// bf16 MFMA GEMM (projections): 128x128 tile, 4 waves 2x2, 16x16x32 mfma.
// ---------------------------------------------------------------------------
#define MG_LDT 40

__global__ __launch_bounds__(256) void mgemm_kernel(
    int M, int N, int K,
    const ushort* __restrict__ A, const int* __restrict__ rowmap,
    const ushort* __restrict__ B, const float* __restrict__ bias,
    void* __restrict__ outp, long ldo, int outBf) {
  __shared__ __align__(16) ushort Al[128 * MG_LDT];
  __shared__ __align__(16) ushort Bl[128 * MG_LDT];
  const int m0 = blockIdx.y * 128, n0 = blockIdx.x * 128;
  const int tid = threadIdx.x;
  const int lane = tid & 63, wid = tid >> 6;
  const int wm = (wid >> 1) * 64, wn = (wid & 1) * 64;
  const int lr = lane & 15, lk = lane >> 4;

  f32x4_ acc[4][4];
#pragma unroll
  for (int i = 0; i < 4; ++i)
#pragma unroll
    for (int j = 0; j < 4; ++j) {
      acc[i][j][0] = 0.f; acc[i][j][1] = 0.f;
      acc[i][j][2] = 0.f; acc[i][j][3] = 0.f;
    }

  for (int k0 = 0; k0 < K; k0 += 32) {
    __syncthreads();
#pragma unroll
    for (int it = 0; it < 2; ++it) {
      int ch = tid + it * 256;          // 0..511
      int rr = ch >> 2, kq = (ch & 3) * 8;
      int gm = m0 + rr; if (gm >= M) gm = M - 1;
      long ar = rowmap ? (long)rowmap[gm] : (long)gm;
      uint4 av = *(const uint4*)(A + ar * K + k0 + kq);
      int gn = n0 + rr; if (gn >= N) gn = N - 1;
      uint4 bv = *(const uint4*)(B + (long)gn * K + k0 + kq);
      *(uint4*)&Al[rr * MG_LDT + kq] = av;
      *(uint4*)&Bl[rr * MG_LDT + kq] = bv;
    }
    __syncthreads();
    s16x8 af[4], bf[4];
#pragma unroll
    for (int i = 0; i < 4; ++i)
      af[i] = *(const s16x8*)&Al[(wm + i * 16 + lr) * MG_LDT + lk * 8];
#pragma unroll
    for (int i = 0; i < 4; ++i)
      bf[i] = *(const s16x8*)&Bl[(wn + i * 16 + lr) * MG_LDT + lk * 8];
#pragma unroll
    for (int i = 0; i < 4; ++i)
#pragma unroll
      for (int j = 0; j < 4; ++j)
        acc[i][j] = __builtin_amdgcn_mfma_f32_16x16x32_bf16(af[i], bf[j], acc[i][j], 0, 0, 0);
  }

#pragma unroll
  for (int i = 0; i < 4; ++i) {
#pragma unroll
    for (int j = 0; j < 4; ++j) {
      int n = n0 + wn + j * 16 + lr;
      if (n >= N) continue;
      float bv = bias ? bias[n] : 0.f;
#pragma unroll
      for (int r = 0; r < 4; ++r) {
        int m = m0 + wm + i * 16 + lk * 4 + r;
        if (m >= M) continue;
        float v = acc[i][j][r] + bv;
        if (outBf) ((ushort*)outp)[(long)m * ldo + n] = (ushort)f2bf(v);
        else       ((float*)outp)[(long)m * ldo + n] = v;
      }
    }
  }
}

// ---------------------------------------------------------------------------
// LSTM b-split recurrence (R8 structure, unchanged)
// ---------------------------------------------------------------------------
__global__ __launch_bounds__(512) void lstm_bsplit_kernel(
    const float* __restrict__ xg_f, const float* __restrict__ xg_b,
    const uint32_t* __restrict__ Wp,
    const float* __restrict__ bhh_f, const float* __restrict__ bhh_b,
    float* __restrict__ x) {
  const int dir = blockIdx.x >> 6, bp = blockIdx.x & 63;
  const float* xg = dir ? xg_b : xg_f;
  const float* bhh = dir ? bhh_b : bhh_f;
  const int j = threadIdx.x & 255;
  const int kh = threadIdx.x >> 8;
  const int gb = bp * 2 + kh;

  __shared__ __align__(16) ushort hh16[2][2][HL];  // [ping][b][j]
  __shared__ float part[2][4][2][HL];              // [b][g][kh][j]
  hh16[0][kh][j] = 0;
  float c = 0.f;
  const float bb0 = bhh[j], bb1 = bhh[HL + j], bb2 = bhh[2 * HL + j], bb3 = bhh[3 * HL + j];

  const uint32_t* wg0 = Wp + ((size_t)(dir * 4 + 0) * 32) * 1024 + j * 4;
  const uint32_t* wg1 = Wp + ((size_t)(dir * 4 + 1) * 32) * 1024 + j * 4;
  const uint32_t* wg2 = Wp + ((size_t)(dir * 4 + 2) * 32) * 1024 + j * 4;
  const uint32_t* wg3 = Wp + ((size_t)(dir * 4 + 3) * 32) * 1024 + j * 4;
  __syncthreads();

  for (int s = 0; s < NT; ++s) {
    const int t = dir ? (NT - 1 - s) : s;
    const long row = (long)t * NB + gb;
    float xi = xg[row * G4 + j];
    float xf = xg[row * G4 + HL + j];
    float xgg = xg[row * G4 + 2 * HL + j];
    float xo = xg[row * G4 + 3 * HL + j];
    const int p = s & 1;
    float a00 = 0.f, a10 = 0.f, a20 = 0.f, a30 = 0.f;
    float a01 = 0.f, a11 = 0.f, a21 = 0.f, a31 = 0.f;
#pragma unroll 4
    for (int k2g = kh * 16; k2g < kh * 16 + 16; ++k2g) {
      uint4 h0 = *(const uint4*)&hh16[p][0][8 * k2g];
      uint4 h1 = *(const uint4*)&hh16[p][1][8 * k2g];
      uint4 w0 = *(const uint4*)(wg0 + (size_t)k2g * 1024);
      uint4 w1 = *(const uint4*)(wg1 + (size_t)k2g * 1024);
      uint4 w2 = *(const uint4*)(wg2 + (size_t)k2g * 1024);
      uint4 w3 = *(const uint4*)(wg3 + (size_t)k2g * 1024);
      a00 = dot2(w0.x, h0.x, a00); a00 = dot2(w0.y, h0.y, a00);
      a00 = dot2(w0.z, h0.z, a00); a00 = dot2(w0.w, h0.w, a00);
      a01 = dot2(w0.x, h1.x, a01); a01 = dot2(w0.y, h1.y, a01);
      a01 = dot2(w0.z, h1.z, a01); a01 = dot2(w0.w, h1.w, a01);
      a10 = dot2(w1.x, h0.x, a10); a10 = dot2(w1.y, h0.y, a10);
      a10 = dot2(w1.z, h0.z, a10); a10 = dot2(w1.w, h0.w, a10);
      a11 = dot2(w1.x, h1.x, a11); a11 = dot2(w1.y, h1.y, a11);
      a11 = dot2(w1.z, h1.z, a11); a11 = dot2(w1.w, h1.w, a11);
      a20 = dot2(w2.x, h0.x, a20); a20 = dot2(w2.y, h0.y, a20);
      a20 = dot2(w2.z, h0.z, a20); a20 = dot2(w2.w, h0.w, a20);
      a21 = dot2(w2.x, h1.x, a21); a21 = dot2(w2.y, h1.y, a21);
      a21 = dot2(w2.z, h1.z, a21); a21 = dot2(w2.w, h1.w, a21);
      a30 = dot2(w3.x, h0.x, a30); a30 = dot2(w3.y, h0.y, a30);
      a30 = dot2(w3.z, h0.z, a30); a30 = dot2(w3.w, h0.w, a30);
      a31 = dot2(w3.x, h1.x, a31); a31 = dot2(w3.y, h1.y, a31);
      a31 = dot2(w3.z, h1.z, a31); a31 = dot2(w3.w, h1.w, a31);
    }
    part[0][0][kh][j] = a00; part[0][1][kh][j] = a10;
    part[0][2][kh][j] = a20; part[0][3][kh][j] = a30;
    part[1][0][kh][j] = a01; part[1][1][kh][j] = a11;
    part[1][2][kh][j] = a21; part[1][3][kh][j] = a31;
    __syncthreads();
    const int b = kh;
    float gi = xi + part[b][0][0][j] + part[b][0][1][j] + bb0;
    float gf = xf + part[b][1][0][j] + part[b][1][1][j] + bb1;
    float gg = xgg + part[b][2][0][j] + part[b][2][1][j] + bb2;
    float go = xo + part[b][3][0][j] + part[b][3][1][j] + bb3;
    c = sigm(gf) * c + sigm(gi) * tanhf(gg);
    float hn = sigm(go) * tanhf(c);
    x[row * XDIM + dir * HL + j] = hn;
    hh16[p ^ 1][b][j] = f2hs(hn);
    __syncthreads();
  }
}

// ---------------------------------------------------------------------------
// GRU sync recurrence: 64 blocks = 4 batch-groups x 16 j-chunks, 256 thr.
// W-chunk (3x32 j x 512 k, f16) resident in LDS; per-step f16 MFMA;
// h exchanged via global f16 ping-pong; 16-block group barrier per step.
// f32 h-carry in registers (static thread->(b,j) ownership).
// ---------------------------------------------------------------------------
__global__ __launch_bounds__(256) void gru_sync_kernel(
    const ushort* __restrict__ xg,    // bf16 [NT*NB][G3]
    const ushort* __restrict__ Wf,    // f16 [G3][NC]
    const float* __restrict__ bhh,
    ushort* __restrict__ hbuf,        // f16 [2][NB][NC]
    ushort* __restrict__ gout,        // bf16 [NT*NB][NC]
    int* __restrict__ bars) {
  const int bg = blockIdx.x >> 4, jc = blockIdx.x & 15;
  const int tid = threadIdx.x;
  const int lane = tid & 63, wid = tid >> 6;
  const int mt = wid >> 1, jsub = wid & 1;
  const int lr = lane & 15, lk = lane >> 4;

  __shared__ __align__(16) ushort Wl[16 * 96 * 40];  // [ktile][g*32+jj][40]

  // stage W chunk into LDS (one-time): 6144 uint4
  for (int i = tid; i < 6144; i += 256) {
    int kt = i / 384, rem = i - kt * 384;
    int row = rem >> 2, kq = rem & 3;
    int g = row >> 5, jj = row & 31;
    const ushort* src = Wf + ((size_t)(g * NC + jc * 32 + jj)) * NC + kt * 32 + kq * 8;
    *(uint4*)&Wl[(kt * 96 + row) * 40 + kq * 8] = *(const uint4*)src;
  }
  // zero own h slice in ping buffer 0
  for (int i = tid; i < 1024; i += 256) {
    int bb = i >> 5, jj = i & 31;
    hbuf[(size_t)(bg * 32 + bb) * NC + jc * 32 + jj] = 0;
  }
  int* bar = bars + bg * 32;
  int* gen = bar + 16;
  gbar(bar, gen, 16, 1);

  const int jg = jc * 32 + jsub * 16 + lr;   // this thread's global j
  const int bbase = bg * 32 + mt * 16;       // A/C m-tile batch base
  const float bb0 = bhh[jg], bb1 = bhh[NC + jg], bb2 = bhh[2 * NC + jg];
  float hreg[4] = {0.f, 0.f, 0.f, 0.f};

  for (int t = 0; t < NT; ++t) {
    const int p = t & 1;
    const ushort* hb = hbuf + (size_t)p * NB * NC;
    f32x4_ ar = {0.f, 0.f, 0.f, 0.f};
    f32x4_ az = {0.f, 0.f, 0.f, 0.f};
    f32x4_ an = {0.f, 0.f, 0.f, 0.f};
#pragma unroll
    for (int kt = 0; kt < 16; ++kt) {
      f16x8 a = *(const f16x8*)(hb + (size_t)(bbase + lr) * NC + kt * 32 + lk * 8);
      f16x8 br = *(const f16x8*)&Wl[(kt * 96 + 0  + jsub * 16 + lr) * 40 + lk * 8];
      f16x8 bz = *(const f16x8*)&Wl[(kt * 96 + 32 + jsub * 16 + lr) * 40 + lk * 8];
      f16x8 bn = *(const f16x8*)&Wl[(kt * 96 + 64 + jsub * 16 + lr) * 40 + lk * 8];
      ar = __builtin_amdgcn_mfma_f32_16x16x32_f16(a, br, ar, 0, 0, 0);
      az = __builtin_amdgcn_mfma_f32_16x16x32_f16(a, bz, az, 0, 0, 0);
      an = __builtin_amdgcn_mfma_f32_16x16x32_f16(a, bn, an, 0, 0, 0);
    }
    ushort* hw = hbuf + (size_t)(p ^ 1) * NB * NC;
#pragma unroll
    for (int r = 0; r < 4; ++r) {
      int b = bbase + lk * 4 + r;
      long row = (long)t * NB + b;
      float xr = bf2f(xg[row * G3 + jg]);
      float xz = bf2f(xg[row * G3 + NC + jg]);
      float xn = bf2f(xg[row * G3 + 2 * NC + jg]);
      float rr = sigm(xr + ar[r] + bb0);
      float zz = sigm(xz + az[r] + bb1);
      float nn = tanhf(xn + rr * (an[r] + bb2));
      float h = (1.f - zz) * nn + zz * hreg[r];
      hreg[r] = h;
      hw[(size_t)b * NC + jg] = f2hs(h);
      gout[row * NC + jg] = (ushort)f2bf(h);
    }
    gbar(bar, gen, 16, t + 2);
  }
}

// ---------------------------------------------------------------------------
extern "C" void kernel_launch(void* const* d_in, const int* in_sizes, int n_in,
                              void* d_out, int out_size, void* d_ws, size_t ws_size,
                              hipStream_t stream) {
  const float* feature = (const float*)d_in[0];
  const float* A       = (const float*)d_in[1];
  const int*   text    = (const int*)d_in[2];
  const int*   tlen    = (const int*)d_in[3];
  const float* Wih_f   = (const float*)d_in[4];
  const float* Whh_f   = (const float*)d_in[5];
  const float* bih_f   = (const float*)d_in[6];
  const float* bhh_f   = (const float*)d_in[7];
  const float* Wih_b   = (const float*)d_in[8];
  const float* Whh_b   = (const float*)d_in[9];
  const float* bih_b   = (const float*)d_in[10];
  const float* bhh_b   = (const float*)d_in[11];
  const float* gWih    = (const float*)d_in[12];
  const float* gWhh    = (const float*)d_in[13];
  const float* gbih    = (const float*)d_in[14];
  const float* gbhh    = (const float*)d_in[15];
  const float* genW    = (const float*)d_in[16];
  const float* genb    = (const float*)d_in[17];
  const float* cemb    = (const float*)d_in[18];
  float* out = (float*)d_out;
  const int total = in_sizes[2];

  char* ws = (char*)d_ws;
  size_t off = 0;
  auto alloc = [&](size_t bytes) -> void* {
    void* p = ws + off;
    off += (bytes + 255) & ~(size_t)255;
    return p;
  };
  float*    asum   = (float*)alloc((size_t)NB * NT * 4);
  int*      offs   = (int*)alloc(NB * 4);
  int*      rowmap = (int*)alloc((size_t)NB * NT * 4);
  int*      bars   = (int*)alloc(4 * 32 * 4);                   // 4 groups x 32 ints
  float*    Cbuf   = (float*)alloc((size_t)NT * NB * NC * 4);   // pool C
  float*    xgf    = (float*)alloc((size_t)NT * NB * G4 * 4);   // lstm fwd xg; later gxg bf16
  float*    xgb    = (float*)alloc((size_t)NT * NB * G4 * 4);   // lstm bwd xg; later overlays
  float*    xbuf   = (float*)alloc((size_t)NT * NB * XDIM * 4);
  uint32_t* WpL    = (uint32_t*)alloc((size_t)2 * 4 * 32 * 256 * 4 * 4);  // 1 MB
  ushort*   Wg16   = (ushort*)alloc((size_t)G3 * NC * 2);       // GRU Whh f16, 1.5 MB
  ushort*   hbuf   = (ushort*)alloc((size_t)2 * NB * NC * 2);   // GRU h ping-pong f16
  ushort*   Cbf    = (ushort*)alloc((size_t)NT * NB * NC * 2);  // C bf16; later gout bf16
  ushort*   Wihf_bf= (ushort*)alloc((size_t)G4 * NC * 2);
  ushort*   Wihb_bf= (ushort*)alloc((size_t)G4 * NC * 2);
  // overlays inside xgb (free after lstm_bsplit):
  ushort*   xbuf_bf = (ushort*)xgb;                               // 10.5 MB
  ushort*   gWih_bf = (ushort*)((char*)xgb + (11u << 20));        // 3 MB
  ushort*   genW_bf = (ushort*)((char*)xgb + (size_t)(14.5 * (1 << 20)));  // 5.12 MB
  ushort*   gxg     = (ushort*)xgf;                               // bf16 [5120][1536]
  ushort*   gout_bf = Cbf;

  // --- setup + weight packing/converts ---
  offsets_kernel<<<1, 64, 0, stream>>>(tlen, offs);
  rowmap_kernel<<<NB, 64, 0, stream>>>(tlen, offs, rowmap);
  zero_kernel<<<1, 256, 0, stream>>>(bars, 128);
  asum_kernel<<<NB * NT, 64, 0, stream>>>(A, asum);
  lstm_pack_kernel<<<2048, 64, 0, stream>>>(Whh_f, Whh_b, WpL);
  cvtf16_kernel<<<768, 256, 0, stream>>>(gWhh, Wg16, G3 * NC / 4);
  cvtbf_kernel<<<512, 256, 0, stream>>>(Wih_f, Wihf_bf, G4 * NC / 4);
  cvtbf_kernel<<<512, 256, 0, stream>>>(Wih_b, Wihb_bf, G4 * NC / 4);

  // --- attention pooling (f32, small N) ---
  sgemm_kernel<<<dim3(1, 4, NB), 256, 0, stream>>>(
      NC, NT, HW,
      feature, HW, (long)NC * HW, nullptr,
      A, HW, (long)NT * HW,
      asum, NT, nullptr,
      Cbuf, 1L, (long)NB * NC, (long)NC);

  // --- LSTM input projections via MFMA ---
  cvtbf_kernel<<<2560, 256, 0, stream>>>(Cbuf, Cbf, NT * NB * NC / 4);
  mgemm_kernel<<<dim3(G4 / 128, NT * NB / 128), 256, 0, stream>>>(
      NT * NB, G4, NC, Cbf, nullptr, Wihf_bf, bih_f, xgf, (long)G4, 0);
  mgemm_kernel<<<dim3(G4 / 128, NT * NB / 128), 256, 0, stream>>>(
      NT * NB, G4, NC, Cbf, nullptr, Wihb_bf, bih_b, xgb, (long)G4, 0);

  // --- LSTM recurrence ---
  lstm_bsplit_kernel<<<128, 512, 0, stream>>>(
      xgf, xgb, WpL, bhh_f, bhh_b, xbuf);

  // --- embedding into x[:,:,512:1024] ---
  emb_kernel<<<NT * NB, 128, 0, stream>>>(cemb, text, tlen, offs, xbuf);

  // --- GRU input projection via MFMA (xgb free -> overlays) ---
  cvtbf_kernel<<<5120, 256, 0, stream>>>(xbuf, xbuf_bf, NT * NB * XDIM / 4);
  cvtbf_kernel<<<1536, 256, 0, stream>>>(gWih, gWih_bf, G3 * XDIM / 4);
  cvtbf_kernel<<<2500, 256, 0, stream>>>(genW, genW_bf, NG * NC / 4);
  mgemm_kernel<<<dim3(G3 / 128, NT * NB / 128), 256, 0, stream>>>(
      NT * NB, G3, XDIM, xbuf_bf, nullptr, gWih_bf, gbih, gxg, (long)G3, 1);

  // --- GRU recurrence: j-split sync groups, MFMA, LDS-resident weights ---
  gru_sync_kernel<<<64, 256, 0, stream>>>(gxg, Wg16, gbhh, hbuf, gout_bf, bars);

  // --- vocab projection via MFMA, ragged rows straight into d_out ---
  mgemm_kernel<<<dim3((NG + 127) / 128, (total + 127) / 128), 256, 0, stream>>>(
      total, NG, NC, gout_bf, rowmap, genW_bf, genb, out, (long)NG, 0);
}

// Round 10
// 832.435 us; speedup vs baseline: 4.9270x; 1.0200x over previous
//
#include <hip/hip_runtime.h>
#include <hip/hip_bf16.h>
#include <hip/hip_fp16.h>
#include <math.h>

#define NB 128     // batch
#define NC 512     // channels
#define NT 40      // time steps
#define HW 512     // nH*nW
#define HL 256     // LSTM hidden per direction
#define NG 5000    // nclass
#define XDIM 1024  // 2*NC (GRU input)
#define G4 1024    // 4*HL
#define G3 1536    // 3*NC

typedef _Float16 half2v __attribute__((ext_vector_type(2)));
typedef _Float16 f16x8 __attribute__((ext_vector_type(8)));
typedef short s16x8 __attribute__((ext_vector_type(8)));
typedef float f32x4_ __attribute__((ext_vector_type(4)));

__device__ __forceinline__ float dot2(uint32_t w, uint32_t h, float acc) {
#if __has_builtin(__builtin_amdgcn_fdot2)
  return __builtin_amdgcn_fdot2(__builtin_bit_cast(half2v, w),
                                __builtin_bit_cast(half2v, h), acc, false);
#else
  half2v wv = __builtin_bit_cast(half2v, w), hv = __builtin_bit_cast(half2v, h);
  return acc + (float)wv.x * (float)hv.x + (float)wv.y * (float)hv.y;
#endif
}

__device__ __forceinline__ float sigm(float x) { return 1.f / (1.f + expf(-x)); }
__device__ __forceinline__ ushort f2hs(float f) {
  _Float16 h = (_Float16)f;
  return __builtin_bit_cast(ushort, h);
}
__device__ __forceinline__ uint32_t f2h(float f) { return (uint32_t)f2hs(f); }
__device__ __forceinline__ uint32_t f2bf(float f) {
  uint32_t u = __float_as_uint(f);
  return (u + 0x7fffu + ((u >> 16) & 1u)) >> 16;
}
__device__ __forceinline__ float bf2f(ushort u) {
  return __uint_as_float((uint32_t)u << 16);
}

// coherent (L2-bypass) 16B load as f16x8, via two agent-scope relaxed u64 loads
__device__ __forceinline__ f16x8 coh_load16(const ushort* p) {
  unsigned long long lo = __hip_atomic_load((const unsigned long long*)p,
                                            __ATOMIC_RELAXED, __HIP_MEMORY_SCOPE_AGENT);
  unsigned long long hi = __hip_atomic_load((const unsigned long long*)(p + 4),
                                            __ATOMIC_RELAXED, __HIP_MEMORY_SCOPE_AGENT);
  union { unsigned long long q[2]; f16x8 v; } u;
  u.q[0] = lo; u.q[1] = hi;
  return u.v;
}

// ---------------------------------------------------------------------------
// small setup kernels
// ---------------------------------------------------------------------------
__global__ void offsets_kernel(const int* __restrict__ tl, int* __restrict__ offs) {
  if (threadIdx.x == 0) {
    int o = 0;
    for (int b = 0; b < NB; ++b) { offs[b] = o; o += tl[b]; }
  }
}

__global__ void rowmap_kernel(const int* __restrict__ tl, const int* __restrict__ offs,
                              int* __restrict__ rowmap) {
  int b = blockIdx.x;
  int len = tl[b], off = offs[b];
  for (int t = threadIdx.x; t < len; t += blockDim.x)
    rowmap[off + t] = t * NB + b;   // row index into [t][b][*] matrices
}

__global__ void zero_kernel(int* __restrict__ p, int n) {
  int i = blockIdx.x * 256 + threadIdx.x;
  if (i < n) p[i] = 0;
}

// 1/sum over HW per (b,t)
__global__ __launch_bounds__(64) void asum_kernel(const float* __restrict__ A,
                                                  float* __restrict__ out) {
  int row = blockIdx.x;  // b*NT + t
  const float* p = A + (size_t)row * HW;
  float s = 0.f;
#pragma unroll
  for (int i = 0; i < 8; ++i) s += p[threadIdx.x + i * 64];
#pragma unroll
  for (int off = 32; off > 0; off >>= 1) s += __shfl_down(s, off);
  if (threadIdx.x == 0) out[row] = 1.0f / s;
}

// teacher-forcing embedding into x[:,:,512:1024]
__global__ __launch_bounds__(128) void emb_kernel(const float* __restrict__ ce,
                                                  const int* __restrict__ text,
                                                  const int* __restrict__ tl,
                                                  const int* __restrict__ offs,
                                                  float* __restrict__ x) {
  int bid = blockIdx.x;  // t*NB + b
  int t = bid >> 7, b = bid & 127;
  int tok = 0;
  if (t >= 2) {
    int p = t - 2;
    if (p < tl[b]) tok = text[offs[b] + p] + 1;
  }
  float4 v = *(const float4*)(ce + (size_t)tok * NC + threadIdx.x * 4);
  *(float4*)(x + (size_t)bid * XDIM + NC + threadIdx.x * 4) = v;
}

// f32 -> bf16 bulk convert (n4 = count/4)
__global__ __launch_bounds__(256) void cvtbf_kernel(const float* __restrict__ in,
                                                    ushort* __restrict__ out, int n4) {
  int i = blockIdx.x * 256 + threadIdx.x;
  if (i >= n4) return;
  float4 v = ((const float4*)in)[i];
  ushort4 o;
  o.x = (ushort)f2bf(v.x); o.y = (ushort)f2bf(v.y);
  o.z = (ushort)f2bf(v.z); o.w = (ushort)f2bf(v.w);
  ((ushort4*)out)[i] = o;
}

// f32 -> f16 bulk convert (n4 = count/4)
__global__ __launch_bounds__(256) void cvtf16_kernel(const float* __restrict__ in,
                                                     ushort* __restrict__ out, int n4) {
  int i = blockIdx.x * 256 + threadIdx.x;
  if (i >= n4) return;
  float4 v = ((const float4*)in)[i];
  ushort4 o;
  o.x = f2hs(v.x); o.y = f2hs(v.y); o.z = f2hs(v.z); o.w = f2hs(v.w);
  ((ushort4*)out)[i] = o;
}

// ---------------------------------------------------------------------------
// LSTM recurrence weight pack: f32 [g][j][k] -> f16 k-pair [g][k2g][j][q]
// ---------------------------------------------------------------------------
__global__ __launch_bounds__(64) void lstm_pack_kernel(
    const float* __restrict__ Wf, const float* __restrict__ Wb,
    uint32_t* __restrict__ Wp) {
  int row = blockIdx.x;                 // (dir*4+g)*256 + j
  int dg = row >> 8, j = row & 255;     // dg = dir*4+g
  int dir = dg >> 2;
  const float* W = (dir ? Wb : Wf) + ((size_t)(dg & 3) * HL + j) * HL;
  int l = threadIdx.x;
  float4 v = *(const float4*)(W + l * 4);
  uint32_t p0 = f2h(v.x) | (f2h(v.y) << 16);   // k2 = 2l
  uint32_t p1 = f2h(v.z) | (f2h(v.w) << 16);   // k2 = 2l+1
  int k2g = l >> 1, q0 = (2 * l) & 3;
  size_t base = ((size_t)dg * 32 + k2g) * 1024 + j * 4;
  Wp[base + q0] = p0;
  Wp[base + q0 + 1] = p1;
}

// ---------------------------------------------------------------------------
// generic f32 SGEMM (pool only): 128x128 tile, 8x8/thread, BK=16.
// ---------------------------------------------------------------------------
__global__ __launch_bounds__(256) void sgemm_kernel(
    int M, int N, int K,
    const float* __restrict__ A, int lda, long Abstride,
    const int* __restrict__ rowmap,
    const float* __restrict__ B, int ldb, long Bbstride,
    const float* __restrict__ bscale, int bscaleBstride,
    const float* __restrict__ bias,
    float* __restrict__ out, long ldoM, long ldoN, long Obstride) {
  const int batch = blockIdx.z;
  A += (long)batch * Abstride;
  B += (long)batch * Bbstride;
  out += (long)batch * Obstride;
  const float* bsc = bscale ? bscale + (long)batch * bscaleBstride : nullptr;

  __shared__ __align__(16) float As[16][132];
  __shared__ __align__(16) float Bs[16][132];

  const int m0 = blockIdx.y * 128, n0 = blockIdx.x * 128;
  const int tid = threadIdx.x;
  const int tm = tid >> 4, tn = tid & 15;
  const int r0 = tm * 8, c0 = tn * 4;
  float acc[8][8] = {};
  float4 pa[2], pb[2];

  auto fetch = [&](int k0) {
#pragma unroll
    for (int it = 0; it < 2; ++it) {
      int ch = tid + it * 256;
      int mm = ch >> 2;
      int kq = (ch & 3) << 2;
      int gm = m0 + mm;
      float4 v = make_float4(0.f, 0.f, 0.f, 0.f);
      if (gm < M) {
        long ar = rowmap ? (long)rowmap[gm] : (long)gm;
        v = *(const float4*)(A + ar * lda + k0 + kq);
      }
      pa[it] = v;
      int gn = n0 + mm;
      v = make_float4(0.f, 0.f, 0.f, 0.f);
      if (gn < N) {
        v = *(const float4*)(B + (long)gn * ldb + k0 + kq);
        if (bsc) { float s = bsc[gn]; v.x *= s; v.y *= s; v.z *= s; v.w *= s; }
      }
      pb[it] = v;
    }
  };

  auto store_lds = [&]() {
#pragma unroll
    for (int it = 0; it < 2; ++it) {
      int ch = tid + it * 256;
      int mm = ch >> 2;
      int kq = (ch & 3) << 2;
      As[kq + 0][mm] = pa[it].x; As[kq + 1][mm] = pa[it].y;
      As[kq + 2][mm] = pa[it].z; As[kq + 3][mm] = pa[it].w;
      Bs[kq + 0][mm] = pb[it].x; Bs[kq + 1][mm] = pb[it].y;
      Bs[kq + 2][mm] = pb[it].z; Bs[kq + 3][mm] = pb[it].w;
    }
  };

  fetch(0);
  for (int k0 = 0; k0 < K; k0 += 16) {
    store_lds();
    __syncthreads();
    if (k0 + 16 < K) fetch(k0 + 16);
#pragma unroll
    for (int kk = 0; kk < 16; ++kk) {
      float a[8], bb[8];
      *(float4*)&a[0] = *(const float4*)&As[kk][r0];
      *(float4*)&a[4] = *(const float4*)&As[kk][r0 + 4];
      *(float4*)&bb[0] = *(const float4*)&Bs[kk][c0];
      *(float4*)&bb[4] = *(const float4*)&Bs[kk][c0 + 64];
#pragma unroll
      for (int i = 0; i < 8; ++i)
#pragma unroll
        for (int j = 0; j < 8; ++j) acc[i][j] += a[i] * bb[j];
    }
    __syncthreads();
  }
#pragma unroll
  for (int i = 0; i < 8; ++i) {
    int gm = m0 + r0 + i;
    if (gm >= M) continue;
#pragma unroll
    for (int j = 0; j < 8; ++j) {
      int gn = n0 + c0 + (j & 3) + ((j >> 2) << 6);
      if (gn >= N) continue;
      float v = acc[i][j];
      if (bias) v += bias[gn];
      out[(long)gm * ldoM + (long)gn * ldoN] = v;
    }
  }
}

// ---------------------------------------------------------------------------
// bf16 MFMA GEMM (projections): 128x128 tile, 4 waves 2x2, 16x16x32 mfma.
// ---------------------------------------------------------------------------
#define MG_LDT 40

__global__ __launch_bounds__(256) void mgemm_kernel(
    int M, int N, int K,
    const ushort* __restrict__ A, const int* __restrict__ rowmap,
    const ushort* __restrict__ B, const float* __restrict__ bias,
    void* __restrict__ outp, long ldo, int outBf) {
  __shared__ __align__(16) ushort Al[128 * MG_LDT];
  __shared__ __align__(16) ushort Bl[128 * MG_LDT];
  const int m0 = blockIdx.y * 128, n0 = blockIdx.x * 128;
  const int tid = threadIdx.x;
  const int lane = tid & 63, wid = tid >> 6;
  const int wm = (wid >> 1) * 64, wn = (wid & 1) * 64;
  const int lr = lane & 15, lk = lane >> 4;

  f32x4_ acc[4][4];
#pragma unroll
  for (int i = 0; i < 4; ++i)
#pragma unroll
    for (int j = 0; j < 4; ++j) {
      acc[i][j][0] = 0.f; acc[i][j][1] = 0.f;
      acc[i][j][2] = 0.f; acc[i][j][3] = 0.f;
    }

  for (int k0 = 0; k0 < K; k0 += 32) {
    __syncthreads();
#pragma unroll
    for (int it = 0; it < 2; ++it) {
      int ch = tid + it * 256;          // 0..511
      int rr = ch >> 2, kq = (ch & 3) * 8;
      int gm = m0 + rr; if (gm >= M) gm = M - 1;
      long ar = rowmap ? (long)rowmap[gm] : (long)gm;
      uint4 av = *(const uint4*)(A + ar * K + k0 + kq);
      int gn = n0 + rr; if (gn >= N) gn = N - 1;
      uint4 bv = *(const uint4*)(B + (long)gn * K + k0 + kq);
      *(uint4*)&Al[rr * MG_LDT + kq] = av;
      *(uint4*)&Bl[rr * MG_LDT + kq] = bv;
    }
    __syncthreads();
    s16x8 af[4], bf[4];
#pragma unroll
    for (int i = 0; i < 4; ++i)
      af[i] = *(const s16x8*)&Al[(wm + i * 16 + lr) * MG_LDT + lk * 8];
#pragma unroll
    for (int i = 0; i < 4; ++i)
      bf[i] = *(const s16x8*)&Bl[(wn + i * 16 + lr) * MG_LDT + lk * 8];
#pragma unroll
    for (int i = 0; i < 4; ++i)
#pragma unroll
      for (int j = 0; j < 4; ++j)
        acc[i][j] = __builtin_amdgcn_mfma_f32_16x16x32_bf16(af[i], bf[j], acc[i][j], 0, 0, 0);
  }

#pragma unroll
  for (int i = 0; i < 4; ++i) {
#pragma unroll
    for (int j = 0; j < 4; ++j) {
      int n = n0 + wn + j * 16 + lr;
      if (n >= N) continue;
      float bv = bias ? bias[n] : 0.f;
#pragma unroll
      for (int r = 0; r < 4; ++r) {
        int m = m0 + wm + i * 16 + lk * 4 + r;
        if (m >= M) continue;
        float v = acc[i][j][r] + bv;
        if (outBf) ((ushort*)outp)[(long)m * ldo + n] = (ushort)f2bf(v);
        else       ((float*)outp)[(long)m * ldo + n] = v;
      }
    }
  }
}

// ---------------------------------------------------------------------------
// LSTM b-split recurrence (unchanged)
// ---------------------------------------------------------------------------
__global__ __launch_bounds__(512) void lstm_bsplit_kernel(
    const float* __restrict__ xg_f, const float* __restrict__ xg_b,
    const uint32_t* __restrict__ Wp,
    const float* __restrict__ bhh_f, const float* __restrict__ bhh_b,
    float* __restrict__ x) {
  const int dir = blockIdx.x >> 6, bp = blockIdx.x & 63;
  const float* xg = dir ? xg_b : xg_f;
  const float* bhh = dir ? bhh_b : bhh_f;
  const int j = threadIdx.x & 255;
  const int kh = threadIdx.x >> 8;
  const int gb = bp * 2 + kh;

  __shared__ __align__(16) ushort hh16[2][2][HL];  // [ping][b][j]
  __shared__ float part[2][4][2][HL];              // [b][g][kh][j]
  hh16[0][kh][j] = 0;
  float c = 0.f;
  const float bb0 = bhh[j], bb1 = bhh[HL + j], bb2 = bhh[2 * HL + j], bb3 = bhh[3 * HL + j];

  const uint32_t* wg0 = Wp + ((size_t)(dir * 4 + 0) * 32) * 1024 + j * 4;
  const uint32_t* wg1 = Wp + ((size_t)(dir * 4 + 1) * 32) * 1024 + j * 4;
  const uint32_t* wg2 = Wp + ((size_t)(dir * 4 + 2) * 32) * 1024 + j * 4;
  const uint32_t* wg3 = Wp + ((size_t)(dir * 4 + 3) * 32) * 1024 + j * 4;
  __syncthreads();

  for (int s = 0; s < NT; ++s) {
    const int t = dir ? (NT - 1 - s) : s;
    const long row = (long)t * NB + gb;
    float xi = xg[row * G4 + j];
    float xf = xg[row * G4 + HL + j];
    float xgg = xg[row * G4 + 2 * HL + j];
    float xo = xg[row * G4 + 3 * HL + j];
    const int p = s & 1;
    float a00 = 0.f, a10 = 0.f, a20 = 0.f, a30 = 0.f;
    float a01 = 0.f, a11 = 0.f, a21 = 0.f, a31 = 0.f;
#pragma unroll 4
    for (int k2g = kh * 16; k2g < kh * 16 + 16; ++k2g) {
      uint4 h0 = *(const uint4*)&hh16[p][0][8 * k2g];
      uint4 h1 = *(const uint4*)&hh16[p][1][8 * k2g];
      uint4 w0 = *(const uint4*)(wg0 + (size_t)k2g * 1024);
      uint4 w1 = *(const uint4*)(wg1 + (size_t)k2g * 1024);
      uint4 w2 = *(const uint4*)(wg2 + (size_t)k2g * 1024);
      uint4 w3 = *(const uint4*)(wg3 + (size_t)k2g * 1024);
      a00 = dot2(w0.x, h0.x, a00); a00 = dot2(w0.y, h0.y, a00);
      a00 = dot2(w0.z, h0.z, a00); a00 = dot2(w0.w, h0.w, a00);
      a01 = dot2(w0.x, h1.x, a01); a01 = dot2(w0.y, h1.y, a01);
      a01 = dot2(w0.z, h1.z, a01); a01 = dot2(w0.w, h1.w, a01);
      a10 = dot2(w1.x, h0.x, a10); a10 = dot2(w1.y, h0.y, a10);
      a10 = dot2(w1.z, h0.z, a10); a10 = dot2(w1.w, h0.w, a10);
      a11 = dot2(w1.x, h1.x, a11); a11 = dot2(w1.y, h1.y, a11);
      a11 = dot2(w1.z, h1.z, a11); a11 = dot2(w1.w, h1.w, a11);
      a20 = dot2(w2.x, h0.x, a20); a20 = dot2(w2.y, h0.y, a20);
      a20 = dot2(w2.z, h0.z, a20); a20 = dot2(w2.w, h0.w, a20);
      a21 = dot2(w2.x, h1.x, a21); a21 = dot2(w2.y, h1.y, a21);
      a21 = dot2(w2.z, h1.z, a21); a21 = dot2(w2.w, h1.w, a21);
      a30 = dot2(w3.x, h0.x, a30); a30 = dot2(w3.y, h0.y, a30);
      a30 = dot2(w3.z, h0.z, a30); a30 = dot2(w3.w, h0.w, a30);
      a31 = dot2(w3.x, h1.x, a31); a31 = dot2(w3.y, h1.y, a31);
      a31 = dot2(w3.z, h1.z, a31); a31 = dot2(w3.w, h1.w, a31);
    }
    part[0][0][kh][j] = a00; part[0][1][kh][j] = a10;
    part[0][2][kh][j] = a20; part[0][3][kh][j] = a30;
    part[1][0][kh][j] = a01; part[1][1][kh][j] = a11;
    part[1][2][kh][j] = a21; part[1][3][kh][j] = a31;
    __syncthreads();
    const int b = kh;
    float gi = xi + part[b][0][0][j] + part[b][0][1][j] + bb0;
    float gf = xf + part[b][1][0][j] + part[b][1][1][j] + bb1;
    float gg = xgg + part[b][2][0][j] + part[b][2][1][j] + bb2;
    float go = xo + part[b][3][0][j] + part[b][3][1][j] + bb3;
    c = sigm(gf) * c + sigm(gi) * tanhf(gg);
    float hn = sigm(go) * tanhf(c);
    x[row * XDIM + dir * HL + j] = hn;
    hh16[p ^ 1][b][j] = f2hs(hn);
    __syncthreads();
  }
}

// ---------------------------------------------------------------------------
// GRU sync recurrence v2: 64 blocks = 4 batch-groups x 16 j-chunks, 256 thr.
// W resident in LDS. h exchange: plain stores + release-store flag (vmcnt0 +
// buffer_wbl2 publishes to L3) ; consumers poll flags (relaxed) and read h
// with agent-scope relaxed u64 loads (sc1, L2-bypass -> L3). NO acquire fence
// -> no buffer_inv -> L2 (xg stream) preserved. xg(t+1) prefetched between
// release and poll so its HBM latency hides under the barrier wait.
// ---------------------------------------------------------------------------
__global__ __launch_bounds__(256) void gru_sync_kernel(
    const ushort* __restrict__ xg,    // bf16 [NT*NB][G3]
    const ushort* __restrict__ Wf,    // f16 [G3][NC]
    const float* __restrict__ bhh,
    ushort* __restrict__ hbuf,        // f16 [2][NB][NC]
    ushort* __restrict__ gout,        // bf16 [NT*NB][NC]
    int* __restrict__ flags) {
  const int bg = blockIdx.x >> 4, jc = blockIdx.x & 15;
  const int tid = threadIdx.x;
  const int lane = tid & 63, wid = tid >> 6;
  const int mt = wid >> 1, jsub = wid & 1;
  const int lr = lane & 15, lk = lane >> 4;

  __shared__ __align__(16) ushort Wl[16 * 96 * 40];  // [ktile][g*32+jj][40]

  // stage W chunk into LDS (one-time): 6144 uint4
  for (int i = tid; i < 6144; i += 256) {
    int kt = i / 384, rem = i - kt * 384;
    int row = rem >> 2, kq = rem & 3;
    int g = row >> 5, jj = row & 31;
    const ushort* src = Wf + ((size_t)(g * NC + jc * 32 + jj)) * NC + kt * 32 + kq * 8;
    *(uint4*)&Wl[(kt * 96 + row) * 40 + kq * 8] = *(const uint4*)src;
  }
  // zero own h slice in ping buffer 0 (plain stores; published by release below)
  for (int i = tid; i < 1024; i += 256) {
    int bb = i >> 5, jj = i & 31;
    hbuf[(size_t)(bg * 32 + bb) * NC + jc * 32 + jj] = 0;
  }

  int* gf = flags + bg * 64;                 // 256B per group
  const int jg = jc * 32 + jsub * 16 + lr;   // this thread's global j
  const int bbase = bg * 32 + mt * 16;       // A/C m-tile batch base
  const float bb0 = bhh[jg], bb1 = bhh[NC + jg], bb2 = bhh[2 * NC + jg];
  float hreg[4] = {0.f, 0.f, 0.f, 0.f};
  float pxr[4], pxz[4], pxn[4];

  auto pref = [&](int t) {
#pragma unroll
    for (int r = 0; r < 4; ++r) {
      int b = bbase + lk * 4 + r;
      long row = (long)t * NB + b;
      pxr[r] = bf2f(xg[row * G3 + jg]);
      pxz[r] = bf2f(xg[row * G3 + NC + jg]);
      pxn[r] = bf2f(xg[row * G3 + 2 * NC + jg]);
    }
  };

  // barrier: release own flag (publishes h via vmcnt0+wbl2), prefetch, poll
  auto bar = [&](int step, int preft) {
    __syncthreads();   // compiler drains vmcnt before s_barrier -> h stores done
    if (tid == 0)
      __hip_atomic_store(&gf[jc], step, __ATOMIC_RELEASE, __HIP_MEMORY_SCOPE_AGENT);
    if (preft >= 0) pref(preft);   // loads fly while we wait
    if (tid < 16) {
      while (__hip_atomic_load(&gf[tid], __ATOMIC_RELAXED, __HIP_MEMORY_SCOPE_AGENT) < step)
        __builtin_amdgcn_s_sleep(1);
    }
    __syncthreads();
  };

  bar(1, 0);   // publish W-stage-done + h zeros; prefetch xg(0)

  for (int t = 0; t < NT; ++t) {
    const int p = t & 1;
    const ushort* hb = hbuf + (size_t)p * NB * NC;
    f32x4_ ar = {0.f, 0.f, 0.f, 0.f};
    f32x4_ az = {0.f, 0.f, 0.f, 0.f};
    f32x4_ an = {0.f, 0.f, 0.f, 0.f};
#pragma unroll
    for (int kt = 0; kt < 16; ++kt) {
      f16x8 a = coh_load16(hb + (size_t)(bbase + lr) * NC + kt * 32 + lk * 8);
      f16x8 br = *(const f16x8*)&Wl[(kt * 96 + 0  + jsub * 16 + lr) * 40 + lk * 8];
      f16x8 bz = *(const f16x8*)&Wl[(kt * 96 + 32 + jsub * 16 + lr) * 40 + lk * 8];
      f16x8 bn = *(const f16x8*)&Wl[(kt * 96 + 64 + jsub * 16 + lr) * 40 + lk * 8];
      ar = __builtin_amdgcn_mfma_f32_16x16x32_f16(a, br, ar, 0, 0, 0);
      az = __builtin_amdgcn_mfma_f32_16x16x32_f16(a, bz, az, 0, 0, 0);
      an = __builtin_amdgcn_mfma_f32_16x16x32_f16(a, bn, an, 0, 0, 0);
    }
    ushort* hw = hbuf + (size_t)(p ^ 1) * NB * NC;
#pragma unroll
    for (int r = 0; r < 4; ++r) {
      int b = bbase + lk * 4 + r;
      long row = (long)t * NB + b;
      float rr = sigm(pxr[r] + ar[r] + bb0);
      float zz = sigm(pxz[r] + az[r] + bb1);
      float nn = tanhf(pxn[r] + rr * (an[r] + bb2));
      float h = (1.f - zz) * nn + zz * hreg[r];
      hreg[r] = h;
      hw[(size_t)b * NC + jg] = f2hs(h);
      gout[row * NC + jg] = (ushort)f2bf(h);
    }
    if (t + 1 < NT) bar(t + 2, t + 1);
  }
}

// ---------------------------------------------------------------------------
extern "C" void kernel_launch(void* const* d_in, const int* in_sizes, int n_in,
                              void* d_out, int out_size, void* d_ws, size_t ws_size,
                              hipStream_t stream) {
  const float* feature = (const float*)d_in[0];
  const float* A       = (const float*)d_in[1];
  const int*   text    = (const int*)d_in[2];
  const int*   tlen    = (const int*)d_in[3];
  const float* Wih_f   = (const float*)d_in[4];
  const float* Whh_f   = (const float*)d_in[5];
  const float* bih_f   = (const float*)d_in[6];
  const float* bhh_f   = (const float*)d_in[7];
  const float* Wih_b   = (const float*)d_in[8];
  const float* Whh_b   = (const float*)d_in[9];
  const float* bih_b   = (const float*)d_in[10];
  const float* bhh_b   = (const float*)d_in[11];
  const float* gWih    = (const float*)d_in[12];
  const float* gWhh    = (const float*)d_in[13];
  const float* gbih    = (const float*)d_in[14];
  const float* gbhh    = (const float*)d_in[15];
  const float* genW    = (const float*)d_in[16];
  const float* genb    = (const float*)d_in[17];
  const float* cemb    = (const float*)d_in[18];
  float* out = (float*)d_out;
  const int total = in_sizes[2];

  char* ws = (char*)d_ws;
  size_t off = 0;
  auto alloc = [&](size_t bytes) -> void* {
    void* p = ws + off;
    off += (bytes + 255) & ~(size_t)255;
    return p;
  };
  float*    asum   = (float*)alloc((size_t)NB * NT * 4);
  int*      offs   = (int*)alloc(NB * 4);
  int*      rowmap = (int*)alloc((size_t)NB * NT * 4);
  int*      flags  = (int*)alloc(4 * 64 * 4);                   // 4 groups x 64 ints
  float*    Cbuf   = (float*)alloc((size_t)NT * NB * NC * 4);   // pool C
  float*    xgf    = (float*)alloc((size_t)NT * NB * G4 * 4);   // lstm fwd xg; later gxg bf16
  float*    xgb    = (float*)alloc((size_t)NT * NB * G4 * 4);   // lstm bwd xg; later overlays
  float*    xbuf   = (float*)alloc((size_t)NT * NB * XDIM * 4);
  uint32_t* WpL    = (uint32_t*)alloc((size_t)2 * 4 * 32 * 256 * 4 * 4);  // 1 MB
  ushort*   Wg16   = (ushort*)alloc((size_t)G3 * NC * 2);       // GRU Whh f16, 1.5 MB
  ushort*   hbuf   = (ushort*)alloc((size_t)2 * NB * NC * 2);   // GRU h ping-pong f16
  ushort*   Cbf    = (ushort*)alloc((size_t)NT * NB * NC * 2);  // C bf16; later gout bf16
  ushort*   Wihf_bf= (ushort*)alloc((size_t)G4 * NC * 2);
  ushort*   Wihb_bf= (ushort*)alloc((size_t)G4 * NC * 2);
  // overlays inside xgb (free after lstm_bsplit):
  ushort*   xbuf_bf = (ushort*)xgb;                               // 10.5 MB
  ushort*   gWih_bf = (ushort*)((char*)xgb + (11u << 20));        // 3 MB
  ushort*   genW_bf = (ushort*)((char*)xgb + (size_t)(14.5 * (1 << 20)));  // 5.12 MB
  ushort*   gxg     = (ushort*)xgf;                               // bf16 [5120][1536]
  ushort*   gout_bf = Cbf;

  // --- setup + weight packing/converts ---
  offsets_kernel<<<1, 64, 0, stream>>>(tlen, offs);
  rowmap_kernel<<<NB, 64, 0, stream>>>(tlen, offs, rowmap);
  zero_kernel<<<1, 256, 0, stream>>>(flags, 256);
  asum_kernel<<<NB * NT, 64, 0, stream>>>(A, asum);
  lstm_pack_kernel<<<2048, 64, 0, stream>>>(Whh_f, Whh_b, WpL);
  cvtf16_kernel<<<768, 256, 0, stream>>>(gWhh, Wg16, G3 * NC / 4);
  cvtbf_kernel<<<512, 256, 0, stream>>>(Wih_f, Wihf_bf, G4 * NC / 4);
  cvtbf_kernel<<<512, 256, 0, stream>>>(Wih_b, Wihb_bf, G4 * NC / 4);

  // --- attention pooling (f32, small N) ---
  sgemm_kernel<<<dim3(1, 4, NB), 256, 0, stream>>>(
      NC, NT, HW,
      feature, HW, (long)NC * HW, nullptr,
      A, HW, (long)NT * HW,
      asum, NT, nullptr,
      Cbuf, 1L, (long)NB * NC, (long)NC);

  // --- LSTM input projections via MFMA ---
  cvtbf_kernel<<<2560, 256, 0, stream>>>(Cbuf, Cbf, NT * NB * NC / 4);
  mgemm_kernel<<<dim3(G4 / 128, NT * NB / 128), 256, 0, stream>>>(
      NT * NB, G4, NC, Cbf, nullptr, Wihf_bf, bih_f, xgf, (long)G4, 0);
  mgemm_kernel<<<dim3(G4 / 128, NT * NB / 128), 256, 0, stream>>>(
      NT * NB, G4, NC, Cbf, nullptr, Wihb_bf, bih_b, xgb, (long)G4, 0);

  // --- LSTM recurrence ---
  lstm_bsplit_kernel<<<128, 512, 0, stream>>>(
      xgf, xgb, WpL, bhh_f, bhh_b, xbuf);

  // --- embedding into x[:,:,512:1024] ---
  emb_kernel<<<NT * NB, 128, 0, stream>>>(cemb, text, tlen, offs, xbuf);

  // --- GRU input projection via MFMA (xgb free -> overlays) ---
  cvtbf_kernel<<<5120, 256, 0, stream>>>(xbuf, xbuf_bf, NT * NB * XDIM / 4);
  cvtbf_kernel<<<1536, 256, 0, stream>>>(gWih, gWih_bf, G3 * XDIM / 4);
  cvtbf_kernel<<<2500, 256, 0, stream>>>(genW, genW_bf, NG * NC / 4);
  mgemm_kernel<<<dim3(G3 / 128, NT * NB / 128), 256, 0, stream>>>(
      NT * NB, G3, XDIM, xbuf_bf, nullptr, gWih_bf, gbih, gxg, (long)G3, 1);

  // --- GRU recurrence: j-split sync groups, MFMA, LDS-resident weights ---
  gru_sync_kernel<<<64, 256, 0, stream>>>(gxg, Wg16, gbhh, hbuf, gout_bf, flags);

  // --- vocab projection via MFMA, ragged rows straight into d_out ---
  mgemm_kernel<<<dim3((NG + 127) / 128, (total + 127) / 128), 256, 0, stream>>>(
      total, NG, NC, gout_bf, rowmap, genW_bf, genb, out, (long)NG, 0);
}